// Round 10
// baseline (944.191 us; speedup 1.0000x reference)
//
#include <hip/hip_runtime.h>
#include <cstdint>
#include <cmath>

// ---------------------------------------------------------------------------
// Informer encoder forward (B=4, L=2048, ENC_IN=32, D_MODEL=512, D_FF=2048,
// E_LAYERS=2, H=8, FACTOR=5).
// Round 10: rank-based parallel top-k (replaces 75 us serial selection with
// ~4 us LDS-broadcast rank scan; exact JAX tie-breaking preserved).
// ---------------------------------------------------------------------------

#define NB 4
#define DM 512
#define NH 8
#define HD 64
#define QS 1536  // QKV row stride

typedef unsigned short ushort_t;
typedef __bf16 bf16x8 __attribute__((ext_vector_type(8)));
typedef float floatx4 __attribute__((ext_vector_type(4)));
typedef unsigned short ushort8_t __attribute__((ext_vector_type(8)));

__device__ inline ushort_t f2b(float f) {
  uint32_t u = __float_as_uint(f);
  uint32_t r = (u + 0x7fffu + ((u >> 16) & 1u)) >> 16;
  return (ushort_t)r;
}
__device__ inline float b2f(ushort_t u) {
  return __uint_as_float((uint32_t)u << 16);
}

// ---------------- fused weight casts ---------------------------------------
__global__ void castqkv_k(const float* __restrict__ Wq,
                          const float* __restrict__ Wk,
                          const float* __restrict__ Wv,
                          ushort_t* __restrict__ out) {
  int gid = blockIdx.x * 256 + threadIdx.x;  // 393216 float4 units
  if (gid >= 393216) return;
  int ly = gid / 196608, r4 = gid - ly * 196608;
  int r = r4 >> 7, c4 = r4 & 127;
  int sel = r >> 9, srow = r & 511;
  const float* src = (sel == 0 ? Wq : sel == 1 ? Wk : Wv) + ly * 262144 +
                     srow * 512 + c4 * 4;
  float4 v = *(const float4*)src;
  ushort4 o;
  o.x = f2b(v.x); o.y = f2b(v.y); o.z = f2b(v.z); o.w = f2b(v.w);
  ((ushort4*)out)[ly * 196608 + r * 128 + c4] = o;
}

__global__ void castw3_k(const float* __restrict__ Wo,
                         const float* __restrict__ W1,
                         const float* __restrict__ W2,
                         const float* __restrict__ tw,
                         ushort_t* __restrict__ oWo, ushort_t* __restrict__ oW1,
                         ushort_t* __restrict__ oW2, ushort_t* __restrict__ otw) {
  int gid = blockIdx.x * 256 + threadIdx.x;  // 1,191,936 float4 units
  if (gid >= 1191936) return;
  const float* src;
  ushort4* dst;
  int i;
  if (gid < 131072) { src = Wo; dst = (ushort4*)oWo; i = gid; }
  else if (gid < 655360) { src = W1; dst = (ushort4*)oW1; i = gid - 131072; }
  else if (gid < 1179648) { src = W2; dst = (ushort4*)oW2; i = gid - 655360; }
  else { src = tw; dst = (ushort4*)otw; i = gid - 1179648; }
  float4 v = ((const float4*)src)[i];
  ushort4 o;
  o.x = f2b(v.x); o.y = f2b(v.y); o.z = f2b(v.z); o.w = f2b(v.w);
  dst[i] = o;
}

__global__ void castw_conv_k(const float* __restrict__ in,
                             ushort_t* __restrict__ out) {
  int gid = blockIdx.x * 256 + threadIdx.x;  // 512*1536
  int d = gid / 1536, r = gid - d * 1536;
  int t = r >> 9, i = r & 511;
  out[gid] = f2b(in[d * 1536 + i * 3 + t]);
}

__global__ void setup_small_k(const float* __restrict__ bq,
                              const float* __restrict__ bk,
                              const float* __restrict__ bv,
                              float* __restrict__ ZB,
                              float* __restrict__ BQKV) {
  int gid = blockIdx.x * 256 + threadIdx.x;  // 3584
  if (gid >= 3584) return;
  if (gid < 512) { ZB[gid] = 0.f; return; }
  int g = gid - 512;
  int layer = g / 1536, r = g - layer * 1536;
  float v;
  if (r < 512) v = bq[layer * 512 + r];
  else if (r < 1024) v = bk[layer * 512 + r - 512];
  else v = bv[layer * 512 + r - 1024];
  BQKV[g] = v;
}

__host__ __device__ inline void threefry2x32(uint32_t k0, uint32_t k1,
                                             uint32_t c0, uint32_t c1,
                                             uint32_t* o0, uint32_t* o1) {
  uint32_t ks0 = k0, ks1 = k1, ks2 = k0 ^ k1 ^ 0x1BD11BDAu;
  uint32_t x0 = c0 + ks0;
  uint32_t x1 = c1 + ks1;
  const uint32_t rotA[4] = {13u, 15u, 26u, 6u};
  const uint32_t rotB[4] = {17u, 29u, 16u, 24u};
  uint32_t ks[3] = {ks0, ks1, ks2};
  #pragma unroll
  for (int i = 0; i < 5; ++i) {
    const uint32_t* r = (i & 1) ? rotB : rotA;
    #pragma unroll
    for (int j = 0; j < 4; ++j) {
      x0 += x1;
      x1 = (x1 << r[j]) | (x1 >> (32u - r[j]));
      x1 ^= x0;
    }
    x0 += ks[(i + 1) % 3];
    x1 += ks[(i + 2) % 3] + (uint32_t)(i + 1);
  }
  *o0 = x0; *o1 = x1;
}

__global__ void gen_idx_k(int* __restrict__ idx, int n, int mask,
                          uint32_t k0, uint32_t k1) {
  int i = blockIdx.x * 256 + threadIdx.x;
  if (i < n) {
    uint32_t o0, o1;
    threefry2x32(k0, k1, 0u, (uint32_t)i, &o0, &o1);
    idx[i] = (int)((o0 ^ o1) & (uint32_t)mask);
  }
}

__device__ inline float wave_sum64(float v) {
  #pragma unroll
  for (int o = 32; o > 0; o >>= 1) v += __shfl_xor(v, o, 64);
  return v;
}
__device__ inline float wave_max64(float v) {
  #pragma unroll
  for (int o = 32; o > 0; o >>= 1) v = fmaxf(v, __shfl_xor(v, o, 64));
  return v;
}

// ---------------- positional-encoding table (2048 x 512) -------------------
__global__ void pe_k(float* __restrict__ pe) {
  int i = blockIdx.x * 256 + threadIdx.x;  // 1,048,576
  int d = i & 511, l = i >> 9;
  int j2 = d & ~1;
  float div = expf((float)j2 * -1.7988946039e-2f);  // -ln(10000)/512
  float ang = (float)l * div;
  pe[i] = (d & 1) ? cosf(ang) : sinf(ang);
}

// ---------------- im2col for token conv: (B*L, 96) bf16 --------------------
__global__ void im2col_tok_k(const float* __restrict__ xe,
                             ushort_t* __restrict__ A) {
  int gid = blockIdx.x * 256 + threadIdx.x;  // 8192*96
  int col = gid % 96;
  int row = gid / 96;
  int c = col / 3, t = col - c * 3;
  int b = row >> 11, l = row & 2047;
  int ls = (l + t - 1) & 2047;
  A[gid] = f2b(xe[((size_t)b * 2048 + ls) * 32 + c]);
}

// ---------------- bf16 MFMA GEMM with XCD swizzle --------------------------
__device__ inline void gload16(const ushort_t* g, ushort_t* l) {
  __builtin_amdgcn_global_load_lds(
      (const __attribute__((address_space(1))) unsigned int*)(const void*)g,
      (__attribute__((address_space(3))) unsigned int*)(void*)l, 16, 0, 0);
}

template <int GELU, int OMODE, int ADDPE>  // OMODE: 0 f32, 1 bf16, 2 both
__global__ __launch_bounds__(256) void mgemm_k(
    const ushort_t* __restrict__ A, const ushort_t* __restrict__ W,
    const float* __restrict__ bias, float* __restrict__ Cf,
    ushort_t* __restrict__ Cb, const float* __restrict__ pe,
    int X, int ldc, int K) {
  __shared__ ushort_t As[128 * 32];
  __shared__ ushort_t Bs[128 * 32];
  int id = blockIdx.x;
  int cc = id & 7, j = id >> 3;
  int bx = j % X;
  int by = (j / X) * 8 + cc;
  int m0 = by * 128, n0 = bx * 128;
  int t = threadIdx.x;
  int lane = t & 63, wv = t >> 6;
  int sr = lane >> 2, sc = (lane & 3) * 8;
  int ra0 = wv * 32 + sr, ra1 = ra0 + 16;
  const ushort_t* gA0 = A + (size_t)(m0 + ra0) * K + sc;
  const ushort_t* gA1 = A + (size_t)(m0 + ra1) * K + sc;
  const ushort_t* gB0 = W + (size_t)(n0 + ra0) * K + sc;
  const ushort_t* gB1 = W + (size_t)(n0 + ra1) * K + sc;
  ushort_t* lA0 = As + wv * 1024;
  ushort_t* lA1 = lA0 + 512;
  ushort_t* lB0 = Bs + wv * 1024;
  ushort_t* lB1 = lB0 + 512;

  int quad = lane >> 4, lr = lane & 15;
  int wm = wv >> 1, wn = wv & 1;

  floatx4 acc[4][4] = {};
  for (int ks = 0; ks < K; ks += 32) {
    gload16(gA0, lA0);
    gload16(gA1, lA1);
    gload16(gB0, lB0);
    gload16(gB1, lB1);
    gA0 += 32; gA1 += 32; gB0 += 32; gB1 += 32;
    __syncthreads();
    bf16x8 av[4], bv[4];
    #pragma unroll
    for (int mt = 0; mt < 4; ++mt)
      av[mt] = *(const bf16x8*)&As[(wm * 64 + mt * 16 + lr) * 32 + quad * 8];
    #pragma unroll
    for (int nt = 0; nt < 4; ++nt)
      bv[nt] = *(const bf16x8*)&Bs[(wn * 64 + nt * 16 + lr) * 32 + quad * 8];
    #pragma unroll
    for (int mt = 0; mt < 4; ++mt)
      #pragma unroll
      for (int nt = 0; nt < 4; ++nt)
        acc[mt][nt] = __builtin_amdgcn_mfma_f32_16x16x32_bf16(
            av[mt], bv[nt], acc[mt][nt], 0, 0, 0);
    __syncthreads();
  }
  #pragma unroll
  for (int nt = 0; nt < 4; ++nt) {
    int col = n0 + wn * 64 + nt * 16 + lr;
    float bsv = bias[col];
    #pragma unroll
    for (int mt = 0; mt < 4; ++mt) {
      int row0 = m0 + wm * 64 + mt * 16 + quad * 4;
      #pragma unroll
      for (int r = 0; r < 4; ++r) {
        int row = row0 + r;
        float v = acc[mt][nt][r] + bsv;
        if (ADDPE) v += pe[(size_t)(row & 2047) * ldc + col];
        if (GELU) v = 0.5f * v * (1.0f + erff(v * 0.70710678118654752f));
        if (OMODE == 0 || OMODE == 2) Cf[(size_t)row * ldc + col] = v;
        if (OMODE == 1 || OMODE == 2) Cb[(size_t)row * ldc + col] = f2b(v);
      }
    }
  }
}

// ---------------- fp32 fallback GEMM (final projection, N=32) --------------
__global__ __launch_bounds__(256) void gemm_k(
    const float* __restrict__ A, const float* __restrict__ W,
    const float* __restrict__ bias, float* __restrict__ C,
    int M, int N, int K) {
  __shared__ float As2[16][64 + 4];
  __shared__ float Ws2[16][64 + 4];
  int m0 = blockIdx.y * 64, n0 = blockIdx.x * 64;
  int t = threadIdx.x;
  int tx = t & 15, ty = t >> 4;
  float acc[4][4] = {};
  for (int k0 = 0; k0 < K; k0 += 16) {
    #pragma unroll
    for (int i = 0; i < 4; ++i) {
      int li = t + i * 256;
      int m = li >> 4, kk = li & 15;
      As2[kk][m] = A[(size_t)(m0 + m) * K + k0 + kk];
    }
    #pragma unroll
    for (int i = 0; i < 4; ++i) {
      int li = t + i * 256;
      int n = li >> 4, kk = li & 15;
      int gn = n0 + n;
      Ws2[kk][n] = (gn < N) ? W[(size_t)gn * K + k0 + kk] : 0.0f;
    }
    __syncthreads();
    #pragma unroll
    for (int kk = 0; kk < 16; ++kk) {
      float4 avv = *(const float4*)&As2[kk][ty * 4];
      float4 bvv = *(const float4*)&Ws2[kk][tx * 4];
      float a[4] = {avv.x, avv.y, avv.z, avv.w};
      float bb[4] = {bvv.x, bvv.y, bvv.z, bvv.w};
      #pragma unroll
      for (int i = 0; i < 4; ++i)
        #pragma unroll
        for (int j = 0; j < 4; ++j) acc[i][j] += a[i] * bb[j];
    }
    __syncthreads();
  }
  #pragma unroll
  for (int i = 0; i < 4; ++i) {
    int m = m0 + ty * 4 + i;
    #pragma unroll
    for (int j = 0; j < 4; ++j) {
      int n = n0 + tx * 4 + j;
      if (n < N) C[(size_t)m * N + n] = acc[i][j] + bias[n];
    }
  }
}

// ---------------- LayerNorm (+optional residual, +optional bf16 copy) ------
__global__ __launch_bounds__(128) void ln_k(
    const float* __restrict__ A, const float* __restrict__ Bres,
    const float* __restrict__ g, const float* __restrict__ be,
    float* __restrict__ O, ushort_t* __restrict__ Ob) {
  int r = blockIdx.x, t = threadIdx.x;
  __shared__ float lds[2];
  float4 v = ((const float4*)(A + (size_t)r * DM))[t];
  if (Bres) {
    float4 u = ((const float4*)(Bres + (size_t)r * DM))[t];
    v.x += u.x; v.y += u.y; v.z += u.z; v.w += u.w;
  }
  float s = wave_sum64(v.x + v.y + v.z + v.w);
  int w = t >> 6;
  if ((t & 63) == 0) lds[w] = s;
  __syncthreads();
  float mu = (lds[0] + lds[1]) * (1.0f / 512.0f);
  __syncthreads();
  float dx = v.x - mu, dy = v.y - mu, dz = v.z - mu, dw = v.w - mu;
  float sq = wave_sum64(dx * dx + dy * dy + dz * dz + dw * dw);
  if ((t & 63) == 0) lds[w] = sq;
  __syncthreads();
  float var = (lds[0] + lds[1]) * (1.0f / 512.0f);
  float inv = 1.0f / sqrtf(var + 1e-5f);
  float4 gv = ((const float4*)g)[t];
  float4 bv = ((const float4*)be)[t];
  float4 o;
  o.x = dx * inv * gv.x + bv.x;
  o.y = dy * inv * gv.y + bv.y;
  o.z = dz * inv * gv.z + bv.z;
  o.w = dw * inv * gv.w + bv.w;
  ((float4*)(O + (size_t)r * DM))[t] = o;
  if (Ob) {
    ushort4 ob;
    ob.x = f2b(o.x); ob.y = f2b(o.y); ob.z = f2b(o.z); ob.w = f2b(o.w);
    ((ushort4*)(Ob + (size_t)r * DM))[t] = ob;
  }
}

// ---------------- M[b,h,l]: one wave per (b,l), all-bf16 QKV ---------------
template <int UU>
__global__ __launch_bounds__(256) void qk_m_k(
    const ushort_t* __restrict__ QKVb, const int* __restrict__ idx,
    float* __restrict__ Mout, int Lx) {
  int l = blockIdx.x;
  int b = threadIdx.x >> 6;  // wave = batch
  int lane = threadIdx.x & 63;
  const ushort_t* qp = QKVb + ((size_t)b * Lx + l) * QS + lane * 8;
  float q[8];
  {
    ushort8_t qv = *(const ushort8_t*)qp;
    #pragma unroll
    for (int c = 0; c < 8; ++c) q[c] = b2f(qv[c]);
  }
  const ushort_t* Kbase = QKVb + (size_t)b * Lx * QS + 512 + lane * 8;
  const int* ip = idx + (size_t)l * UU;
  float maxv = -INFINITY, sumv = 0.f;
  #pragma unroll
  for (int u0 = 0; u0 < UU; u0 += 8) {
    ushort8_t kv[8];
    #pragma unroll
    for (int j = 0; j < 8; ++j) {
      if (u0 + j < UU)
        kv[j] = *(const ushort8_t*)(Kbase + (size_t)ip[u0 + j] * QS);
    }
    #pragma unroll
    for (int j = 0; j < 8; ++j) {
      if (u0 + j < UU) {
        float p = 0.f;
        #pragma unroll
        for (int c = 0; c < 8; ++c) p += q[c] * b2f(kv[j][c]);
        p += __shfl_xor(p, 1, 64);
        p += __shfl_xor(p, 2, 64);
        p += __shfl_xor(p, 4, 64);
        maxv = fmaxf(maxv, p);
        sumv += p;
      }
    }
  }
  if ((lane & 7) == 0) {
    int h = lane >> 3;
    Mout[(size_t)(b * 8 + h) * Lx + l] = maxv - sumv / (float)Lx;
  }
}

// ---------------- rank-based top-U (exact JAX tie-breaking) ----------------
// block = 1024 threads per (b,h); element i is top-U iff
// rank(i) = #{j : M[j] > M[i] || (M[j]==M[i] && j<i)} < U, output pos = rank.
__global__ __launch_bounds__(1024) void topk_k(
    const float* __restrict__ Mbuf, int* __restrict__ Mtop, int Lx, int U) {
  int bh = blockIdx.x;
  const float* m = Mbuf + (size_t)bh * Lx;
  __shared__ float sm[2048];
  int t = threadIdx.x;
  for (int i = t; i < Lx; i += 1024) sm[i] = m[i];
  __syncthreads();
  int i0 = t, i1 = t + 1024;
  float v0 = sm[i0];
  float v1 = (i1 < Lx) ? sm[i1] : 0.f;
  int r0 = 0, r1 = 0;
  for (int j = 0; j < Lx; j += 4) {
    float4 mj = *(const float4*)&sm[j];
    r0 += (mj.x > v0) || (mj.x == v0 && (j + 0) < i0);
    r0 += (mj.y > v0) || (mj.y == v0 && (j + 1) < i0);
    r0 += (mj.z > v0) || (mj.z == v0 && (j + 2) < i0);
    r0 += (mj.w > v0) || (mj.w == v0 && (j + 3) < i0);
    if (i1 < Lx) {
      r1 += (mj.x > v1) || (mj.x == v1 && (j + 0) < i1);
      r1 += (mj.y > v1) || (mj.y == v1 && (j + 1) < i1);
      r1 += (mj.z > v1) || (mj.z == v1 && (j + 2) < i1);
      r1 += (mj.w > v1) || (mj.w == v1 && (j + 3) < i1);
    }
  }
  if (r0 < U) Mtop[bh * U + r0] = i0;
  if (i1 < Lx && r1 < U) Mtop[bh * U + r1] = i1;
}

// ---------------- meanV from bf16 QKV (V at +1024) -------------------------
__global__ __launch_bounds__(512) void meanv1_k(const ushort_t* __restrict__ QKVb,
                                                float* __restrict__ part,
                                                int Lx) {
  int b = blockIdx.x >> 4, chunk = blockIdx.x & 15;
  int rows = Lx >> 4;
  int t = threadIdx.x;  // 512
  const ushort_t* vp =
      QKVb + ((size_t)b * Lx + (size_t)chunk * rows) * QS + 1024 + t;
  float s = 0.f;
  for (int l = 0; l < rows; ++l) s += b2f(vp[(size_t)l * QS]);
  part[(size_t)blockIdx.x * DM + t] = s;
}
__global__ __launch_bounds__(512) void meanv2_k(const float* __restrict__ part,
                                                float* __restrict__ mv,
                                                int Lx) {
  int b = blockIdx.x, t = threadIdx.x;
  float s = 0.f;
  #pragma unroll
  for (int c = 0; c < 16; ++c) s += part[(size_t)(b * 16 + c) * DM + t];
  mv[b * DM + t] = s / (float)Lx;
}

__global__ void fillctx_k(ushort_t* __restrict__ ctx,
                          const float* __restrict__ mv, int Lx) {
  size_t i4 = (size_t)blockIdx.x * 256 + threadIdx.x;
  int col4 = (int)(i4 & 127);
  size_t row = i4 >> 7;
  int b = (int)(row / (size_t)Lx);
  const float* m = mv + b * DM + col4 * 4;
  ushort4 o;
  o.x = f2b(m[0]); o.y = f2b(m[1]); o.z = f2b(m[2]); o.w = f2b(m[3]);
  ((ushort4*)ctx)[i4] = o;
}

// ---------------- flash split-K attention (bf16 QKV) -----------------------
__global__ __launch_bounds__(512) void attn_flash_k(
    const ushort_t* __restrict__ QKVb, const int* __restrict__ Mtop,
    float* __restrict__ part, int Lx, int U, int nchunk) {
  int blk = blockIdx.x;
  int chunk = blk % nchunk, bh = blk / nchunk;
  int h = bh & 7, b = bh >> 3;
  int rows = Lx / nchunk;
  int ntile = rows >> 6;
  __shared__ float s_q[40 * 64];
  __shared__ float s_k[64 * 65];
  __shared__ float s_v[64 * 65];
  __shared__ float s_p[40 * 64];
  __shared__ float s_m[40], s_l[40], s_a[40];
  int t = threadIdx.x;
  int d = t & 63, wv = t >> 6;

  for (int i = t; i < U * 64; i += 512) {
    int u = i >> 6, dd = i & 63;
    int qi = Mtop[bh * U + u];
    s_q[i] = b2f(QKVb[((size_t)b * Lx + qi) * QS + h * HD + dd]) * 0.125f;
  }
  if (t < U) { s_m[t] = -INFINITY; s_l[t] = 0.f; s_a[t] = 0.f; }
  float o[5] = {0.f, 0.f, 0.f, 0.f, 0.f};
  __syncthreads();

  const ushort_t* Kp = QKVb + (size_t)b * Lx * QS + 512 + h * HD;
  const ushort_t* Vp = QKVb + (size_t)b * Lx * QS + 1024 + h * HD;

  for (int tile = 0; tile < ntile; ++tile) {
    int kr0 = chunk * rows + tile * 64;
    {
      int r = t >> 3, c8 = (t & 7) * 8;  // 8 threads/row x 64 rows
      ushort8_t kv = *(const ushort8_t*)&Kp[(size_t)(kr0 + r) * QS + c8];
      ushort8_t vv = *(const ushort8_t*)&Vp[(size_t)(kr0 + r) * QS + c8];
      float* kd = &s_k[r * 65 + c8];
      float* vd = &s_v[r * 65 + c8];
      #pragma unroll
      for (int jj = 0; jj < 8; ++jj) {
        kd[jj] = b2f(kv[jj]);
        vd[jj] = b2f(vv[jj]);
      }
    }
    __syncthreads();
    {
      float kr[64];
      #pragma unroll
      for (int dd = 0; dd < 64; ++dd) kr[dd] = s_k[d * 65 + dd];
      for (int u = wv; u < U; u += 8) {
        float acc = 0.f;
        #pragma unroll
        for (int c = 0; c < 16; ++c) {
          float4 qv = *(const float4*)&s_q[u * 64 + c * 4];
          acc += qv.x * kr[c * 4] + qv.y * kr[c * 4 + 1] +
                 qv.z * kr[c * 4 + 2] + qv.w * kr[c * 4 + 3];
        }
        s_p[u * 64 + d] = acc;
      }
    }
    __syncthreads();
    for (int u = wv; u < U; u += 8) {
      float sv_ = s_p[u * 64 + d];
      float mx = wave_max64(sv_);
      float mold = s_m[u];
      float mnew = fmaxf(mold, mx);
      float e = expf(sv_ - mnew);
      float se = wave_sum64(e);
      s_p[u * 64 + d] = e;
      if (d == 0) {
        float alpha = expf(mold - mnew);
        s_a[u] = alpha;
        s_l[u] = s_l[u] * alpha + se;
        s_m[u] = mnew;
      }
    }
    __syncthreads();
    {
      float vr[64];
      #pragma unroll
      for (int k = 0; k < 64; ++k) vr[k] = s_v[k * 65 + d];
      int i = 0;
      for (int u = wv; u < U; u += 8, ++i) {
        float acc = 0.f;
        #pragma unroll
        for (int c = 0; c < 16; ++c) {
          float4 pv = *(const float4*)&s_p[u * 64 + c * 4];
          acc += pv.x * vr[c * 4] + pv.y * vr[c * 4 + 1] +
                 pv.z * vr[c * 4 + 2] + pv.w * vr[c * 4 + 3];
        }
        o[i] = o[i] * s_a[u] + acc;
      }
    }
    __syncthreads();
  }
  {
    int i = 0;
    for (int u = wv; u < U; u += 8, ++i) {
      float* pp = part + ((size_t)(bh * nchunk + chunk) * U + u) * 66;
      pp[d] = o[i];
      if (d == 0) { pp[64] = s_m[u]; pp[65] = s_l[u]; }
    }
  }
}

__global__ __launch_bounds__(64) void attn_merge_k(
    const float* __restrict__ part, const int* __restrict__ Mtop,
    ushort_t* __restrict__ ctx, int Lx, int U, int nchunk) {
  int bu = blockIdx.x;
  int u = bu % U, bh = bu / U;
  int h = bh & 7, b = bh >> 3;
  int d = threadIdx.x;  // 64
  float M = -INFINITY;
  for (int c = 0; c < nchunk; ++c)
    M = fmaxf(M, part[((size_t)(bh * nchunk + c) * U + u) * 66 + 64]);
  float L = 0.f, O = 0.f;
  for (int c = 0; c < nchunk; ++c) {
    const float* pp = part + ((size_t)(bh * nchunk + c) * U + u) * 66;
    float w = expf(pp[64] - M);
    L += pp[65] * w;
    O += pp[d] * w;
  }
  int qi = Mtop[bh * U + u];
  ctx[((size_t)b * Lx + qi) * DM + h * HD + d] = f2b(O / L);
}

// ---------------- distil im2col (circular, k=3) -> bf16, [t][c] layout -----
__global__ void im2col_k(const float* __restrict__ X,
                         ushort_t* __restrict__ A2) {
  int gid = blockIdx.x * 256 + threadIdx.x;  // 8192*3*128 ushort4 units
  int i4 = gid & 127;
  int rt = gid >> 7;
  int t = rt % 3, row = rt / 3;
  int b = row >> 11, l = row & 2047;
  int ls = (l + t - 1) & 2047;
  float4 v = ((const float4*)(X + ((size_t)b * 2048 + ls) * DM))[i4];
  ushort4 o;
  o.x = f2b(v.x); o.y = f2b(v.y); o.z = f2b(v.z); o.w = f2b(v.w);
  ((ushort4*)A2)[(size_t)row * 384 + t * 128 + i4] = o;
}

// ---------------- batch-norm stats: coalesced two-stage --------------------
__global__ __launch_bounds__(256) void bn1_k(const float* __restrict__ Y,
                                             float* __restrict__ ps,
                                             float* __restrict__ pq) {
  int blk = blockIdx.x;
  int t = threadIdx.x;
  float s0 = 0, q0 = 0, s1 = 0, q1 = 0;
  const float* base = Y + (size_t)blk * 256 * DM;
  for (int r = 0; r < 256; ++r) {
    float a = base[(size_t)r * DM + t];
    float b = base[(size_t)r * DM + t + 256];
    s0 += a; q0 += a * a; s1 += b; q1 += b * b;
  }
  ps[blk * DM + t] = s0; ps[blk * DM + t + 256] = s1;
  pq[blk * DM + t] = q0; pq[blk * DM + t + 256] = q1;
}
__global__ __launch_bounds__(512) void bn2_k(const float* __restrict__ ps,
                                             const float* __restrict__ pq,
                                             float* __restrict__ mu,
                                             float* __restrict__ var) {
  int t = threadIdx.x;
  float s = 0, q = 0;
  #pragma unroll
  for (int c = 0; c < 32; ++c) { s += ps[c * DM + t]; q += pq[c * DM + t]; }
  float m = s * (1.0f / 8192.f);
  mu[t] = m;
  var[t] = q * (1.0f / 8192.f) - m * m;
}

// fused bn+elu+maxpool(k=3,s=2,pad=1)
__global__ void bnpool_k(const float* __restrict__ Y,
                         const float* __restrict__ mu,
                         const float* __restrict__ var,
                         const float* __restrict__ g,
                         const float* __restrict__ be, float* __restrict__ O,
                         ushort_t* __restrict__ Ob) {
  size_t i = (size_t)blockIdx.x * 256 + threadIdx.x;  // 4*1024*512
  int c = (int)(i & 511);
  size_t row = i >> 9;
  int lo = (int)(row & 1023);
  int b = (int)(row >> 10);
  float sc = g[c] / sqrtf(var[c] + 1e-5f);
  float sh = be[c] - mu[c] * sc;
  int l0 = 2 * lo - 1;
  float m = -INFINITY;
  #pragma unroll
  for (int tt = 0; tt < 3; ++tt) {
    int l = l0 + tt;
    if (l >= 0 && l < 2048) {
      float v = Y[((size_t)b * 2048 + l) * DM + c] * sc + sh;
      v = v > 0.f ? v : expm1f(v);
      m = fmaxf(m, v);
    }
  }
  O[i] = m;
  Ob[i] = f2b(m);
}

// ---------------------------------------------------------------------------
extern "C" void kernel_launch(void* const* d_in, const int* in_sizes, int n_in,
                              void* d_out, int out_size, void* d_ws,
                              size_t ws_size, hipStream_t stream) {
  (void)in_sizes; (void)n_in; (void)out_size; (void)ws_size;
  const float* x_enc  = (const float*)d_in[0];
  const float* tok_w  = (const float*)d_in[1];
  const float* Wq     = (const float*)d_in[2];
  const float* bq     = (const float*)d_in[3];
  const float* Wk     = (const float*)d_in[4];
  const float* bk     = (const float*)d_in[5];
  const float* Wv     = (const float*)d_in[6];
  const float* bv     = (const float*)d_in[7];
  const float* Wo     = (const float*)d_in[8];
  const float* bo     = (const float*)d_in[9];
  const float* W1     = (const float*)d_in[10];
  const float* b1     = (const float*)d_in[11];
  const float* W2     = (const float*)d_in[12];
  const float* b2     = (const float*)d_in[13];
  const float* ln1_g  = (const float*)d_in[14];
  const float* ln1_b  = (const float*)d_in[15];
  const float* ln2_g  = (const float*)d_in[16];
  const float* ln2_b  = (const float*)d_in[17];
  const float* conv_w = (const float*)d_in[18];
  const float* conv_b = (const float*)d_in[19];
  const float* bn_g   = (const float*)d_in[20];
  const float* bn_b   = (const float*)d_in[21];
  const float* normf_g = (const float*)d_in[22];
  const float* normf_b = (const float*)d_in[23];
  const float* proj_w = (const float*)d_in[24];
  const float* proj_b = (const float*)d_in[25];
  float* out = (float*)d_out;
  float* ws = (float*)d_ws;

  // ---- fp32 workspace layout (float offsets) ----
  float* X    = ws;                    // 4,194,304
  float* SCR  = ws + 4194304;          // 12,582,912 (final-LN scratch)
  ushort_t* CTXb = (ushort_t*)(ws + 16777216);  // bf16 ctx
  float* Y2   = ws + 20971520;         // 4,194,304 (attn partials / conv out)
  float* Mb   = ws + 25165824;         // 65,536
  float* MV   = ws + 25231360;         // 2,048
  float* MVP  = ws + 25233408;         // 32,768
  float* BNps = ws + 25266176;         // 16,384
  float* BNpq = ws + 25282560;         // 16,384
  float* BNmu = ws + 25298944;         // 512
  float* BNvr = ws + 25299456;         // 512
  float* ZB   = ws + 25299968;         // 512 (zero bias)
  float* BQKV = ws + 25300480;         // 3,072 (concat qkv bias, 2 layers)
  int*   IDX  = (int*)(ws + 25303552); // 81,920
  int*   MT   = (int*)(ws + 25385472); // 1,280
  // ---- bf16 workspace ----
  ushort_t* U0   = (ushort_t*)(ws + 25386752);
  ushort_t* Xb   = U0;                 // 4,194,304
  ushort_t* Hb   = U0 + 4194304;       // 16,777,216 (FFN hidden / im2col)
  ushort_t* QKVb = Hb;                 // alias: bf16 QKV — live QKV-GEMM ->
                                       // attn, before FFN uses Hb
  ushort_t* Wqkvb= U0 + 20971520;      // 1,572,864
  ushort_t* Wob  = U0 + 22544384;      // 524,288
  ushort_t* W1b  = U0 + 23068672;      // 2,097,152
  ushort_t* W2b  = U0 + 25165824;      // 2,097,152
  ushort_t* Cwb  = U0 + 27262976;      // 786,432
  ushort_t* Twb  = U0 + 28049408;      // 49,152
  ushort_t* Atok = U0 + 28098560;      // 786,432
  float* PEf = ws + 39829248;          // 1,048,576 (PE table)

  // ---- fused preamble ----
  castqkv_k<<<1536, 256, 0, stream>>>(Wq, Wk, Wv, Wqkvb);
  castw3_k<<<4656, 256, 0, stream>>>(Wo, W1, W2, tok_w, Wob, W1b, W2b, Twb);
  castw_conv_k<<<3072, 256, 0, stream>>>(conv_w, Cwb);
  setup_small_k<<<14, 256, 0, stream>>>(bq, bk, bv, ZB, BQKV);
  pe_k<<<4096, 256, 0, stream>>>(PEf);
  im2col_tok_k<<<3072, 256, 0, stream>>>(x_enc, Atok);

  // token embedding GEMM (+PE): X=4, Y=64 -> 256 blocks
  mgemm_k<0, 2, 1><<<256, 256, 0, stream>>>(
      Atok, Twb, ZB, X, Xb, PEf, 4, DM, 96);

  for (int layer = 0; layer < 2; ++layer) {
    const int Lx = (layer == 0) ? 2048 : 1024;
    const int U  = (layer == 0) ? 40 : 35;
    const int M  = NB * Lx;
    const int Yt = M / 128;
    const int NCH = 8;

    uint32_t kl0, kl1, s0, s1;
    threefry2x32(0u, 42u, 0u, (uint32_t)layer, &kl0, &kl1);
    threefry2x32(kl0, kl1, 0u, 1u, &s0, &s1);
    int nidx = Lx * U;
    gen_idx_k<<<(nidx + 255) / 256, 256, 0, stream>>>(IDX, nidx, Lx - 1, s0, s1);

    // fused QKV GEMM: bf16-only output, XCD-swizzled
    mgemm_k<0, 1, 0><<<12 * Yt, 256, 0, stream>>>(
        Xb, Wqkvb + (size_t)layer * 786432, BQKV + layer * 1536, nullptr, QKVb,
        nullptr, 12, QS, DM);

    // ProbSparse attention (all bf16 QKV)
    if (layer == 0)
      qk_m_k<40><<<Lx, 256, 0, stream>>>(QKVb, IDX, Mb, Lx);
    else
      qk_m_k<35><<<Lx, 256, 0, stream>>>(QKVb, IDX, Mb, Lx);
    topk_k<<<NB * NH, 1024, 0, stream>>>(Mb, MT, Lx, U);
    meanv1_k<<<NB * 16, 512, 0, stream>>>(QKVb, MVP, Lx);
    meanv2_k<<<NB, 512, 0, stream>>>(MVP, MV, Lx);
    fillctx_k<<<(M * DM / 4) / 256, 256, 0, stream>>>(CTXb, MV, Lx);
    attn_flash_k<<<NB * NH * NCH, 512, 0, stream>>>(QKVb, MT, Y2, Lx, U, NCH);
    attn_merge_k<<<NB * NH * U, 64, 0, stream>>>(Y2, MT, CTXb, Lx, U, NCH);

    // output projection + residual + LN1 (emits bf16 for FFN1)
    mgemm_k<0, 0, 0><<<4 * Yt, 256, 0, stream>>>(
        CTXb, Wob + (size_t)layer * 262144, bo + layer * DM, Y2, nullptr,
        nullptr, 4, DM, DM);
    ln_k<<<M, 128, 0, stream>>>(X, Y2, ln1_g + layer * DM, ln1_b + layer * DM, X, Xb);

    // FFN (GELU fused; hidden kept in bf16); LN2 emits bf16
    mgemm_k<1, 1, 0><<<16 * Yt, 256, 0, stream>>>(
        Xb, W1b + (size_t)layer * 1048576, b1 + layer * 2048, nullptr, Hb,
        nullptr, 16, 2048, DM);
    mgemm_k<0, 0, 0><<<4 * Yt, 256, 0, stream>>>(
        Hb, W2b + (size_t)layer * 1048576, b2 + layer * DM, Y2, nullptr,
        nullptr, 4, DM, 2048);
    ln_k<<<M, 128, 0, stream>>>(X, Y2, ln2_g + layer * DM, ln2_b + layer * DM, X, Xb);

    if (layer == 0) {
      im2col_k<<<12288, 256, 0, stream>>>(X, Hb);
      mgemm_k<0, 0, 0><<<4 * 64, 256, 0, stream>>>(
          Hb, Cwb, conv_b, Y2, nullptr, nullptr, 4, DM, 1536);
      bn1_k<<<32, 256, 0, stream>>>(Y2, BNps, BNpq);
      bn2_k<<<1, 512, 0, stream>>>(BNps, BNpq, BNmu, BNvr);
      bnpool_k<<<(NB * 1024 * 512) / 256, 256, 0, stream>>>(
          Y2, BNmu, BNvr, bn_g, bn_b, X, Xb);
    }
  }

  // final LN + projection (N=32, fp32)
  ln_k<<<NB * 1024, 128, 0, stream>>>(X, nullptr, normf_g, normf_b, SCR, nullptr);
  gemm_k<<<dim3(1, 4096 / 64), 256, 0, stream>>>(SCR, proj_w, proj_b, out,
                                                 4096, 32, DM);
}

// Round 11
// 804.662 us; speedup vs baseline: 1.1734x; 1.1734x over previous
//
#include <hip/hip_runtime.h>
#include <cstdint>
#include <cmath>

// ---------------------------------------------------------------------------
// Informer encoder forward (B=4, L=2048, ENC_IN=32, D_MODEL=512, D_FF=2048,
// E_LAYERS=2, H=8, FACTOR=5).
// Round 11: rank-based top-k redistributed — one candidate per thread over
// bh x (Lx/256) blocks (O(L^2) work now spread across all CUs, ~7 us).
// ---------------------------------------------------------------------------

#define NB 4
#define DM 512
#define NH 8
#define HD 64
#define QS 1536  // QKV row stride

typedef unsigned short ushort_t;
typedef __bf16 bf16x8 __attribute__((ext_vector_type(8)));
typedef float floatx4 __attribute__((ext_vector_type(4)));
typedef unsigned short ushort8_t __attribute__((ext_vector_type(8)));

__device__ inline ushort_t f2b(float f) {
  uint32_t u = __float_as_uint(f);
  uint32_t r = (u + 0x7fffu + ((u >> 16) & 1u)) >> 16;
  return (ushort_t)r;
}
__device__ inline float b2f(ushort_t u) {
  return __uint_as_float((uint32_t)u << 16);
}

// ---------------- fused weight casts ---------------------------------------
__global__ void castqkv_k(const float* __restrict__ Wq,
                          const float* __restrict__ Wk,
                          const float* __restrict__ Wv,
                          ushort_t* __restrict__ out) {
  int gid = blockIdx.x * 256 + threadIdx.x;  // 393216 float4 units
  if (gid >= 393216) return;
  int ly = gid / 196608, r4 = gid - ly * 196608;
  int r = r4 >> 7, c4 = r4 & 127;
  int sel = r >> 9, srow = r & 511;
  const float* src = (sel == 0 ? Wq : sel == 1 ? Wk : Wv) + ly * 262144 +
                     srow * 512 + c4 * 4;
  float4 v = *(const float4*)src;
  ushort4 o;
  o.x = f2b(v.x); o.y = f2b(v.y); o.z = f2b(v.z); o.w = f2b(v.w);
  ((ushort4*)out)[ly * 196608 + r * 128 + c4] = o;
}

__global__ void castw3_k(const float* __restrict__ Wo,
                         const float* __restrict__ W1,
                         const float* __restrict__ W2,
                         const float* __restrict__ tw,
                         ushort_t* __restrict__ oWo, ushort_t* __restrict__ oW1,
                         ushort_t* __restrict__ oW2, ushort_t* __restrict__ otw) {
  int gid = blockIdx.x * 256 + threadIdx.x;  // 1,191,936 float4 units
  if (gid >= 1191936) return;
  const float* src;
  ushort4* dst;
  int i;
  if (gid < 131072) { src = Wo; dst = (ushort4*)oWo; i = gid; }
  else if (gid < 655360) { src = W1; dst = (ushort4*)oW1; i = gid - 131072; }
  else if (gid < 1179648) { src = W2; dst = (ushort4*)oW2; i = gid - 655360; }
  else { src = tw; dst = (ushort4*)otw; i = gid - 1179648; }
  float4 v = ((const float4*)src)[i];
  ushort4 o;
  o.x = f2b(v.x); o.y = f2b(v.y); o.z = f2b(v.z); o.w = f2b(v.w);
  dst[i] = o;
}

__global__ void castw_conv_k(const float* __restrict__ in,
                             ushort_t* __restrict__ out) {
  int gid = blockIdx.x * 256 + threadIdx.x;  // 512*1536
  int d = gid / 1536, r = gid - d * 1536;
  int t = r >> 9, i = r & 511;
  out[gid] = f2b(in[d * 1536 + i * 3 + t]);
}

__global__ void setup_small_k(const float* __restrict__ bq,
                              const float* __restrict__ bk,
                              const float* __restrict__ bv,
                              float* __restrict__ ZB,
                              float* __restrict__ BQKV) {
  int gid = blockIdx.x * 256 + threadIdx.x;  // 3584
  if (gid >= 3584) return;
  if (gid < 512) { ZB[gid] = 0.f; return; }
  int g = gid - 512;
  int layer = g / 1536, r = g - layer * 1536;
  float v;
  if (r < 512) v = bq[layer * 512 + r];
  else if (r < 1024) v = bk[layer * 512 + r - 512];
  else v = bv[layer * 512 + r - 1024];
  BQKV[g] = v;
}

__host__ __device__ inline void threefry2x32(uint32_t k0, uint32_t k1,
                                             uint32_t c0, uint32_t c1,
                                             uint32_t* o0, uint32_t* o1) {
  uint32_t ks0 = k0, ks1 = k1, ks2 = k0 ^ k1 ^ 0x1BD11BDAu;
  uint32_t x0 = c0 + ks0;
  uint32_t x1 = c1 + ks1;
  const uint32_t rotA[4] = {13u, 15u, 26u, 6u};
  const uint32_t rotB[4] = {17u, 29u, 16u, 24u};
  uint32_t ks[3] = {ks0, ks1, ks2};
  #pragma unroll
  for (int i = 0; i < 5; ++i) {
    const uint32_t* r = (i & 1) ? rotB : rotA;
    #pragma unroll
    for (int j = 0; j < 4; ++j) {
      x0 += x1;
      x1 = (x1 << r[j]) | (x1 >> (32u - r[j]));
      x1 ^= x0;
    }
    x0 += ks[(i + 1) % 3];
    x1 += ks[(i + 2) % 3] + (uint32_t)(i + 1);
  }
  *o0 = x0; *o1 = x1;
}

__global__ void gen_idx_k(int* __restrict__ idx, int n, int mask,
                          uint32_t k0, uint32_t k1) {
  int i = blockIdx.x * 256 + threadIdx.x;
  if (i < n) {
    uint32_t o0, o1;
    threefry2x32(k0, k1, 0u, (uint32_t)i, &o0, &o1);
    idx[i] = (int)((o0 ^ o1) & (uint32_t)mask);
  }
}

__device__ inline float wave_sum64(float v) {
  #pragma unroll
  for (int o = 32; o > 0; o >>= 1) v += __shfl_xor(v, o, 64);
  return v;
}
__device__ inline float wave_max64(float v) {
  #pragma unroll
  for (int o = 32; o > 0; o >>= 1) v = fmaxf(v, __shfl_xor(v, o, 64));
  return v;
}

// ---------------- positional-encoding table (2048 x 512) -------------------
__global__ void pe_k(float* __restrict__ pe) {
  int i = blockIdx.x * 256 + threadIdx.x;  // 1,048,576
  int d = i & 511, l = i >> 9;
  int j2 = d & ~1;
  float div = expf((float)j2 * -1.7988946039e-2f);  // -ln(10000)/512
  float ang = (float)l * div;
  pe[i] = (d & 1) ? cosf(ang) : sinf(ang);
}

// ---------------- im2col for token conv: (B*L, 96) bf16 --------------------
__global__ void im2col_tok_k(const float* __restrict__ xe,
                             ushort_t* __restrict__ A) {
  int gid = blockIdx.x * 256 + threadIdx.x;  // 8192*96
  int col = gid % 96;
  int row = gid / 96;
  int c = col / 3, t = col - c * 3;
  int b = row >> 11, l = row & 2047;
  int ls = (l + t - 1) & 2047;
  A[gid] = f2b(xe[((size_t)b * 2048 + ls) * 32 + c]);
}

// ---------------- bf16 MFMA GEMM with XCD swizzle --------------------------
__device__ inline void gload16(const ushort_t* g, ushort_t* l) {
  __builtin_amdgcn_global_load_lds(
      (const __attribute__((address_space(1))) unsigned int*)(const void*)g,
      (__attribute__((address_space(3))) unsigned int*)(void*)l, 16, 0, 0);
}

template <int GELU, int OMODE, int ADDPE>  // OMODE: 0 f32, 1 bf16, 2 both
__global__ __launch_bounds__(256) void mgemm_k(
    const ushort_t* __restrict__ A, const ushort_t* __restrict__ W,
    const float* __restrict__ bias, float* __restrict__ Cf,
    ushort_t* __restrict__ Cb, const float* __restrict__ pe,
    int X, int ldc, int K) {
  __shared__ ushort_t As[128 * 32];
  __shared__ ushort_t Bs[128 * 32];
  int id = blockIdx.x;
  int cc = id & 7, j = id >> 3;
  int bx = j % X;
  int by = (j / X) * 8 + cc;
  int m0 = by * 128, n0 = bx * 128;
  int t = threadIdx.x;
  int lane = t & 63, wv = t >> 6;
  int sr = lane >> 2, sc = (lane & 3) * 8;
  int ra0 = wv * 32 + sr, ra1 = ra0 + 16;
  const ushort_t* gA0 = A + (size_t)(m0 + ra0) * K + sc;
  const ushort_t* gA1 = A + (size_t)(m0 + ra1) * K + sc;
  const ushort_t* gB0 = W + (size_t)(n0 + ra0) * K + sc;
  const ushort_t* gB1 = W + (size_t)(n0 + ra1) * K + sc;
  ushort_t* lA0 = As + wv * 1024;
  ushort_t* lA1 = lA0 + 512;
  ushort_t* lB0 = Bs + wv * 1024;
  ushort_t* lB1 = lB0 + 512;

  int quad = lane >> 4, lr = lane & 15;
  int wm = wv >> 1, wn = wv & 1;

  floatx4 acc[4][4] = {};
  for (int ks = 0; ks < K; ks += 32) {
    gload16(gA0, lA0);
    gload16(gA1, lA1);
    gload16(gB0, lB0);
    gload16(gB1, lB1);
    gA0 += 32; gA1 += 32; gB0 += 32; gB1 += 32;
    __syncthreads();
    bf16x8 av[4], bv[4];
    #pragma unroll
    for (int mt = 0; mt < 4; ++mt)
      av[mt] = *(const bf16x8*)&As[(wm * 64 + mt * 16 + lr) * 32 + quad * 8];
    #pragma unroll
    for (int nt = 0; nt < 4; ++nt)
      bv[nt] = *(const bf16x8*)&Bs[(wn * 64 + nt * 16 + lr) * 32 + quad * 8];
    #pragma unroll
    for (int mt = 0; mt < 4; ++mt)
      #pragma unroll
      for (int nt = 0; nt < 4; ++nt)
        acc[mt][nt] = __builtin_amdgcn_mfma_f32_16x16x32_bf16(
            av[mt], bv[nt], acc[mt][nt], 0, 0, 0);
    __syncthreads();
  }
  #pragma unroll
  for (int nt = 0; nt < 4; ++nt) {
    int col = n0 + wn * 64 + nt * 16 + lr;
    float bsv = bias[col];
    #pragma unroll
    for (int mt = 0; mt < 4; ++mt) {
      int row0 = m0 + wm * 64 + mt * 16 + quad * 4;
      #pragma unroll
      for (int r = 0; r < 4; ++r) {
        int row = row0 + r;
        float v = acc[mt][nt][r] + bsv;
        if (ADDPE) v += pe[(size_t)(row & 2047) * ldc + col];
        if (GELU) v = 0.5f * v * (1.0f + erff(v * 0.70710678118654752f));
        if (OMODE == 0 || OMODE == 2) Cf[(size_t)row * ldc + col] = v;
        if (OMODE == 1 || OMODE == 2) Cb[(size_t)row * ldc + col] = f2b(v);
      }
    }
  }
}

// ---------------- fp32 fallback GEMM (final projection, N=32) --------------
__global__ __launch_bounds__(256) void gemm_k(
    const float* __restrict__ A, const float* __restrict__ W,
    const float* __restrict__ bias, float* __restrict__ C,
    int M, int N, int K) {
  __shared__ float As2[16][64 + 4];
  __shared__ float Ws2[16][64 + 4];
  int m0 = blockIdx.y * 64, n0 = blockIdx.x * 64;
  int t = threadIdx.x;
  int tx = t & 15, ty = t >> 4;
  float acc[4][4] = {};
  for (int k0 = 0; k0 < K; k0 += 16) {
    #pragma unroll
    for (int i = 0; i < 4; ++i) {
      int li = t + i * 256;
      int m = li >> 4, kk = li & 15;
      As2[kk][m] = A[(size_t)(m0 + m) * K + k0 + kk];
    }
    #pragma unroll
    for (int i = 0; i < 4; ++i) {
      int li = t + i * 256;
      int n = li >> 4, kk = li & 15;
      int gn = n0 + n;
      Ws2[kk][n] = (gn < N) ? W[(size_t)gn * K + k0 + kk] : 0.0f;
    }
    __syncthreads();
    #pragma unroll
    for (int kk = 0; kk < 16; ++kk) {
      float4 avv = *(const float4*)&As2[kk][ty * 4];
      float4 bvv = *(const float4*)&Ws2[kk][tx * 4];
      float a[4] = {avv.x, avv.y, avv.z, avv.w};
      float bb[4] = {bvv.x, bvv.y, bvv.z, bvv.w};
      #pragma unroll
      for (int i = 0; i < 4; ++i)
        #pragma unroll
        for (int j = 0; j < 4; ++j) acc[i][j] += a[i] * bb[j];
    }
    __syncthreads();
  }
  #pragma unroll
  for (int i = 0; i < 4; ++i) {
    int m = m0 + ty * 4 + i;
    #pragma unroll
    for (int j = 0; j < 4; ++j) {
      int n = n0 + tx * 4 + j;
      if (n < N) C[(size_t)m * N + n] = acc[i][j] + bias[n];
    }
  }
}

// ---------------- LayerNorm (+optional residual, +optional bf16 copy) ------
__global__ __launch_bounds__(128) void ln_k(
    const float* __restrict__ A, const float* __restrict__ Bres,
    const float* __restrict__ g, const float* __restrict__ be,
    float* __restrict__ O, ushort_t* __restrict__ Ob) {
  int r = blockIdx.x, t = threadIdx.x;
  __shared__ float lds[2];
  float4 v = ((const float4*)(A + (size_t)r * DM))[t];
  if (Bres) {
    float4 u = ((const float4*)(Bres + (size_t)r * DM))[t];
    v.x += u.x; v.y += u.y; v.z += u.z; v.w += u.w;
  }
  float s = wave_sum64(v.x + v.y + v.z + v.w);
  int w = t >> 6;
  if ((t & 63) == 0) lds[w] = s;
  __syncthreads();
  float mu = (lds[0] + lds[1]) * (1.0f / 512.0f);
  __syncthreads();
  float dx = v.x - mu, dy = v.y - mu, dz = v.z - mu, dw = v.w - mu;
  float sq = wave_sum64(dx * dx + dy * dy + dz * dz + dw * dw);
  if ((t & 63) == 0) lds[w] = sq;
  __syncthreads();
  float var = (lds[0] + lds[1]) * (1.0f / 512.0f);
  float inv = 1.0f / sqrtf(var + 1e-5f);
  float4 gv = ((const float4*)g)[t];
  float4 bv = ((const float4*)be)[t];
  float4 o;
  o.x = dx * inv * gv.x + bv.x;
  o.y = dy * inv * gv.y + bv.y;
  o.z = dz * inv * gv.z + bv.z;
  o.w = dw * inv * gv.w + bv.w;
  ((float4*)(O + (size_t)r * DM))[t] = o;
  if (Ob) {
    ushort4 ob;
    ob.x = f2b(o.x); ob.y = f2b(o.y); ob.z = f2b(o.z); ob.w = f2b(o.w);
    ((ushort4*)(Ob + (size_t)r * DM))[t] = ob;
  }
}

// ---------------- M[b,h,l]: one wave per (b,l), all-bf16 QKV ---------------
template <int UU>
__global__ __launch_bounds__(256) void qk_m_k(
    const ushort_t* __restrict__ QKVb, const int* __restrict__ idx,
    float* __restrict__ Mout, int Lx) {
  int l = blockIdx.x;
  int b = threadIdx.x >> 6;  // wave = batch
  int lane = threadIdx.x & 63;
  const ushort_t* qp = QKVb + ((size_t)b * Lx + l) * QS + lane * 8;
  float q[8];
  {
    ushort8_t qv = *(const ushort8_t*)qp;
    #pragma unroll
    for (int c = 0; c < 8; ++c) q[c] = b2f(qv[c]);
  }
  const ushort_t* Kbase = QKVb + (size_t)b * Lx * QS + 512 + lane * 8;
  const int* ip = idx + (size_t)l * UU;
  float maxv = -INFINITY, sumv = 0.f;
  #pragma unroll
  for (int u0 = 0; u0 < UU; u0 += 8) {
    ushort8_t kv[8];
    #pragma unroll
    for (int j = 0; j < 8; ++j) {
      if (u0 + j < UU)
        kv[j] = *(const ushort8_t*)(Kbase + (size_t)ip[u0 + j] * QS);
    }
    #pragma unroll
    for (int j = 0; j < 8; ++j) {
      if (u0 + j < UU) {
        float p = 0.f;
        #pragma unroll
        for (int c = 0; c < 8; ++c) p += q[c] * b2f(kv[j][c]);
        p += __shfl_xor(p, 1, 64);
        p += __shfl_xor(p, 2, 64);
        p += __shfl_xor(p, 4, 64);
        maxv = fmaxf(maxv, p);
        sumv += p;
      }
    }
  }
  if ((lane & 7) == 0) {
    int h = lane >> 3;
    Mout[(size_t)(b * 8 + h) * Lx + l] = maxv - sumv / (float)Lx;
  }
}

// ---------------- rank-based top-U, chunked (exact JAX tie-breaking) -------
// grid = bh * (Lx/256); 256 threads; thread ranks ONE candidate against the
// full M row staged in LDS. rank < U => write at position rank.
__global__ __launch_bounds__(256) void topk_k(
    const float* __restrict__ Mbuf, int* __restrict__ Mtop, int Lx, int U) {
  int nch = Lx >> 8;
  int bh = blockIdx.x / nch, ch = blockIdx.x % nch;
  const float* m = Mbuf + (size_t)bh * Lx;
  __shared__ float sm[2048];
  int t = threadIdx.x;
  for (int i = t; i < Lx; i += 256) sm[i] = m[i];
  __syncthreads();
  int i0 = (ch << 8) + t;
  float v0 = sm[i0];
  int r0 = 0;
  for (int j = 0; j < Lx; j += 4) {
    float4 mj = *(const float4*)&sm[j];
    r0 += (mj.x > v0) || (mj.x == v0 && (j + 0) < i0);
    r0 += (mj.y > v0) || (mj.y == v0 && (j + 1) < i0);
    r0 += (mj.z > v0) || (mj.z == v0 && (j + 2) < i0);
    r0 += (mj.w > v0) || (mj.w == v0 && (j + 3) < i0);
  }
  if (r0 < U) Mtop[bh * U + r0] = i0;
}

// ---------------- meanV from bf16 QKV (V at +1024) -------------------------
__global__ __launch_bounds__(512) void meanv1_k(const ushort_t* __restrict__ QKVb,
                                                float* __restrict__ part,
                                                int Lx) {
  int b = blockIdx.x >> 4, chunk = blockIdx.x & 15;
  int rows = Lx >> 4;
  int t = threadIdx.x;  // 512
  const ushort_t* vp =
      QKVb + ((size_t)b * Lx + (size_t)chunk * rows) * QS + 1024 + t;
  float s = 0.f;
  for (int l = 0; l < rows; ++l) s += b2f(vp[(size_t)l * QS]);
  part[(size_t)blockIdx.x * DM + t] = s;
}
__global__ __launch_bounds__(512) void meanv2_k(const float* __restrict__ part,
                                                float* __restrict__ mv,
                                                int Lx) {
  int b = blockIdx.x, t = threadIdx.x;
  float s = 0.f;
  #pragma unroll
  for (int c = 0; c < 16; ++c) s += part[(size_t)(b * 16 + c) * DM + t];
  mv[b * DM + t] = s / (float)Lx;
}

__global__ void fillctx_k(ushort_t* __restrict__ ctx,
                          const float* __restrict__ mv, int Lx) {
  size_t i4 = (size_t)blockIdx.x * 256 + threadIdx.x;
  int col4 = (int)(i4 & 127);
  size_t row = i4 >> 7;
  int b = (int)(row / (size_t)Lx);
  const float* m = mv + b * DM + col4 * 4;
  ushort4 o;
  o.x = f2b(m[0]); o.y = f2b(m[1]); o.z = f2b(m[2]); o.w = f2b(m[3]);
  ((ushort4*)ctx)[i4] = o;
}

// ---------------- flash split-K attention (bf16 QKV) -----------------------
__global__ __launch_bounds__(512) void attn_flash_k(
    const ushort_t* __restrict__ QKVb, const int* __restrict__ Mtop,
    float* __restrict__ part, int Lx, int U, int nchunk) {
  int blk = blockIdx.x;
  int chunk = blk % nchunk, bh = blk / nchunk;
  int h = bh & 7, b = bh >> 3;
  int rows = Lx / nchunk;
  int ntile = rows >> 6;
  __shared__ float s_q[40 * 64];
  __shared__ float s_k[64 * 65];
  __shared__ float s_v[64 * 65];
  __shared__ float s_p[40 * 64];
  __shared__ float s_m[40], s_l[40], s_a[40];
  int t = threadIdx.x;
  int d = t & 63, wv = t >> 6;

  for (int i = t; i < U * 64; i += 512) {
    int u = i >> 6, dd = i & 63;
    int qi = Mtop[bh * U + u];
    s_q[i] = b2f(QKVb[((size_t)b * Lx + qi) * QS + h * HD + dd]) * 0.125f;
  }
  if (t < U) { s_m[t] = -INFINITY; s_l[t] = 0.f; s_a[t] = 0.f; }
  float o[5] = {0.f, 0.f, 0.f, 0.f, 0.f};
  __syncthreads();

  const ushort_t* Kp = QKVb + (size_t)b * Lx * QS + 512 + h * HD;
  const ushort_t* Vp = QKVb + (size_t)b * Lx * QS + 1024 + h * HD;

  for (int tile = 0; tile < ntile; ++tile) {
    int kr0 = chunk * rows + tile * 64;
    {
      int r = t >> 3, c8 = (t & 7) * 8;  // 8 threads/row x 64 rows
      ushort8_t kv = *(const ushort8_t*)&Kp[(size_t)(kr0 + r) * QS + c8];
      ushort8_t vv = *(const ushort8_t*)&Vp[(size_t)(kr0 + r) * QS + c8];
      float* kd = &s_k[r * 65 + c8];
      float* vd = &s_v[r * 65 + c8];
      #pragma unroll
      for (int jj = 0; jj < 8; ++jj) {
        kd[jj] = b2f(kv[jj]);
        vd[jj] = b2f(vv[jj]);
      }
    }
    __syncthreads();
    {
      float kr[64];
      #pragma unroll
      for (int dd = 0; dd < 64; ++dd) kr[dd] = s_k[d * 65 + dd];
      for (int u = wv; u < U; u += 8) {
        float acc = 0.f;
        #pragma unroll
        for (int c = 0; c < 16; ++c) {
          float4 qv = *(const float4*)&s_q[u * 64 + c * 4];
          acc += qv.x * kr[c * 4] + qv.y * kr[c * 4 + 1] +
                 qv.z * kr[c * 4 + 2] + qv.w * kr[c * 4 + 3];
        }
        s_p[u * 64 + d] = acc;
      }
    }
    __syncthreads();
    for (int u = wv; u < U; u += 8) {
      float sv_ = s_p[u * 64 + d];
      float mx = wave_max64(sv_);
      float mold = s_m[u];
      float mnew = fmaxf(mold, mx);
      float e = expf(sv_ - mnew);
      float se = wave_sum64(e);
      s_p[u * 64 + d] = e;
      if (d == 0) {
        float alpha = expf(mold - mnew);
        s_a[u] = alpha;
        s_l[u] = s_l[u] * alpha + se;
        s_m[u] = mnew;
      }
    }
    __syncthreads();
    {
      float vr[64];
      #pragma unroll
      for (int k = 0; k < 64; ++k) vr[k] = s_v[k * 65 + d];
      int i = 0;
      for (int u = wv; u < U; u += 8, ++i) {
        float acc = 0.f;
        #pragma unroll
        for (int c = 0; c < 16; ++c) {
          float4 pv = *(const float4*)&s_p[u * 64 + c * 4];
          acc += pv.x * vr[c * 4] + pv.y * vr[c * 4 + 1] +
                 pv.z * vr[c * 4 + 2] + pv.w * vr[c * 4 + 3];
        }
        o[i] = o[i] * s_a[u] + acc;
      }
    }
    __syncthreads();
  }
  {
    int i = 0;
    for (int u = wv; u < U; u += 8, ++i) {
      float* pp = part + ((size_t)(bh * nchunk + chunk) * U + u) * 66;
      pp[d] = o[i];
      if (d == 0) { pp[64] = s_m[u]; pp[65] = s_l[u]; }
    }
  }
}

__global__ __launch_bounds__(64) void attn_merge_k(
    const float* __restrict__ part, const int* __restrict__ Mtop,
    ushort_t* __restrict__ ctx, int Lx, int U, int nchunk) {
  int bu = blockIdx.x;
  int u = bu % U, bh = bu / U;
  int h = bh & 7, b = bh >> 3;
  int d = threadIdx.x;  // 64
  float M = -INFINITY;
  for (int c = 0; c < nchunk; ++c)
    M = fmaxf(M, part[((size_t)(bh * nchunk + c) * U + u) * 66 + 64]);
  float L = 0.f, O = 0.f;
  for (int c = 0; c < nchunk; ++c) {
    const float* pp = part + ((size_t)(bh * nchunk + c) * U + u) * 66;
    float w = expf(pp[64] - M);
    L += pp[65] * w;
    O += pp[d] * w;
  }
  int qi = Mtop[bh * U + u];
  ctx[((size_t)b * Lx + qi) * DM + h * HD + d] = f2b(O / L);
}

// ---------------- distil im2col (circular, k=3) -> bf16, [t][c] layout -----
__global__ void im2col_k(const float* __restrict__ X,
                         ushort_t* __restrict__ A2) {
  int gid = blockIdx.x * 256 + threadIdx.x;  // 8192*3*128 ushort4 units
  int i4 = gid & 127;
  int rt = gid >> 7;
  int t = rt % 3, row = rt / 3;
  int b = row >> 11, l = row & 2047;
  int ls = (l + t - 1) & 2047;
  float4 v = ((const float4*)(X + ((size_t)b * 2048 + ls) * DM))[i4];
  ushort4 o;
  o.x = f2b(v.x); o.y = f2b(v.y); o.z = f2b(v.z); o.w = f2b(v.w);
  ((ushort4*)A2)[(size_t)row * 384 + t * 128 + i4] = o;
}

// ---------------- batch-norm stats: coalesced two-stage --------------------
__global__ __launch_bounds__(256) void bn1_k(const float* __restrict__ Y,
                                             float* __restrict__ ps,
                                             float* __restrict__ pq) {
  int blk = blockIdx.x;
  int t = threadIdx.x;
  float s0 = 0, q0 = 0, s1 = 0, q1 = 0;
  const float* base = Y + (size_t)blk * 256 * DM;
  for (int r = 0; r < 256; ++r) {
    float a = base[(size_t)r * DM + t];
    float b = base[(size_t)r * DM + t + 256];
    s0 += a; q0 += a * a; s1 += b; q1 += b * b;
  }
  ps[blk * DM + t] = s0; ps[blk * DM + t + 256] = s1;
  pq[blk * DM + t] = q0; pq[blk * DM + t + 256] = q1;
}
__global__ __launch_bounds__(512) void bn2_k(const float* __restrict__ ps,
                                             const float* __restrict__ pq,
                                             float* __restrict__ mu,
                                             float* __restrict__ var) {
  int t = threadIdx.x;
  float s = 0, q = 0;
  #pragma unroll
  for (int c = 0; c < 32; ++c) { s += ps[c * DM + t]; q += pq[c * DM + t]; }
  float m = s * (1.0f / 8192.f);
  mu[t] = m;
  var[t] = q * (1.0f / 8192.f) - m * m;
}

// fused bn+elu+maxpool(k=3,s=2,pad=1)
__global__ void bnpool_k(const float* __restrict__ Y,
                         const float* __restrict__ mu,
                         const float* __restrict__ var,
                         const float* __restrict__ g,
                         const float* __restrict__ be, float* __restrict__ O,
                         ushort_t* __restrict__ Ob) {
  size_t i = (size_t)blockIdx.x * 256 + threadIdx.x;  // 4*1024*512
  int c = (int)(i & 511);
  size_t row = i >> 9;
  int lo = (int)(row & 1023);
  int b = (int)(row >> 10);
  float sc = g[c] / sqrtf(var[c] + 1e-5f);
  float sh = be[c] - mu[c] * sc;
  int l0 = 2 * lo - 1;
  float m = -INFINITY;
  #pragma unroll
  for (int tt = 0; tt < 3; ++tt) {
    int l = l0 + tt;
    if (l >= 0 && l < 2048) {
      float v = Y[((size_t)b * 2048 + l) * DM + c] * sc + sh;
      v = v > 0.f ? v : expm1f(v);
      m = fmaxf(m, v);
    }
  }
  O[i] = m;
  Ob[i] = f2b(m);
}

// ---------------------------------------------------------------------------
extern "C" void kernel_launch(void* const* d_in, const int* in_sizes, int n_in,
                              void* d_out, int out_size, void* d_ws,
                              size_t ws_size, hipStream_t stream) {
  (void)in_sizes; (void)n_in; (void)out_size; (void)ws_size;
  const float* x_enc  = (const float*)d_in[0];
  const float* tok_w  = (const float*)d_in[1];
  const float* Wq     = (const float*)d_in[2];
  const float* bq     = (const float*)d_in[3];
  const float* Wk     = (const float*)d_in[4];
  const float* bk     = (const float*)d_in[5];
  const float* Wv     = (const float*)d_in[6];
  const float* bv     = (const float*)d_in[7];
  const float* Wo     = (const float*)d_in[8];
  const float* bo     = (const float*)d_in[9];
  const float* W1     = (const float*)d_in[10];
  const float* b1     = (const float*)d_in[11];
  const float* W2     = (const float*)d_in[12];
  const float* b2     = (const float*)d_in[13];
  const float* ln1_g  = (const float*)d_in[14];
  const float* ln1_b  = (const float*)d_in[15];
  const float* ln2_g  = (const float*)d_in[16];
  const float* ln2_b  = (const float*)d_in[17];
  const float* conv_w = (const float*)d_in[18];
  const float* conv_b = (const float*)d_in[19];
  const float* bn_g   = (const float*)d_in[20];
  const float* bn_b   = (const float*)d_in[21];
  const float* normf_g = (const float*)d_in[22];
  const float* normf_b = (const float*)d_in[23];
  const float* proj_w = (const float*)d_in[24];
  const float* proj_b = (const float*)d_in[25];
  float* out = (float*)d_out;
  float* ws = (float*)d_ws;

  // ---- fp32 workspace layout (float offsets) ----
  float* X    = ws;                    // 4,194,304
  float* SCR  = ws + 4194304;          // 12,582,912 (final-LN scratch)
  ushort_t* CTXb = (ushort_t*)(ws + 16777216);  // bf16 ctx
  float* Y2   = ws + 20971520;         // 4,194,304 (attn partials / conv out)
  float* Mb   = ws + 25165824;         // 65,536
  float* MV   = ws + 25231360;         // 2,048
  float* MVP  = ws + 25233408;         // 32,768
  float* BNps = ws + 25266176;         // 16,384
  float* BNpq = ws + 25282560;         // 16,384
  float* BNmu = ws + 25298944;         // 512
  float* BNvr = ws + 25299456;         // 512
  float* ZB   = ws + 25299968;         // 512 (zero bias)
  float* BQKV = ws + 25300480;         // 3,072 (concat qkv bias, 2 layers)
  int*   IDX  = (int*)(ws + 25303552); // 81,920
  int*   MT   = (int*)(ws + 25385472); // 1,280
  // ---- bf16 workspace ----
  ushort_t* U0   = (ushort_t*)(ws + 25386752);
  ushort_t* Xb   = U0;                 // 4,194,304
  ushort_t* Hb   = U0 + 4194304;       // 16,777,216 (FFN hidden / im2col)
  ushort_t* QKVb = Hb;                 // alias: bf16 QKV — live QKV-GEMM ->
                                       // attn, before FFN uses Hb
  ushort_t* Wqkvb= U0 + 20971520;      // 1,572,864
  ushort_t* Wob  = U0 + 22544384;      // 524,288
  ushort_t* W1b  = U0 + 23068672;      // 2,097,152
  ushort_t* W2b  = U0 + 25165824;      // 2,097,152
  ushort_t* Cwb  = U0 + 27262976;      // 786,432
  ushort_t* Twb  = U0 + 28049408;      // 49,152
  ushort_t* Atok = U0 + 28098560;      // 786,432
  float* PEf = ws + 39829248;          // 1,048,576 (PE table)

  // ---- fused preamble ----
  castqkv_k<<<1536, 256, 0, stream>>>(Wq, Wk, Wv, Wqkvb);
  castw3_k<<<4656, 256, 0, stream>>>(Wo, W1, W2, tok_w, Wob, W1b, W2b, Twb);
  castw_conv_k<<<3072, 256, 0, stream>>>(conv_w, Cwb);
  setup_small_k<<<14, 256, 0, stream>>>(bq, bk, bv, ZB, BQKV);
  pe_k<<<4096, 256, 0, stream>>>(PEf);
  im2col_tok_k<<<3072, 256, 0, stream>>>(x_enc, Atok);

  // token embedding GEMM (+PE): X=4, Y=64 -> 256 blocks
  mgemm_k<0, 2, 1><<<256, 256, 0, stream>>>(
      Atok, Twb, ZB, X, Xb, PEf, 4, DM, 96);

  for (int layer = 0; layer < 2; ++layer) {
    const int Lx = (layer == 0) ? 2048 : 1024;
    const int U  = (layer == 0) ? 40 : 35;
    const int M  = NB * Lx;
    const int Yt = M / 128;
    const int NCH = 8;

    uint32_t kl0, kl1, s0, s1;
    threefry2x32(0u, 42u, 0u, (uint32_t)layer, &kl0, &kl1);
    threefry2x32(kl0, kl1, 0u, 1u, &s0, &s1);
    int nidx = Lx * U;
    gen_idx_k<<<(nidx + 255) / 256, 256, 0, stream>>>(IDX, nidx, Lx - 1, s0, s1);

    // fused QKV GEMM: bf16-only output, XCD-swizzled
    mgemm_k<0, 1, 0><<<12 * Yt, 256, 0, stream>>>(
        Xb, Wqkvb + (size_t)layer * 786432, BQKV + layer * 1536, nullptr, QKVb,
        nullptr, 12, QS, DM);

    // ProbSparse attention (all bf16 QKV)
    if (layer == 0)
      qk_m_k<40><<<Lx, 256, 0, stream>>>(QKVb, IDX, Mb, Lx);
    else
      qk_m_k<35><<<Lx, 256, 0, stream>>>(QKVb, IDX, Mb, Lx);
    topk_k<<<NB * NH * (Lx >> 8), 256, 0, stream>>>(Mb, MT, Lx, U);
    meanv1_k<<<NB * 16, 512, 0, stream>>>(QKVb, MVP, Lx);
    meanv2_k<<<NB, 512, 0, stream>>>(MVP, MV, Lx);
    fillctx_k<<<(M * DM / 4) / 256, 256, 0, stream>>>(CTXb, MV, Lx);
    attn_flash_k<<<NB * NH * NCH, 512, 0, stream>>>(QKVb, MT, Y2, Lx, U, NCH);
    attn_merge_k<<<NB * NH * U, 64, 0, stream>>>(Y2, MT, CTXb, Lx, U, NCH);

    // output projection + residual + LN1 (emits bf16 for FFN1)
    mgemm_k<0, 0, 0><<<4 * Yt, 256, 0, stream>>>(
        CTXb, Wob + (size_t)layer * 262144, bo + layer * DM, Y2, nullptr,
        nullptr, 4, DM, DM);
    ln_k<<<M, 128, 0, stream>>>(X, Y2, ln1_g + layer * DM, ln1_b + layer * DM, X, Xb);

    // FFN (GELU fused; hidden kept in bf16); LN2 emits bf16
    mgemm_k<1, 1, 0><<<16 * Yt, 256, 0, stream>>>(
        Xb, W1b + (size_t)layer * 1048576, b1 + layer * 2048, nullptr, Hb,
        nullptr, 16, 2048, DM);
    mgemm_k<0, 0, 0><<<4 * Yt, 256, 0, stream>>>(
        Hb, W2b + (size_t)layer * 1048576, b2 + layer * DM, Y2, nullptr,
        nullptr, 4, DM, 2048);
    ln_k<<<M, 128, 0, stream>>>(X, Y2, ln2_g + layer * DM, ln2_b + layer * DM, X, Xb);

    if (layer == 0) {
      im2col_k<<<12288, 256, 0, stream>>>(X, Hb);
      mgemm_k<0, 0, 0><<<4 * 64, 256, 0, stream>>>(
          Hb, Cwb, conv_b, Y2, nullptr, nullptr, 4, DM, 1536);
      bn1_k<<<32, 256, 0, stream>>>(Y2, BNps, BNpq);
      bn2_k<<<1, 512, 0, stream>>>(BNps, BNpq, BNmu, BNvr);
      bnpool_k<<<(NB * 1024 * 512) / 256, 256, 0, stream>>>(
          Y2, BNmu, BNvr, bn_g, bn_b, X, Xb);
    }
  }

  // final LN + projection (N=32, fp32)
  ln_k<<<NB * 1024, 128, 0, stream>>>(X, nullptr, normf_g, normf_b, SCR, nullptr);
  gemm_k<<<dim3(1, 4096 / 64), 256, 0, stream>>>(SCR, proj_w, proj_b, out,
                                                 4096, 32, DM);
}

// Round 12
// 786.983 us; speedup vs baseline: 1.1998x; 1.0225x over previous
//
#include <hip/hip_runtime.h>
#include <cstdint>
#include <cmath>

// ---------------------------------------------------------------------------
// Informer encoder forward (B=4, L=2048, ENC_IN=32, D_MODEL=512, D_FF=2048,
// E_LAYERS=2, H=8, FACTOR=5).
// Round 12: XOR bank swizzle in mgemm LDS tiles — kills the 8-way ds_read
// conflict (SQ_LDS_BANK_CONFLICT 2.1M/dispatch) present in every GEMM.
// Position p = (lane&3) ^ s(row), s(r) = (r&3)^((r>>2)&3); 2 lanes/bank = free.
// ---------------------------------------------------------------------------

#define NB 4
#define DM 512
#define NH 8
#define HD 64
#define QS 1536  // QKV row stride

typedef unsigned short ushort_t;
typedef __bf16 bf16x8 __attribute__((ext_vector_type(8)));
typedef float floatx4 __attribute__((ext_vector_type(4)));
typedef unsigned short ushort8_t __attribute__((ext_vector_type(8)));

__device__ inline ushort_t f2b(float f) {
  uint32_t u = __float_as_uint(f);
  uint32_t r = (u + 0x7fffu + ((u >> 16) & 1u)) >> 16;
  return (ushort_t)r;
}
__device__ inline float b2f(ushort_t u) {
  return __uint_as_float((uint32_t)u << 16);
}

// ---------------- fused weight casts ---------------------------------------
__global__ void castqkv_k(const float* __restrict__ Wq,
                          const float* __restrict__ Wk,
                          const float* __restrict__ Wv,
                          ushort_t* __restrict__ out) {
  int gid = blockIdx.x * 256 + threadIdx.x;  // 393216 float4 units
  if (gid >= 393216) return;
  int ly = gid / 196608, r4 = gid - ly * 196608;
  int r = r4 >> 7, c4 = r4 & 127;
  int sel = r >> 9, srow = r & 511;
  const float* src = (sel == 0 ? Wq : sel == 1 ? Wk : Wv) + ly * 262144 +
                     srow * 512 + c4 * 4;
  float4 v = *(const float4*)src;
  ushort4 o;
  o.x = f2b(v.x); o.y = f2b(v.y); o.z = f2b(v.z); o.w = f2b(v.w);
  ((ushort4*)out)[ly * 196608 + r * 128 + c4] = o;
}

__global__ void castw3_k(const float* __restrict__ Wo,
                         const float* __restrict__ W1,
                         const float* __restrict__ W2,
                         const float* __restrict__ tw,
                         ushort_t* __restrict__ oWo, ushort_t* __restrict__ oW1,
                         ushort_t* __restrict__ oW2, ushort_t* __restrict__ otw) {
  int gid = blockIdx.x * 256 + threadIdx.x;  // 1,191,936 float4 units
  if (gid >= 1191936) return;
  const float* src;
  ushort4* dst;
  int i;
  if (gid < 131072) { src = Wo; dst = (ushort4*)oWo; i = gid; }
  else if (gid < 655360) { src = W1; dst = (ushort4*)oW1; i = gid - 131072; }
  else if (gid < 1179648) { src = W2; dst = (ushort4*)oW2; i = gid - 655360; }
  else { src = tw; dst = (ushort4*)otw; i = gid - 1179648; }
  float4 v = ((const float4*)src)[i];
  ushort4 o;
  o.x = f2b(v.x); o.y = f2b(v.y); o.z = f2b(v.z); o.w = f2b(v.w);
  dst[i] = o;
}

__global__ void castw_conv_k(const float* __restrict__ in,
                             ushort_t* __restrict__ out) {
  int gid = blockIdx.x * 256 + threadIdx.x;  // 512*1536
  int d = gid / 1536, r = gid - d * 1536;
  int t = r >> 9, i = r & 511;
  out[gid] = f2b(in[d * 1536 + i * 3 + t]);
}

__global__ void setup_small_k(const float* __restrict__ bq,
                              const float* __restrict__ bk,
                              const float* __restrict__ bv,
                              float* __restrict__ ZB,
                              float* __restrict__ BQKV) {
  int gid = blockIdx.x * 256 + threadIdx.x;  // 3584
  if (gid >= 3584) return;
  if (gid < 512) { ZB[gid] = 0.f; return; }
  int g = gid - 512;
  int layer = g / 1536, r = g - layer * 1536;
  float v;
  if (r < 512) v = bq[layer * 512 + r];
  else if (r < 1024) v = bk[layer * 512 + r - 512];
  else v = bv[layer * 512 + r - 1024];
  BQKV[g] = v;
}

__host__ __device__ inline void threefry2x32(uint32_t k0, uint32_t k1,
                                             uint32_t c0, uint32_t c1,
                                             uint32_t* o0, uint32_t* o1) {
  uint32_t ks0 = k0, ks1 = k1, ks2 = k0 ^ k1 ^ 0x1BD11BDAu;
  uint32_t x0 = c0 + ks0;
  uint32_t x1 = c1 + ks1;
  const uint32_t rotA[4] = {13u, 15u, 26u, 6u};
  const uint32_t rotB[4] = {17u, 29u, 16u, 24u};
  uint32_t ks[3] = {ks0, ks1, ks2};
  #pragma unroll
  for (int i = 0; i < 5; ++i) {
    const uint32_t* r = (i & 1) ? rotB : rotA;
    #pragma unroll
    for (int j = 0; j < 4; ++j) {
      x0 += x1;
      x1 = (x1 << r[j]) | (x1 >> (32u - r[j]));
      x1 ^= x0;
    }
    x0 += ks[(i + 1) % 3];
    x1 += ks[(i + 2) % 3] + (uint32_t)(i + 1);
  }
  *o0 = x0; *o1 = x1;
}

__global__ void gen_idx_k(int* __restrict__ idx, int n, int mask,
                          uint32_t k0, uint32_t k1) {
  int i = blockIdx.x * 256 + threadIdx.x;
  if (i < n) {
    uint32_t o0, o1;
    threefry2x32(k0, k1, 0u, (uint32_t)i, &o0, &o1);
    idx[i] = (int)((o0 ^ o1) & (uint32_t)mask);
  }
}

__device__ inline float wave_sum64(float v) {
  #pragma unroll
  for (int o = 32; o > 0; o >>= 1) v += __shfl_xor(v, o, 64);
  return v;
}
__device__ inline float wave_max64(float v) {
  #pragma unroll
  for (int o = 32; o > 0; o >>= 1) v = fmaxf(v, __shfl_xor(v, o, 64));
  return v;
}

// ---------------- positional-encoding table (2048 x 512) -------------------
__global__ void pe_k(float* __restrict__ pe) {
  int i = blockIdx.x * 256 + threadIdx.x;  // 1,048,576
  int d = i & 511, l = i >> 9;
  int j2 = d & ~1;
  float div = expf((float)j2 * -1.7988946039e-2f);  // -ln(10000)/512
  float ang = (float)l * div;
  pe[i] = (d & 1) ? cosf(ang) : sinf(ang);
}

// ---------------- im2col for token conv: (B*L, 96) bf16 --------------------
__global__ void im2col_tok_k(const float* __restrict__ xe,
                             ushort_t* __restrict__ A) {
  int gid = blockIdx.x * 256 + threadIdx.x;  // 8192*96
  int col = gid % 96;
  int row = gid / 96;
  int c = col / 3, t = col - c * 3;
  int b = row >> 11, l = row & 2047;
  int ls = (l + t - 1) & 2047;
  A[gid] = f2b(xe[((size_t)b * 2048 + ls) * 32 + c]);
}

// ---------------- bf16 MFMA GEMM, XCD swizzle + LDS bank swizzle -----------
__device__ inline void gload16(const ushort_t* g, ushort_t* l) {
  __builtin_amdgcn_global_load_lds(
      (const __attribute__((address_space(1))) unsigned int*)(const void*)g,
      (__attribute__((address_space(3))) unsigned int*)(void*)l, 16, 0, 0);
}

template <int GELU, int OMODE, int ADDPE>  // OMODE: 0 f32, 1 bf16, 2 both
__global__ __launch_bounds__(256) void mgemm_k(
    const ushort_t* __restrict__ A, const ushort_t* __restrict__ W,
    const float* __restrict__ bias, float* __restrict__ Cf,
    ushort_t* __restrict__ Cb, const float* __restrict__ pe,
    int X, int ldc, int K) {
  __shared__ ushort_t As[128 * 32];
  __shared__ ushort_t Bs[128 * 32];
  int id = blockIdx.x;
  int cc = id & 7, j = id >> 3;
  int bx = j % X;
  int by = (j / X) * 8 + cc;
  int m0 = by * 128, n0 = bx * 128;
  int t = threadIdx.x;
  int lane = t & 63, wv = t >> 6;
  // staging with XOR bank swizzle: local row sr, position pp; lane fetches
  // global column group g = pp ^ s(sr) so LDS slot (sr,pp) holds group g.
  int sr = lane >> 2, pp = lane & 3;
  int sw = (sr & 3) ^ ((sr >> 2) & 3);
  int sc = (pp ^ sw) * 8;
  int ra0 = wv * 32 + sr, ra1 = ra0 + 16;
  const ushort_t* gA0 = A + (size_t)(m0 + ra0) * K + sc;
  const ushort_t* gA1 = A + (size_t)(m0 + ra1) * K + sc;
  const ushort_t* gB0 = W + (size_t)(n0 + ra0) * K + sc;
  const ushort_t* gB1 = W + (size_t)(n0 + ra1) * K + sc;
  ushort_t* lA0 = As + wv * 1024;
  ushort_t* lA1 = lA0 + 512;
  ushort_t* lB0 = Bs + wv * 1024;
  ushort_t* lB1 = lB0 + 512;

  int quad = lane >> 4, lr = lane & 15;
  int wm = wv >> 1, wn = wv & 1;
  // read-side swizzled position for row lr
  int sR = (lr & 3) ^ ((lr >> 2) & 3);
  int rq = (quad ^ sR) * 8;

  floatx4 acc[4][4] = {};
  for (int ks = 0; ks < K; ks += 32) {
    gload16(gA0, lA0);
    gload16(gA1, lA1);
    gload16(gB0, lB0);
    gload16(gB1, lB1);
    gA0 += 32; gA1 += 32; gB0 += 32; gB1 += 32;
    __syncthreads();
    bf16x8 av[4], bv[4];
    #pragma unroll
    for (int mt = 0; mt < 4; ++mt)
      av[mt] = *(const bf16x8*)&As[(wm * 64 + mt * 16 + lr) * 32 + rq];
    #pragma unroll
    for (int nt = 0; nt < 4; ++nt)
      bv[nt] = *(const bf16x8*)&Bs[(wn * 64 + nt * 16 + lr) * 32 + rq];
    #pragma unroll
    for (int mt = 0; mt < 4; ++mt)
      #pragma unroll
      for (int nt = 0; nt < 4; ++nt)
        acc[mt][nt] = __builtin_amdgcn_mfma_f32_16x16x32_bf16(
            av[mt], bv[nt], acc[mt][nt], 0, 0, 0);
    __syncthreads();
  }
  #pragma unroll
  for (int nt = 0; nt < 4; ++nt) {
    int col = n0 + wn * 64 + nt * 16 + lr;
    float bsv = bias[col];
    #pragma unroll
    for (int mt = 0; mt < 4; ++mt) {
      int row0 = m0 + wm * 64 + mt * 16 + quad * 4;
      #pragma unroll
      for (int r = 0; r < 4; ++r) {
        int row = row0 + r;
        float v = acc[mt][nt][r] + bsv;
        if (ADDPE) v += pe[(size_t)(row & 2047) * ldc + col];
        if (GELU) v = 0.5f * v * (1.0f + erff(v * 0.70710678118654752f));
        if (OMODE == 0 || OMODE == 2) Cf[(size_t)row * ldc + col] = v;
        if (OMODE == 1 || OMODE == 2) Cb[(size_t)row * ldc + col] = f2b(v);
      }
    }
  }
}

// ---------------- fp32 fallback GEMM (final projection, N=32) --------------
__global__ __launch_bounds__(256) void gemm_k(
    const float* __restrict__ A, const float* __restrict__ W,
    const float* __restrict__ bias, float* __restrict__ C,
    int M, int N, int K) {
  __shared__ float As2[16][64 + 4];
  __shared__ float Ws2[16][64 + 4];
  int m0 = blockIdx.y * 64, n0 = blockIdx.x * 64;
  int t = threadIdx.x;
  int tx = t & 15, ty = t >> 4;
  float acc[4][4] = {};
  for (int k0 = 0; k0 < K; k0 += 16) {
    #pragma unroll
    for (int i = 0; i < 4; ++i) {
      int li = t + i * 256;
      int m = li >> 4, kk = li & 15;
      As2[kk][m] = A[(size_t)(m0 + m) * K + k0 + kk];
    }
    #pragma unroll
    for (int i = 0; i < 4; ++i) {
      int li = t + i * 256;
      int n = li >> 4, kk = li & 15;
      int gn = n0 + n;
      Ws2[kk][n] = (gn < N) ? W[(size_t)gn * K + k0 + kk] : 0.0f;
    }
    __syncthreads();
    #pragma unroll
    for (int kk = 0; kk < 16; ++kk) {
      float4 avv = *(const float4*)&As2[kk][ty * 4];
      float4 bvv = *(const float4*)&Ws2[kk][tx * 4];
      float a[4] = {avv.x, avv.y, avv.z, avv.w};
      float bb[4] = {bvv.x, bvv.y, bvv.z, bvv.w};
      #pragma unroll
      for (int i = 0; i < 4; ++i)
        #pragma unroll
        for (int j = 0; j < 4; ++j) acc[i][j] += a[i] * bb[j];
    }
    __syncthreads();
  }
  #pragma unroll
  for (int i = 0; i < 4; ++i) {
    int m = m0 + ty * 4 + i;
    #pragma unroll
    for (int j = 0; j < 4; ++j) {
      int n = n0 + tx * 4 + j;
      if (n < N) C[(size_t)m * N + n] = acc[i][j] + bias[n];
    }
  }
}

// ---------------- LayerNorm (+optional residual, +optional bf16 copy) ------
__global__ __launch_bounds__(128) void ln_k(
    const float* __restrict__ A, const float* __restrict__ Bres,
    const float* __restrict__ g, const float* __restrict__ be,
    float* __restrict__ O, ushort_t* __restrict__ Ob) {
  int r = blockIdx.x, t = threadIdx.x;
  __shared__ float lds[2];
  float4 v = ((const float4*)(A + (size_t)r * DM))[t];
  if (Bres) {
    float4 u = ((const float4*)(Bres + (size_t)r * DM))[t];
    v.x += u.x; v.y += u.y; v.z += u.z; v.w += u.w;
  }
  float s = wave_sum64(v.x + v.y + v.z + v.w);
  int w = t >> 6;
  if ((t & 63) == 0) lds[w] = s;
  __syncthreads();
  float mu = (lds[0] + lds[1]) * (1.0f / 512.0f);
  __syncthreads();
  float dx = v.x - mu, dy = v.y - mu, dz = v.z - mu, dw = v.w - mu;
  float sq = wave_sum64(dx * dx + dy * dy + dz * dz + dw * dw);
  if ((t & 63) == 0) lds[w] = sq;
  __syncthreads();
  float var = (lds[0] + lds[1]) * (1.0f / 512.0f);
  float inv = 1.0f / sqrtf(var + 1e-5f);
  float4 gv = ((const float4*)g)[t];
  float4 bv = ((const float4*)be)[t];
  float4 o;
  o.x = dx * inv * gv.x + bv.x;
  o.y = dy * inv * gv.y + bv.y;
  o.z = dz * inv * gv.z + bv.z;
  o.w = dw * inv * gv.w + bv.w;
  ((float4*)(O + (size_t)r * DM))[t] = o;
  if (Ob) {
    ushort4 ob;
    ob.x = f2b(o.x); ob.y = f2b(o.y); ob.z = f2b(o.z); ob.w = f2b(o.w);
    ((ushort4*)(Ob + (size_t)r * DM))[t] = ob;
  }
}

// ---------------- M[b,h,l]: one wave per (b,l), all-bf16 QKV ---------------
template <int UU>
__global__ __launch_bounds__(256) void qk_m_k(
    const ushort_t* __restrict__ QKVb, const int* __restrict__ idx,
    float* __restrict__ Mout, int Lx) {
  int l = blockIdx.x;
  int b = threadIdx.x >> 6;  // wave = batch
  int lane = threadIdx.x & 63;
  const ushort_t* qp = QKVb + ((size_t)b * Lx + l) * QS + lane * 8;
  float q[8];
  {
    ushort8_t qv = *(const ushort8_t*)qp;
    #pragma unroll
    for (int c = 0; c < 8; ++c) q[c] = b2f(qv[c]);
  }
  const ushort_t* Kbase = QKVb + (size_t)b * Lx * QS + 512 + lane * 8;
  const int* ip = idx + (size_t)l * UU;
  float maxv = -INFINITY, sumv = 0.f;
  #pragma unroll
  for (int u0 = 0; u0 < UU; u0 += 8) {
    ushort8_t kv[8];
    #pragma unroll
    for (int j = 0; j < 8; ++j) {
      if (u0 + j < UU)
        kv[j] = *(const ushort8_t*)(Kbase + (size_t)ip[u0 + j] * QS);
    }
    #pragma unroll
    for (int j = 0; j < 8; ++j) {
      if (u0 + j < UU) {
        float p = 0.f;
        #pragma unroll
        for (int c = 0; c < 8; ++c) p += q[c] * b2f(kv[j][c]);
        p += __shfl_xor(p, 1, 64);
        p += __shfl_xor(p, 2, 64);
        p += __shfl_xor(p, 4, 64);
        maxv = fmaxf(maxv, p);
        sumv += p;
      }
    }
  }
  if ((lane & 7) == 0) {
    int h = lane >> 3;
    Mout[(size_t)(b * 8 + h) * Lx + l] = maxv - sumv / (float)Lx;
  }
}

// ---------------- rank-based top-U, chunked (exact JAX tie-breaking) -------
__global__ __launch_bounds__(256) void topk_k(
    const float* __restrict__ Mbuf, int* __restrict__ Mtop, int Lx, int U) {
  int nch = Lx >> 8;
  int bh = blockIdx.x / nch, ch = blockIdx.x % nch;
  const float* m = Mbuf + (size_t)bh * Lx;
  __shared__ float sm[2048];
  int t = threadIdx.x;
  for (int i = t; i < Lx; i += 256) sm[i] = m[i];
  __syncthreads();
  int i0 = (ch << 8) + t;
  float v0 = sm[i0];
  int r0 = 0;
  for (int j = 0; j < Lx; j += 4) {
    float4 mj = *(const float4*)&sm[j];
    r0 += (mj.x > v0) || (mj.x == v0 && (j + 0) < i0);
    r0 += (mj.y > v0) || (mj.y == v0 && (j + 1) < i0);
    r0 += (mj.z > v0) || (mj.z == v0 && (j + 2) < i0);
    r0 += (mj.w > v0) || (mj.w == v0 && (j + 3) < i0);
  }
  if (r0 < U) Mtop[bh * U + r0] = i0;
}

// ---------------- meanV from bf16 QKV (V at +1024) -------------------------
__global__ __launch_bounds__(512) void meanv1_k(const ushort_t* __restrict__ QKVb,
                                                float* __restrict__ part,
                                                int Lx) {
  int b = blockIdx.x >> 4, chunk = blockIdx.x & 15;
  int rows = Lx >> 4;
  int t = threadIdx.x;  // 512
  const ushort_t* vp =
      QKVb + ((size_t)b * Lx + (size_t)chunk * rows) * QS + 1024 + t;
  float s = 0.f;
  for (int l = 0; l < rows; ++l) s += b2f(vp[(size_t)l * QS]);
  part[(size_t)blockIdx.x * DM + t] = s;
}
__global__ __launch_bounds__(512) void meanv2_k(const float* __restrict__ part,
                                                float* __restrict__ mv,
                                                int Lx) {
  int b = blockIdx.x, t = threadIdx.x;
  float s = 0.f;
  #pragma unroll
  for (int c = 0; c < 16; ++c) s += part[(size_t)(b * 16 + c) * DM + t];
  mv[b * DM + t] = s / (float)Lx;
}

__global__ void fillctx_k(ushort_t* __restrict__ ctx,
                          const float* __restrict__ mv, int Lx) {
  size_t i4 = (size_t)blockIdx.x * 256 + threadIdx.x;
  int col4 = (int)(i4 & 127);
  size_t row = i4 >> 7;
  int b = (int)(row / (size_t)Lx);
  const float* m = mv + b * DM + col4 * 4;
  ushort4 o;
  o.x = f2b(m[0]); o.y = f2b(m[1]); o.z = f2b(m[2]); o.w = f2b(m[3]);
  ((ushort4*)ctx)[i4] = o;
}

// ---------------- flash split-K attention (bf16 QKV) -----------------------
__global__ __launch_bounds__(512) void attn_flash_k(
    const ushort_t* __restrict__ QKVb, const int* __restrict__ Mtop,
    float* __restrict__ part, int Lx, int U, int nchunk) {
  int blk = blockIdx.x;
  int chunk = blk % nchunk, bh = blk / nchunk;
  int h = bh & 7, b = bh >> 3;
  int rows = Lx / nchunk;
  int ntile = rows >> 6;
  __shared__ float s_q[40 * 64];
  __shared__ float s_k[64 * 65];
  __shared__ float s_v[64 * 65];
  __shared__ float s_p[40 * 64];
  __shared__ float s_m[40], s_l[40], s_a[40];
  int t = threadIdx.x;
  int d = t & 63, wv = t >> 6;

  for (int i = t; i < U * 64; i += 512) {
    int u = i >> 6, dd = i & 63;
    int qi = Mtop[bh * U + u];
    s_q[i] = b2f(QKVb[((size_t)b * Lx + qi) * QS + h * HD + dd]) * 0.125f;
  }
  if (t < U) { s_m[t] = -INFINITY; s_l[t] = 0.f; s_a[t] = 0.f; }
  float o[5] = {0.f, 0.f, 0.f, 0.f, 0.f};
  __syncthreads();

  const ushort_t* Kp = QKVb + (size_t)b * Lx * QS + 512 + h * HD;
  const ushort_t* Vp = QKVb + (size_t)b * Lx * QS + 1024 + h * HD;

  for (int tile = 0; tile < ntile; ++tile) {
    int kr0 = chunk * rows + tile * 64;
    {
      int r = t >> 3, c8 = (t & 7) * 8;  // 8 threads/row x 64 rows
      ushort8_t kv = *(const ushort8_t*)&Kp[(size_t)(kr0 + r) * QS + c8];
      ushort8_t vv = *(const ushort8_t*)&Vp[(size_t)(kr0 + r) * QS + c8];
      float* kd = &s_k[r * 65 + c8];
      float* vd = &s_v[r * 65 + c8];
      #pragma unroll
      for (int jj = 0; jj < 8; ++jj) {
        kd[jj] = b2f(kv[jj]);
        vd[jj] = b2f(vv[jj]);
      }
    }
    __syncthreads();
    {
      float kr[64];
      #pragma unroll
      for (int dd = 0; dd < 64; ++dd) kr[dd] = s_k[d * 65 + dd];
      for (int u = wv; u < U; u += 8) {
        float acc = 0.f;
        #pragma unroll
        for (int c = 0; c < 16; ++c) {
          float4 qv = *(const float4*)&s_q[u * 64 + c * 4];
          acc += qv.x * kr[c * 4] + qv.y * kr[c * 4 + 1] +
                 qv.z * kr[c * 4 + 2] + qv.w * kr[c * 4 + 3];
        }
        s_p[u * 64 + d] = acc;
      }
    }
    __syncthreads();
    for (int u = wv; u < U; u += 8) {
      float sv_ = s_p[u * 64 + d];
      float mx = wave_max64(sv_);
      float mold = s_m[u];
      float mnew = fmaxf(mold, mx);
      float e = expf(sv_ - mnew);
      float se = wave_sum64(e);
      s_p[u * 64 + d] = e;
      if (d == 0) {
        float alpha = expf(mold - mnew);
        s_a[u] = alpha;
        s_l[u] = s_l[u] * alpha + se;
        s_m[u] = mnew;
      }
    }
    __syncthreads();
    {
      float vr[64];
      #pragma unroll
      for (int k = 0; k < 64; ++k) vr[k] = s_v[k * 65 + d];
      int i = 0;
      for (int u = wv; u < U; u += 8, ++i) {
        float acc = 0.f;
        #pragma unroll
        for (int c = 0; c < 16; ++c) {
          float4 pv = *(const float4*)&s_p[u * 64 + c * 4];
          acc += pv.x * vr[c * 4] + pv.y * vr[c * 4 + 1] +
                 pv.z * vr[c * 4 + 2] + pv.w * vr[c * 4 + 3];
        }
        o[i] = o[i] * s_a[u] + acc;
      }
    }
    __syncthreads();
  }
  {
    int i = 0;
    for (int u = wv; u < U; u += 8, ++i) {
      float* pp = part + ((size_t)(bh * nchunk + chunk) * U + u) * 66;
      pp[d] = o[i];
      if (d == 0) { pp[64] = s_m[u]; pp[65] = s_l[u]; }
    }
  }
}

__global__ __launch_bounds__(64) void attn_merge_k(
    const float* __restrict__ part, const int* __restrict__ Mtop,
    ushort_t* __restrict__ ctx, int Lx, int U, int nchunk) {
  int bu = blockIdx.x;
  int u = bu % U, bh = bu / U;
  int h = bh & 7, b = bh >> 3;
  int d = threadIdx.x;  // 64
  float M = -INFINITY;
  for (int c = 0; c < nchunk; ++c)
    M = fmaxf(M, part[((size_t)(bh * nchunk + c) * U + u) * 66 + 64]);
  float L = 0.f, O = 0.f;
  for (int c = 0; c < nchunk; ++c) {
    const float* pp = part + ((size_t)(bh * nchunk + c) * U + u) * 66;
    float w = expf(pp[64] - M);
    L += pp[65] * w;
    O += pp[d] * w;
  }
  int qi = Mtop[bh * U + u];
  ctx[((size_t)b * Lx + qi) * DM + h * HD + d] = f2b(O / L);
}

// ---------------- distil im2col (circular, k=3) -> bf16, [t][c] layout -----
__global__ void im2col_k(const float* __restrict__ X,
                         ushort_t* __restrict__ A2) {
  int gid = blockIdx.x * 256 + threadIdx.x;  // 8192*3*128 ushort4 units
  int i4 = gid & 127;
  int rt = gid >> 7;
  int t = rt % 3, row = rt / 3;
  int b = row >> 11, l = row & 2047;
  int ls = (l + t - 1) & 2047;
  float4 v = ((const float4*)(X + ((size_t)b * 2048 + ls) * DM))[i4];
  ushort4 o;
  o.x = f2b(v.x); o.y = f2b(v.y); o.z = f2b(v.z); o.w = f2b(v.w);
  ((ushort4*)A2)[(size_t)row * 384 + t * 128 + i4] = o;
}

// ---------------- batch-norm stats: coalesced two-stage --------------------
__global__ __launch_bounds__(256) void bn1_k(const float* __restrict__ Y,
                                             float* __restrict__ ps,
                                             float* __restrict__ pq) {
  int blk = blockIdx.x;
  int t = threadIdx.x;
  float s0 = 0, q0 = 0, s1 = 0, q1 = 0;
  const float* base = Y + (size_t)blk * 256 * DM;
  for (int r = 0; r < 256; ++r) {
    float a = base[(size_t)r * DM + t];
    float b = base[(size_t)r * DM + t + 256];
    s0 += a; q0 += a * a; s1 += b; q1 += b * b;
  }
  ps[blk * DM + t] = s0; ps[blk * DM + t + 256] = s1;
  pq[blk * DM + t] = q0; pq[blk * DM + t + 256] = q1;
}
__global__ __launch_bounds__(512) void bn2_k(const float* __restrict__ ps,
                                             const float* __restrict__ pq,
                                             float* __restrict__ mu,
                                             float* __restrict__ var) {
  int t = threadIdx.x;
  float s = 0, q = 0;
  #pragma unroll
  for (int c = 0; c < 32; ++c) { s += ps[c * DM + t]; q += pq[c * DM + t]; }
  float m = s * (1.0f / 8192.f);
  mu[t] = m;
  var[t] = q * (1.0f / 8192.f) - m * m;
}

// fused bn+elu+maxpool(k=3,s=2,pad=1)
__global__ void bnpool_k(const float* __restrict__ Y,
                         const float* __restrict__ mu,
                         const float* __restrict__ var,
                         const float* __restrict__ g,
                         const float* __restrict__ be, float* __restrict__ O,
                         ushort_t* __restrict__ Ob) {
  size_t i = (size_t)blockIdx.x * 256 + threadIdx.x;  // 4*1024*512
  int c = (int)(i & 511);
  size_t row = i >> 9;
  int lo = (int)(row & 1023);
  int b = (int)(row >> 10);
  float sc = g[c] / sqrtf(var[c] + 1e-5f);
  float sh = be[c] - mu[c] * sc;
  int l0 = 2 * lo - 1;
  float m = -INFINITY;
  #pragma unroll
  for (int tt = 0; tt < 3; ++tt) {
    int l = l0 + tt;
    if (l >= 0 && l < 2048) {
      float v = Y[((size_t)b * 2048 + l) * DM + c] * sc + sh;
      v = v > 0.f ? v : expm1f(v);
      m = fmaxf(m, v);
    }
  }
  O[i] = m;
  Ob[i] = f2b(m);
}

// ---------------------------------------------------------------------------
extern "C" void kernel_launch(void* const* d_in, const int* in_sizes, int n_in,
                              void* d_out, int out_size, void* d_ws,
                              size_t ws_size, hipStream_t stream) {
  (void)in_sizes; (void)n_in; (void)out_size; (void)ws_size;
  const float* x_enc  = (const float*)d_in[0];
  const float* tok_w  = (const float*)d_in[1];
  const float* Wq     = (const float*)d_in[2];
  const float* bq     = (const float*)d_in[3];
  const float* Wk     = (const float*)d_in[4];
  const float* bk     = (const float*)d_in[5];
  const float* Wv     = (const float*)d_in[6];
  const float* bv     = (const float*)d_in[7];
  const float* Wo     = (const float*)d_in[8];
  const float* bo     = (const float*)d_in[9];
  const float* W1     = (const float*)d_in[10];
  const float* b1     = (const float*)d_in[11];
  const float* W2     = (const float*)d_in[12];
  const float* b2     = (const float*)d_in[13];
  const float* ln1_g  = (const float*)d_in[14];
  const float* ln1_b  = (const float*)d_in[15];
  const float* ln2_g  = (const float*)d_in[16];
  const float* ln2_b  = (const float*)d_in[17];
  const float* conv_w = (const float*)d_in[18];
  const float* conv_b = (const float*)d_in[19];
  const float* bn_g   = (const float*)d_in[20];
  const float* bn_b   = (const float*)d_in[21];
  const float* normf_g = (const float*)d_in[22];
  const float* normf_b = (const float*)d_in[23];
  const float* proj_w = (const float*)d_in[24];
  const float* proj_b = (const float*)d_in[25];
  float* out = (float*)d_out;
  float* ws = (float*)d_ws;

  // ---- fp32 workspace layout (float offsets) ----
  float* X    = ws;                    // 4,194,304
  float* SCR  = ws + 4194304;          // 12,582,912 (final-LN scratch)
  ushort_t* CTXb = (ushort_t*)(ws + 16777216);  // bf16 ctx
  float* Y2   = ws + 20971520;         // 4,194,304 (attn partials / conv out)
  float* Mb   = ws + 25165824;         // 65,536
  float* MV   = ws + 25231360;         // 2,048
  float* MVP  = ws + 25233408;         // 32,768
  float* BNps = ws + 25266176;         // 16,384
  float* BNpq = ws + 25282560;         // 16,384
  float* BNmu = ws + 25298944;         // 512
  float* BNvr = ws + 25299456;         // 512
  float* ZB   = ws + 25299968;         // 512 (zero bias)
  float* BQKV = ws + 25300480;         // 3,072 (concat qkv bias, 2 layers)
  int*   IDX  = (int*)(ws + 25303552); // 81,920
  int*   MT   = (int*)(ws + 25385472); // 1,280
  // ---- bf16 workspace ----
  ushort_t* U0   = (ushort_t*)(ws + 25386752);
  ushort_t* Xb   = U0;                 // 4,194,304
  ushort_t* Hb   = U0 + 4194304;       // 16,777,216 (FFN hidden / im2col)
  ushort_t* QKVb = Hb;                 // alias: bf16 QKV — live QKV-GEMM ->
                                       // attn, before FFN uses Hb
  ushort_t* Wqkvb= U0 + 20971520;      // 1,572,864
  ushort_t* Wob  = U0 + 22544384;      // 524,288
  ushort_t* W1b  = U0 + 23068672;      // 2,097,152
  ushort_t* W2b  = U0 + 25165824;      // 2,097,152
  ushort_t* Cwb  = U0 + 27262976;      // 786,432
  ushort_t* Twb  = U0 + 28049408;      // 49,152
  ushort_t* Atok = U0 + 28098560;      // 786,432
  float* PEf = ws + 39829248;          // 1,048,576 (PE table)

  // ---- fused preamble ----
  castqkv_k<<<1536, 256, 0, stream>>>(Wq, Wk, Wv, Wqkvb);
  castw3_k<<<4656, 256, 0, stream>>>(Wo, W1, W2, tok_w, Wob, W1b, W2b, Twb);
  castw_conv_k<<<3072, 256, 0, stream>>>(conv_w, Cwb);
  setup_small_k<<<14, 256, 0, stream>>>(bq, bk, bv, ZB, BQKV);
  pe_k<<<4096, 256, 0, stream>>>(PEf);
  im2col_tok_k<<<3072, 256, 0, stream>>>(x_enc, Atok);

  // token embedding GEMM (+PE): X=4, Y=64 -> 256 blocks
  mgemm_k<0, 2, 1><<<256, 256, 0, stream>>>(
      Atok, Twb, ZB, X, Xb, PEf, 4, DM, 96);

  for (int layer = 0; layer < 2; ++layer) {
    const int Lx = (layer == 0) ? 2048 : 1024;
    const int U  = (layer == 0) ? 40 : 35;
    const int M  = NB * Lx;
    const int Yt = M / 128;
    const int NCH = 8;

    uint32_t kl0, kl1, s0, s1;
    threefry2x32(0u, 42u, 0u, (uint32_t)layer, &kl0, &kl1);
    threefry2x32(kl0, kl1, 0u, 1u, &s0, &s1);
    int nidx = Lx * U;
    gen_idx_k<<<(nidx + 255) / 256, 256, 0, stream>>>(IDX, nidx, Lx - 1, s0, s1);

    // fused QKV GEMM: bf16-only output, XCD-swizzled
    mgemm_k<0, 1, 0><<<12 * Yt, 256, 0, stream>>>(
        Xb, Wqkvb + (size_t)layer * 786432, BQKV + layer * 1536, nullptr, QKVb,
        nullptr, 12, QS, DM);

    // ProbSparse attention (all bf16 QKV)
    if (layer == 0)
      qk_m_k<40><<<Lx, 256, 0, stream>>>(QKVb, IDX, Mb, Lx);
    else
      qk_m_k<35><<<Lx, 256, 0, stream>>>(QKVb, IDX, Mb, Lx);
    topk_k<<<NB * NH * (Lx >> 8), 256, 0, stream>>>(Mb, MT, Lx, U);
    meanv1_k<<<NB * 16, 512, 0, stream>>>(QKVb, MVP, Lx);
    meanv2_k<<<NB, 512, 0, stream>>>(MVP, MV, Lx);
    fillctx_k<<<(M * DM / 4) / 256, 256, 0, stream>>>(CTXb, MV, Lx);
    attn_flash_k<<<NB * NH * NCH, 512, 0, stream>>>(QKVb, MT, Y2, Lx, U, NCH);
    attn_merge_k<<<NB * NH * U, 64, 0, stream>>>(Y2, MT, CTXb, Lx, U, NCH);

    // output projection + residual + LN1 (emits bf16 for FFN1)
    mgemm_k<0, 0, 0><<<4 * Yt, 256, 0, stream>>>(
        CTXb, Wob + (size_t)layer * 262144, bo + layer * DM, Y2, nullptr,
        nullptr, 4, DM, DM);
    ln_k<<<M, 128, 0, stream>>>(X, Y2, ln1_g + layer * DM, ln1_b + layer * DM, X, Xb);

    // FFN (GELU fused; hidden kept in bf16); LN2 emits bf16
    mgemm_k<1, 1, 0><<<16 * Yt, 256, 0, stream>>>(
        Xb, W1b + (size_t)layer * 1048576, b1 + layer * 2048, nullptr, Hb,
        nullptr, 16, 2048, DM);
    mgemm_k<0, 0, 0><<<4 * Yt, 256, 0, stream>>>(
        Hb, W2b + (size_t)layer * 1048576, b2 + layer * DM, Y2, nullptr,
        nullptr, 4, DM, 2048);
    ln_k<<<M, 128, 0, stream>>>(X, Y2, ln2_g + layer * DM, ln2_b + layer * DM, X, Xb);

    if (layer == 0) {
      im2col_k<<<12288, 256, 0, stream>>>(X, Hb);
      mgemm_k<0, 0, 0><<<4 * 64, 256, 0, stream>>>(
          Hb, Cwb, conv_b, Y2, nullptr, nullptr, 4, DM, 1536);
      bn1_k<<<32, 256, 0, stream>>>(Y2, BNps, BNpq);
      bn2_k<<<1, 512, 0, stream>>>(BNps, BNpq, BNmu, BNvr);
      bnpool_k<<<(NB * 1024 * 512) / 256, 256, 0, stream>>>(
          Y2, BNmu, BNvr, bn_g, bn_b, X, Xb);
    }
  }

  // final LN + projection (N=32, fp32)
  ln_k<<<NB * 1024, 128, 0, stream>>>(X, nullptr, normf_g, normf_b, SCR, nullptr);
  gemm_k<<<dim3(1, 4096 / 64), 256, 0, stream>>>(SCR, proj_w, proj_b, out,
                                                 4096, 32, DM);
}

// Round 13
// 785.467 us; speedup vs baseline: 1.2021x; 1.0019x over previous
//
#include <hip/hip_runtime.h>
#include <cstdint>
#include <cmath>

// ---------------------------------------------------------------------------
// Informer encoder forward (B=4, L=2048, ENC_IN=32, D_MODEL=512, D_FF=2048,
// E_LAYERS=2, H=8, FACTOR=5).
// Round 13: double-buffered LDS staging in mgemm — prefetch tile k+1 before
// consuming tile k so the pre-barrier vmcnt drain overlaps compute (we're in
// the short-K latency-bound regime, not the m97 plateau). 1 barrier/step.
// NOTE: SQ_LDS_BANK_CONFLICT ~2.1M is inherent b128 data-volume serialization
// (1 KB/instr vs 128 B/clk LDS), not avoidable waste — r12 swizzle kept.
// ---------------------------------------------------------------------------

#define NB 4
#define DM 512
#define NH 8
#define HD 64
#define QS 1536  // QKV row stride

typedef unsigned short ushort_t;
typedef __bf16 bf16x8 __attribute__((ext_vector_type(8)));
typedef float floatx4 __attribute__((ext_vector_type(4)));
typedef unsigned short ushort8_t __attribute__((ext_vector_type(8)));

__device__ inline ushort_t f2b(float f) {
  uint32_t u = __float_as_uint(f);
  uint32_t r = (u + 0x7fffu + ((u >> 16) & 1u)) >> 16;
  return (ushort_t)r;
}
__device__ inline float b2f(ushort_t u) {
  return __uint_as_float((uint32_t)u << 16);
}

// ---------------- fused weight casts ---------------------------------------
__global__ void castqkv_k(const float* __restrict__ Wq,
                          const float* __restrict__ Wk,
                          const float* __restrict__ Wv,
                          ushort_t* __restrict__ out) {
  int gid = blockIdx.x * 256 + threadIdx.x;  // 393216 float4 units
  if (gid >= 393216) return;
  int ly = gid / 196608, r4 = gid - ly * 196608;
  int r = r4 >> 7, c4 = r4 & 127;
  int sel = r >> 9, srow = r & 511;
  const float* src = (sel == 0 ? Wq : sel == 1 ? Wk : Wv) + ly * 262144 +
                     srow * 512 + c4 * 4;
  float4 v = *(const float4*)src;
  ushort4 o;
  o.x = f2b(v.x); o.y = f2b(v.y); o.z = f2b(v.z); o.w = f2b(v.w);
  ((ushort4*)out)[ly * 196608 + r * 128 + c4] = o;
}

__global__ void castw3_k(const float* __restrict__ Wo,
                         const float* __restrict__ W1,
                         const float* __restrict__ W2,
                         const float* __restrict__ tw,
                         ushort_t* __restrict__ oWo, ushort_t* __restrict__ oW1,
                         ushort_t* __restrict__ oW2, ushort_t* __restrict__ otw) {
  int gid = blockIdx.x * 256 + threadIdx.x;  // 1,191,936 float4 units
  if (gid >= 1191936) return;
  const float* src;
  ushort4* dst;
  int i;
  if (gid < 131072) { src = Wo; dst = (ushort4*)oWo; i = gid; }
  else if (gid < 655360) { src = W1; dst = (ushort4*)oW1; i = gid - 131072; }
  else if (gid < 1179648) { src = W2; dst = (ushort4*)oW2; i = gid - 655360; }
  else { src = tw; dst = (ushort4*)otw; i = gid - 1179648; }
  float4 v = ((const float4*)src)[i];
  ushort4 o;
  o.x = f2b(v.x); o.y = f2b(v.y); o.z = f2b(v.z); o.w = f2b(v.w);
  dst[i] = o;
}

__global__ void castw_conv_k(const float* __restrict__ in,
                             ushort_t* __restrict__ out) {
  int gid = blockIdx.x * 256 + threadIdx.x;  // 512*1536
  int d = gid / 1536, r = gid - d * 1536;
  int t = r >> 9, i = r & 511;
  out[gid] = f2b(in[d * 1536 + i * 3 + t]);
}

__global__ void setup_small_k(const float* __restrict__ bq,
                              const float* __restrict__ bk,
                              const float* __restrict__ bv,
                              float* __restrict__ ZB,
                              float* __restrict__ BQKV) {
  int gid = blockIdx.x * 256 + threadIdx.x;  // 3584
  if (gid >= 3584) return;
  if (gid < 512) { ZB[gid] = 0.f; return; }
  int g = gid - 512;
  int layer = g / 1536, r = g - layer * 1536;
  float v;
  if (r < 512) v = bq[layer * 512 + r];
  else if (r < 1024) v = bk[layer * 512 + r - 512];
  else v = bv[layer * 512 + r - 1024];
  BQKV[g] = v;
}

__host__ __device__ inline void threefry2x32(uint32_t k0, uint32_t k1,
                                             uint32_t c0, uint32_t c1,
                                             uint32_t* o0, uint32_t* o1) {
  uint32_t ks0 = k0, ks1 = k1, ks2 = k0 ^ k1 ^ 0x1BD11BDAu;
  uint32_t x0 = c0 + ks0;
  uint32_t x1 = c1 + ks1;
  const uint32_t rotA[4] = {13u, 15u, 26u, 6u};
  const uint32_t rotB[4] = {17u, 29u, 16u, 24u};
  uint32_t ks[3] = {ks0, ks1, ks2};
  #pragma unroll
  for (int i = 0; i < 5; ++i) {
    const uint32_t* r = (i & 1) ? rotB : rotA;
    #pragma unroll
    for (int j = 0; j < 4; ++j) {
      x0 += x1;
      x1 = (x1 << r[j]) | (x1 >> (32u - r[j]));
      x1 ^= x0;
    }
    x0 += ks[(i + 1) % 3];
    x1 += ks[(i + 2) % 3] + (uint32_t)(i + 1);
  }
  *o0 = x0; *o1 = x1;
}

__global__ void gen_idx_k(int* __restrict__ idx, int n, int mask,
                          uint32_t k0, uint32_t k1) {
  int i = blockIdx.x * 256 + threadIdx.x;
  if (i < n) {
    uint32_t o0, o1;
    threefry2x32(k0, k1, 0u, (uint32_t)i, &o0, &o1);
    idx[i] = (int)((o0 ^ o1) & (uint32_t)mask);
  }
}

__device__ inline float wave_sum64(float v) {
  #pragma unroll
  for (int o = 32; o > 0; o >>= 1) v += __shfl_xor(v, o, 64);
  return v;
}
__device__ inline float wave_max64(float v) {
  #pragma unroll
  for (int o = 32; o > 0; o >>= 1) v = fmaxf(v, __shfl_xor(v, o, 64));
  return v;
}

// ---------------- positional-encoding table (2048 x 512) -------------------
__global__ void pe_k(float* __restrict__ pe) {
  int i = blockIdx.x * 256 + threadIdx.x;  // 1,048,576
  int d = i & 511, l = i >> 9;
  int j2 = d & ~1;
  float div = expf((float)j2 * -1.7988946039e-2f);  // -ln(10000)/512
  float ang = (float)l * div;
  pe[i] = (d & 1) ? cosf(ang) : sinf(ang);
}

// ---------------- im2col for token conv: (B*L, 96) bf16 --------------------
__global__ void im2col_tok_k(const float* __restrict__ xe,
                             ushort_t* __restrict__ A) {
  int gid = blockIdx.x * 256 + threadIdx.x;  // 8192*96
  int col = gid % 96;
  int row = gid / 96;
  int c = col / 3, t = col - c * 3;
  int b = row >> 11, l = row & 2047;
  int ls = (l + t - 1) & 2047;
  A[gid] = f2b(xe[((size_t)b * 2048 + ls) * 32 + c]);
}

// ---------------- bf16 MFMA GEMM, XCD swizzle + LDS double buffer ----------
__device__ inline void gload16(const ushort_t* g, ushort_t* l) {
  __builtin_amdgcn_global_load_lds(
      (const __attribute__((address_space(1))) unsigned int*)(const void*)g,
      (__attribute__((address_space(3))) unsigned int*)(void*)l, 16, 0, 0);
}

template <int GELU, int OMODE, int ADDPE>  // OMODE: 0 f32, 1 bf16, 2 both
__global__ __launch_bounds__(256) void mgemm_k(
    const ushort_t* __restrict__ A, const ushort_t* __restrict__ W,
    const float* __restrict__ bias, float* __restrict__ Cf,
    ushort_t* __restrict__ Cb, const float* __restrict__ pe,
    int X, int ldc, int K) {
  __shared__ ushort_t As[2][128 * 32];
  __shared__ ushort_t Bs[2][128 * 32];
  int id = blockIdx.x;
  int cc = id & 7, j = id >> 3;
  int bx = j % X;
  int by = (j / X) * 8 + cc;
  int m0 = by * 128, n0 = bx * 128;
  int t = threadIdx.x;
  int lane = t & 63, wv = t >> 6;
  // staging with XOR bank swizzle (kept from r12, neutral): lane fetches
  // global column group (pp ^ s(sr)) so LDS slot (sr,pp) holds that group.
  int sr = lane >> 2, pp = lane & 3;
  int sw = (sr & 3) ^ ((sr >> 2) & 3);
  int sc = (pp ^ sw) * 8;
  int ra0 = wv * 32 + sr, ra1 = ra0 + 16;
  const ushort_t* gA0 = A + (size_t)(m0 + ra0) * K + sc;
  const ushort_t* gA1 = A + (size_t)(m0 + ra1) * K + sc;
  const ushort_t* gB0 = W + (size_t)(n0 + ra0) * K + sc;
  const ushort_t* gB1 = W + (size_t)(n0 + ra1) * K + sc;
  int ldst = wv * 1024;

  int quad = lane >> 4, lr = lane & 15;
  int wm = wv >> 1, wn = wv & 1;
  int sR = (lr & 3) ^ ((lr >> 2) & 3);
  int rq = (quad ^ sR) * 8;

  // preload buffer 0
  gload16(gA0, As[0] + ldst);
  gload16(gA1, As[0] + ldst + 512);
  gload16(gB0, Bs[0] + ldst);
  gload16(gB1, Bs[0] + ldst + 512);
  gA0 += 32; gA1 += 32; gB0 += 32; gB1 += 32;
  __syncthreads();

  floatx4 acc[4][4] = {};
  int cur = 0;
  for (int ks = 0; ks < K; ks += 32) {
    int nxt = cur ^ 1;
    if (ks + 32 < K) {
      // prefetch next tile; its vmcnt drain at the end-of-step barrier is
      // overlapped by the ds_read+MFMA work below.
      gload16(gA0, As[nxt] + ldst);
      gload16(gA1, As[nxt] + ldst + 512);
      gload16(gB0, Bs[nxt] + ldst);
      gload16(gB1, Bs[nxt] + ldst + 512);
      gA0 += 32; gA1 += 32; gB0 += 32; gB1 += 32;
    }
    bf16x8 av[4], bv[4];
    #pragma unroll
    for (int mt = 0; mt < 4; ++mt)
      av[mt] = *(const bf16x8*)&As[cur][(wm * 64 + mt * 16 + lr) * 32 + rq];
    #pragma unroll
    for (int nt = 0; nt < 4; ++nt)
      bv[nt] = *(const bf16x8*)&Bs[cur][(wn * 64 + nt * 16 + lr) * 32 + rq];
    #pragma unroll
    for (int mt = 0; mt < 4; ++mt)
      #pragma unroll
      for (int nt = 0; nt < 4; ++nt)
        acc[mt][nt] = __builtin_amdgcn_mfma_f32_16x16x32_bf16(
            av[mt], bv[nt], acc[mt][nt], 0, 0, 0);
    __syncthreads();  // drains prefetch + protects cur for overwrite next iter
    cur = nxt;
  }
  #pragma unroll
  for (int nt = 0; nt < 4; ++nt) {
    int col = n0 + wn * 64 + nt * 16 + lr;
    float bsv = bias[col];
    #pragma unroll
    for (int mt = 0; mt < 4; ++mt) {
      int row0 = m0 + wm * 64 + mt * 16 + quad * 4;
      #pragma unroll
      for (int r = 0; r < 4; ++r) {
        int row = row0 + r;
        float v = acc[mt][nt][r] + bsv;
        if (ADDPE) v += pe[(size_t)(row & 2047) * ldc + col];
        if (GELU) v = 0.5f * v * (1.0f + erff(v * 0.70710678118654752f));
        if (OMODE == 0 || OMODE == 2) Cf[(size_t)row * ldc + col] = v;
        if (OMODE == 1 || OMODE == 2) Cb[(size_t)row * ldc + col] = f2b(v);
      }
    }
  }
}

// ---------------- fp32 fallback GEMM (final projection, N=32) --------------
__global__ __launch_bounds__(256) void gemm_k(
    const float* __restrict__ A, const float* __restrict__ W,
    const float* __restrict__ bias, float* __restrict__ C,
    int M, int N, int K) {
  __shared__ float As2[16][64 + 4];
  __shared__ float Ws2[16][64 + 4];
  int m0 = blockIdx.y * 64, n0 = blockIdx.x * 64;
  int t = threadIdx.x;
  int tx = t & 15, ty = t >> 4;
  float acc[4][4] = {};
  for (int k0 = 0; k0 < K; k0 += 16) {
    #pragma unroll
    for (int i = 0; i < 4; ++i) {
      int li = t + i * 256;
      int m = li >> 4, kk = li & 15;
      As2[kk][m] = A[(size_t)(m0 + m) * K + k0 + kk];
    }
    #pragma unroll
    for (int i = 0; i < 4; ++i) {
      int li = t + i * 256;
      int n = li >> 4, kk = li & 15;
      int gn = n0 + n;
      Ws2[kk][n] = (gn < N) ? W[(size_t)gn * K + k0 + kk] : 0.0f;
    }
    __syncthreads();
    #pragma unroll
    for (int kk = 0; kk < 16; ++kk) {
      float4 avv = *(const float4*)&As2[kk][ty * 4];
      float4 bvv = *(const float4*)&Ws2[kk][tx * 4];
      float a[4] = {avv.x, avv.y, avv.z, avv.w};
      float bb[4] = {bvv.x, bvv.y, bvv.z, bvv.w};
      #pragma unroll
      for (int i = 0; i < 4; ++i)
        #pragma unroll
        for (int j = 0; j < 4; ++j) acc[i][j] += a[i] * bb[j];
    }
    __syncthreads();
  }
  #pragma unroll
  for (int i = 0; i < 4; ++i) {
    int m = m0 + ty * 4 + i;
    #pragma unroll
    for (int j = 0; j < 4; ++j) {
      int n = n0 + tx * 4 + j;
      if (n < N) C[(size_t)m * N + n] = acc[i][j] + bias[n];
    }
  }
}

// ---------------- LayerNorm (+optional residual, +optional bf16 copy) ------
__global__ __launch_bounds__(128) void ln_k(
    const float* __restrict__ A, const float* __restrict__ Bres,
    const float* __restrict__ g, const float* __restrict__ be,
    float* __restrict__ O, ushort_t* __restrict__ Ob) {
  int r = blockIdx.x, t = threadIdx.x;
  __shared__ float lds[2];
  float4 v = ((const float4*)(A + (size_t)r * DM))[t];
  if (Bres) {
    float4 u = ((const float4*)(Bres + (size_t)r * DM))[t];
    v.x += u.x; v.y += u.y; v.z += u.z; v.w += u.w;
  }
  float s = wave_sum64(v.x + v.y + v.z + v.w);
  int w = t >> 6;
  if ((t & 63) == 0) lds[w] = s;
  __syncthreads();
  float mu = (lds[0] + lds[1]) * (1.0f / 512.0f);
  __syncthreads();
  float dx = v.x - mu, dy = v.y - mu, dz = v.z - mu, dw = v.w - mu;
  float sq = wave_sum64(dx * dx + dy * dy + dz * dz + dw * dw);
  if ((t & 63) == 0) lds[w] = sq;
  __syncthreads();
  float var = (lds[0] + lds[1]) * (1.0f / 512.0f);
  float inv = 1.0f / sqrtf(var + 1e-5f);
  float4 gv = ((const float4*)g)[t];
  float4 bv = ((const float4*)be)[t];
  float4 o;
  o.x = dx * inv * gv.x + bv.x;
  o.y = dy * inv * gv.y + bv.y;
  o.z = dz * inv * gv.z + bv.z;
  o.w = dw * inv * gv.w + bv.w;
  ((float4*)(O + (size_t)r * DM))[t] = o;
  if (Ob) {
    ushort4 ob;
    ob.x = f2b(o.x); ob.y = f2b(o.y); ob.z = f2b(o.z); ob.w = f2b(o.w);
    ((ushort4*)(Ob + (size_t)r * DM))[t] = ob;
  }
}

// ---------------- M[b,h,l]: one wave per (b,l), all-bf16 QKV ---------------
template <int UU>
__global__ __launch_bounds__(256) void qk_m_k(
    const ushort_t* __restrict__ QKVb, const int* __restrict__ idx,
    float* __restrict__ Mout, int Lx) {
  int l = blockIdx.x;
  int b = threadIdx.x >> 6;  // wave = batch
  int lane = threadIdx.x & 63;
  const ushort_t* qp = QKVb + ((size_t)b * Lx + l) * QS + lane * 8;
  float q[8];
  {
    ushort8_t qv = *(const ushort8_t*)qp;
    #pragma unroll
    for (int c = 0; c < 8; ++c) q[c] = b2f(qv[c]);
  }
  const ushort_t* Kbase = QKVb + (size_t)b * Lx * QS + 512 + lane * 8;
  const int* ip = idx + (size_t)l * UU;
  float maxv = -INFINITY, sumv = 0.f;
  #pragma unroll
  for (int u0 = 0; u0 < UU; u0 += 8) {
    ushort8_t kv[8];
    #pragma unroll
    for (int j = 0; j < 8; ++j) {
      if (u0 + j < UU)
        kv[j] = *(const ushort8_t*)(Kbase + (size_t)ip[u0 + j] * QS);
    }
    #pragma unroll
    for (int j = 0; j < 8; ++j) {
      if (u0 + j < UU) {
        float p = 0.f;
        #pragma unroll
        for (int c = 0; c < 8; ++c) p += q[c] * b2f(kv[j][c]);
        p += __shfl_xor(p, 1, 64);
        p += __shfl_xor(p, 2, 64);
        p += __shfl_xor(p, 4, 64);
        maxv = fmaxf(maxv, p);
        sumv += p;
      }
    }
  }
  if ((lane & 7) == 0) {
    int h = lane >> 3;
    Mout[(size_t)(b * 8 + h) * Lx + l] = maxv - sumv / (float)Lx;
  }
}

// ---------------- rank-based top-U, chunked (exact JAX tie-breaking) -------
__global__ __launch_bounds__(256) void topk_k(
    const float* __restrict__ Mbuf, int* __restrict__ Mtop, int Lx, int U) {
  int nch = Lx >> 8;
  int bh = blockIdx.x / nch, ch = blockIdx.x % nch;
  const float* m = Mbuf + (size_t)bh * Lx;
  __shared__ float sm[2048];
  int t = threadIdx.x;
  for (int i = t; i < Lx; i += 256) sm[i] = m[i];
  __syncthreads();
  int i0 = (ch << 8) + t;
  float v0 = sm[i0];
  int r0 = 0;
  for (int j = 0; j < Lx; j += 4) {
    float4 mj = *(const float4*)&sm[j];
    r0 += (mj.x > v0) || (mj.x == v0 && (j + 0) < i0);
    r0 += (mj.y > v0) || (mj.y == v0 && (j + 1) < i0);
    r0 += (mj.z > v0) || (mj.z == v0 && (j + 2) < i0);
    r0 += (mj.w > v0) || (mj.w == v0 && (j + 3) < i0);
  }
  if (r0 < U) Mtop[bh * U + r0] = i0;
}

// ---------------- meanV from bf16 QKV (V at +1024) -------------------------
__global__ __launch_bounds__(512) void meanv1_k(const ushort_t* __restrict__ QKVb,
                                                float* __restrict__ part,
                                                int Lx) {
  int b = blockIdx.x >> 4, chunk = blockIdx.x & 15;
  int rows = Lx >> 4;
  int t = threadIdx.x;  // 512
  const ushort_t* vp =
      QKVb + ((size_t)b * Lx + (size_t)chunk * rows) * QS + 1024 + t;
  float s = 0.f;
  for (int l = 0; l < rows; ++l) s += b2f(vp[(size_t)l * QS]);
  part[(size_t)blockIdx.x * DM + t] = s;
}
__global__ __launch_bounds__(512) void meanv2_k(const float* __restrict__ part,
                                                float* __restrict__ mv,
                                                int Lx) {
  int b = blockIdx.x, t = threadIdx.x;
  float s = 0.f;
  #pragma unroll
  for (int c = 0; c < 16; ++c) s += part[(size_t)(b * 16 + c) * DM + t];
  mv[b * DM + t] = s / (float)Lx;
}

__global__ void fillctx_k(ushort_t* __restrict__ ctx,
                          const float* __restrict__ mv, int Lx) {
  size_t i4 = (size_t)blockIdx.x * 256 + threadIdx.x;
  int col4 = (int)(i4 & 127);
  size_t row = i4 >> 7;
  int b = (int)(row / (size_t)Lx);
  const float* m = mv + b * DM + col4 * 4;
  ushort4 o;
  o.x = f2b(m[0]); o.y = f2b(m[1]); o.z = f2b(m[2]); o.w = f2b(m[3]);
  ((ushort4*)ctx)[i4] = o;
}

// ---------------- flash split-K attention (bf16 QKV) -----------------------
__global__ __launch_bounds__(512) void attn_flash_k(
    const ushort_t* __restrict__ QKVb, const int* __restrict__ Mtop,
    float* __restrict__ part, int Lx, int U, int nchunk) {
  int blk = blockIdx.x;
  int chunk = blk % nchunk, bh = blk / nchunk;
  int h = bh & 7, b = bh >> 3;
  int rows = Lx / nchunk;
  int ntile = rows >> 6;
  __shared__ float s_q[40 * 64];
  __shared__ float s_k[64 * 65];
  __shared__ float s_v[64 * 65];
  __shared__ float s_p[40 * 64];
  __shared__ float s_m[40], s_l[40], s_a[40];
  int t = threadIdx.x;
  int d = t & 63, wv = t >> 6;

  for (int i = t; i < U * 64; i += 512) {
    int u = i >> 6, dd = i & 63;
    int qi = Mtop[bh * U + u];
    s_q[i] = b2f(QKVb[((size_t)b * Lx + qi) * QS + h * HD + dd]) * 0.125f;
  }
  if (t < U) { s_m[t] = -INFINITY; s_l[t] = 0.f; s_a[t] = 0.f; }
  float o[5] = {0.f, 0.f, 0.f, 0.f, 0.f};
  __syncthreads();

  const ushort_t* Kp = QKVb + (size_t)b * Lx * QS + 512 + h * HD;
  const ushort_t* Vp = QKVb + (size_t)b * Lx * QS + 1024 + h * HD;

  for (int tile = 0; tile < ntile; ++tile) {
    int kr0 = chunk * rows + tile * 64;
    {
      int r = t >> 3, c8 = (t & 7) * 8;  // 8 threads/row x 64 rows
      ushort8_t kv = *(const ushort8_t*)&Kp[(size_t)(kr0 + r) * QS + c8];
      ushort8_t vv = *(const ushort8_t*)&Vp[(size_t)(kr0 + r) * QS + c8];
      float* kd = &s_k[r * 65 + c8];
      float* vd = &s_v[r * 65 + c8];
      #pragma unroll
      for (int jj = 0; jj < 8; ++jj) {
        kd[jj] = b2f(kv[jj]);
        vd[jj] = b2f(vv[jj]);
      }
    }
    __syncthreads();
    {
      float kr[64];
      #pragma unroll
      for (int dd = 0; dd < 64; ++dd) kr[dd] = s_k[d * 65 + dd];
      for (int u = wv; u < U; u += 8) {
        float acc = 0.f;
        #pragma unroll
        for (int c = 0; c < 16; ++c) {
          float4 qv = *(const float4*)&s_q[u * 64 + c * 4];
          acc += qv.x * kr[c * 4] + qv.y * kr[c * 4 + 1] +
                 qv.z * kr[c * 4 + 2] + qv.w * kr[c * 4 + 3];
        }
        s_p[u * 64 + d] = acc;
      }
    }
    __syncthreads();
    for (int u = wv; u < U; u += 8) {
      float sv_ = s_p[u * 64 + d];
      float mx = wave_max64(sv_);
      float mold = s_m[u];
      float mnew = fmaxf(mold, mx);
      float e = expf(sv_ - mnew);
      float se = wave_sum64(e);
      s_p[u * 64 + d] = e;
      if (d == 0) {
        float alpha = expf(mold - mnew);
        s_a[u] = alpha;
        s_l[u] = s_l[u] * alpha + se;
        s_m[u] = mnew;
      }
    }
    __syncthreads();
    {
      float vr[64];
      #pragma unroll
      for (int k = 0; k < 64; ++k) vr[k] = s_v[k * 65 + d];
      int i = 0;
      for (int u = wv; u < U; u += 8, ++i) {
        float acc = 0.f;
        #pragma unroll
        for (int c = 0; c < 16; ++c) {
          float4 pv = *(const float4*)&s_p[u * 64 + c * 4];
          acc += pv.x * vr[c * 4] + pv.y * vr[c * 4 + 1] +
                 pv.z * vr[c * 4 + 2] + pv.w * vr[c * 4 + 3];
        }
        o[i] = o[i] * s_a[u] + acc;
      }
    }
    __syncthreads();
  }
  {
    int i = 0;
    for (int u = wv; u < U; u += 8, ++i) {
      float* pp = part + ((size_t)(bh * nchunk + chunk) * U + u) * 66;
      pp[d] = o[i];
      if (d == 0) { pp[64] = s_m[u]; pp[65] = s_l[u]; }
    }
  }
}

__global__ __launch_bounds__(64) void attn_merge_k(
    const float* __restrict__ part, const int* __restrict__ Mtop,
    ushort_t* __restrict__ ctx, int Lx, int U, int nchunk) {
  int bu = blockIdx.x;
  int u = bu % U, bh = bu / U;
  int h = bh & 7, b = bh >> 3;
  int d = threadIdx.x;  // 64
  float M = -INFINITY;
  for (int c = 0; c < nchunk; ++c)
    M = fmaxf(M, part[((size_t)(bh * nchunk + c) * U + u) * 66 + 64]);
  float L = 0.f, O = 0.f;
  for (int c = 0; c < nchunk; ++c) {
    const float* pp = part + ((size_t)(bh * nchunk + c) * U + u) * 66;
    float w = expf(pp[64] - M);
    L += pp[65] * w;
    O += pp[d] * w;
  }
  int qi = Mtop[bh * U + u];
  ctx[((size_t)b * Lx + qi) * DM + h * HD + d] = f2b(O / L);
}

// ---------------- distil im2col (circular, k=3) -> bf16, [t][c] layout -----
__global__ void im2col_k(const float* __restrict__ X,
                         ushort_t* __restrict__ A2) {
  int gid = blockIdx.x * 256 + threadIdx.x;  // 8192*3*128 ushort4 units
  int i4 = gid & 127;
  int rt = gid >> 7;
  int t = rt % 3, row = rt / 3;
  int b = row >> 11, l = row & 2047;
  int ls = (l + t - 1) & 2047;
  float4 v = ((const float4*)(X + ((size_t)b * 2048 + ls) * DM))[i4];
  ushort4 o;
  o.x = f2b(v.x); o.y = f2b(v.y); o.z = f2b(v.z); o.w = f2b(v.w);
  ((ushort4*)A2)[(size_t)row * 384 + t * 128 + i4] = o;
}

// ---------------- batch-norm stats: coalesced two-stage --------------------
__global__ __launch_bounds__(256) void bn1_k(const float* __restrict__ Y,
                                             float* __restrict__ ps,
                                             float* __restrict__ pq) {
  int blk = blockIdx.x;
  int t = threadIdx.x;
  float s0 = 0, q0 = 0, s1 = 0, q1 = 0;
  const float* base = Y + (size_t)blk * 256 * DM;
  for (int r = 0; r < 256; ++r) {
    float a = base[(size_t)r * DM + t];
    float b = base[(size_t)r * DM + t + 256];
    s0 += a; q0 += a * a; s1 += b; q1 += b * b;
  }
  ps[blk * DM + t] = s0; ps[blk * DM + t + 256] = s1;
  pq[blk * DM + t] = q0; pq[blk * DM + t + 256] = q1;
}
__global__ __launch_bounds__(512) void bn2_k(const float* __restrict__ ps,
                                             const float* __restrict__ pq,
                                             float* __restrict__ mu,
                                             float* __restrict__ var) {
  int t = threadIdx.x;
  float s = 0, q = 0;
  #pragma unroll
  for (int c = 0; c < 32; ++c) { s += ps[c * DM + t]; q += pq[c * DM + t]; }
  float m = s * (1.0f / 8192.f);
  mu[t] = m;
  var[t] = q * (1.0f / 8192.f) - m * m;
}

// fused bn+elu+maxpool(k=3,s=2,pad=1)
__global__ void bnpool_k(const float* __restrict__ Y,
                         const float* __restrict__ mu,
                         const float* __restrict__ var,
                         const float* __restrict__ g,
                         const float* __restrict__ be, float* __restrict__ O,
                         ushort_t* __restrict__ Ob) {
  size_t i = (size_t)blockIdx.x * 256 + threadIdx.x;  // 4*1024*512
  int c = (int)(i & 511);
  size_t row = i >> 9;
  int lo = (int)(row & 1023);
  int b = (int)(row >> 10);
  float sc = g[c] / sqrtf(var[c] + 1e-5f);
  float sh = be[c] - mu[c] * sc;
  int l0 = 2 * lo - 1;
  float m = -INFINITY;
  #pragma unroll
  for (int tt = 0; tt < 3; ++tt) {
    int l = l0 + tt;
    if (l >= 0 && l < 2048) {
      float v = Y[((size_t)b * 2048 + l) * DM + c] * sc + sh;
      v = v > 0.f ? v : expm1f(v);
      m = fmaxf(m, v);
    }
  }
  O[i] = m;
  Ob[i] = f2b(m);
}

// ---------------------------------------------------------------------------
extern "C" void kernel_launch(void* const* d_in, const int* in_sizes, int n_in,
                              void* d_out, int out_size, void* d_ws,
                              size_t ws_size, hipStream_t stream) {
  (void)in_sizes; (void)n_in; (void)out_size; (void)ws_size;
  const float* x_enc  = (const float*)d_in[0];
  const float* tok_w  = (const float*)d_in[1];
  const float* Wq     = (const float*)d_in[2];
  const float* bq     = (const float*)d_in[3];
  const float* Wk     = (const float*)d_in[4];
  const float* bk     = (const float*)d_in[5];
  const float* Wv     = (const float*)d_in[6];
  const float* bv     = (const float*)d_in[7];
  const float* Wo     = (const float*)d_in[8];
  const float* bo     = (const float*)d_in[9];
  const float* W1     = (const float*)d_in[10];
  const float* b1     = (const float*)d_in[11];
  const float* W2     = (const float*)d_in[12];
  const float* b2     = (const float*)d_in[13];
  const float* ln1_g  = (const float*)d_in[14];
  const float* ln1_b  = (const float*)d_in[15];
  const float* ln2_g  = (const float*)d_in[16];
  const float* ln2_b  = (const float*)d_in[17];
  const float* conv_w = (const float*)d_in[18];
  const float* conv_b = (const float*)d_in[19];
  const float* bn_g   = (const float*)d_in[20];
  const float* bn_b   = (const float*)d_in[21];
  const float* normf_g = (const float*)d_in[22];
  const float* normf_b = (const float*)d_in[23];
  const float* proj_w = (const float*)d_in[24];
  const float* proj_b = (const float*)d_in[25];
  float* out = (float*)d_out;
  float* ws = (float*)d_ws;

  // ---- fp32 workspace layout (float offsets) ----
  float* X    = ws;                    // 4,194,304
  float* SCR  = ws + 4194304;          // 12,582,912 (final-LN scratch)
  ushort_t* CTXb = (ushort_t*)(ws + 16777216);  // bf16 ctx
  float* Y2   = ws + 20971520;         // 4,194,304 (attn partials / conv out)
  float* Mb   = ws + 25165824;         // 65,536
  float* MV   = ws + 25231360;         // 2,048
  float* MVP  = ws + 25233408;         // 32,768
  float* BNps = ws + 25266176;         // 16,384
  float* BNpq = ws + 25282560;         // 16,384
  float* BNmu = ws + 25298944;         // 512
  float* BNvr = ws + 25299456;         // 512
  float* ZB   = ws + 25299968;         // 512 (zero bias)
  float* BQKV = ws + 25300480;         // 3,072 (concat qkv bias, 2 layers)
  int*   IDX  = (int*)(ws + 25303552); // 81,920
  int*   MT   = (int*)(ws + 25385472); // 1,280
  // ---- bf16 workspace ----
  ushort_t* U0   = (ushort_t*)(ws + 25386752);
  ushort_t* Xb   = U0;                 // 4,194,304
  ushort_t* Hb   = U0 + 4194304;       // 16,777,216 (FFN hidden / im2col)
  ushort_t* QKVb = Hb;                 // alias: bf16 QKV — live QKV-GEMM ->
                                       // attn, before FFN uses Hb
  ushort_t* Wqkvb= U0 + 20971520;      // 1,572,864
  ushort_t* Wob  = U0 + 22544384;      // 524,288
  ushort_t* W1b  = U0 + 23068672;      // 2,097,152
  ushort_t* W2b  = U0 + 25165824;      // 2,097,152
  ushort_t* Cwb  = U0 + 27262976;      // 786,432
  ushort_t* Twb  = U0 + 28049408;      // 49,152
  ushort_t* Atok = U0 + 28098560;      // 786,432
  float* PEf = ws + 39829248;          // 1,048,576 (PE table)

  // ---- fused preamble ----
  castqkv_k<<<1536, 256, 0, stream>>>(Wq, Wk, Wv, Wqkvb);
  castw3_k<<<4656, 256, 0, stream>>>(Wo, W1, W2, tok_w, Wob, W1b, W2b, Twb);
  castw_conv_k<<<3072, 256, 0, stream>>>(conv_w, Cwb);
  setup_small_k<<<14, 256, 0, stream>>>(bq, bk, bv, ZB, BQKV);
  pe_k<<<4096, 256, 0, stream>>>(PEf);
  im2col_tok_k<<<3072, 256, 0, stream>>>(x_enc, Atok);

  // token embedding GEMM (+PE): X=4, Y=64 -> 256 blocks
  mgemm_k<0, 2, 1><<<256, 256, 0, stream>>>(
      Atok, Twb, ZB, X, Xb, PEf, 4, DM, 96);

  for (int layer = 0; layer < 2; ++layer) {
    const int Lx = (layer == 0) ? 2048 : 1024;
    const int U  = (layer == 0) ? 40 : 35;
    const int M  = NB * Lx;
    const int Yt = M / 128;
    const int NCH = 8;

    uint32_t kl0, kl1, s0, s1;
    threefry2x32(0u, 42u, 0u, (uint32_t)layer, &kl0, &kl1);
    threefry2x32(kl0, kl1, 0u, 1u, &s0, &s1);
    int nidx = Lx * U;
    gen_idx_k<<<(nidx + 255) / 256, 256, 0, stream>>>(IDX, nidx, Lx - 1, s0, s1);

    // fused QKV GEMM: bf16-only output, XCD-swizzled, double-buffered
    mgemm_k<0, 1, 0><<<12 * Yt, 256, 0, stream>>>(
        Xb, Wqkvb + (size_t)layer * 786432, BQKV + layer * 1536, nullptr, QKVb,
        nullptr, 12, QS, DM);

    // ProbSparse attention (all bf16 QKV)
    if (layer == 0)
      qk_m_k<40><<<Lx, 256, 0, stream>>>(QKVb, IDX, Mb, Lx);
    else
      qk_m_k<35><<<Lx, 256, 0, stream>>>(QKVb, IDX, Mb, Lx);
    topk_k<<<NB * NH * (Lx >> 8), 256, 0, stream>>>(Mb, MT, Lx, U);
    meanv1_k<<<NB * 16, 512, 0, stream>>>(QKVb, MVP, Lx);
    meanv2_k<<<NB, 512, 0, stream>>>(MVP, MV, Lx);
    fillctx_k<<<(M * DM / 4) / 256, 256, 0, stream>>>(CTXb, MV, Lx);
    attn_flash_k<<<NB * NH * NCH, 512, 0, stream>>>(QKVb, MT, Y2, Lx, U, NCH);
    attn_merge_k<<<NB * NH * U, 64, 0, stream>>>(Y2, MT, CTXb, Lx, U, NCH);

    // output projection + residual + LN1 (emits bf16 for FFN1)
    mgemm_k<0, 0, 0><<<4 * Yt, 256, 0, stream>>>(
        CTXb, Wob + (size_t)layer * 262144, bo + layer * DM, Y2, nullptr,
        nullptr, 4, DM, DM);
    ln_k<<<M, 128, 0, stream>>>(X, Y2, ln1_g + layer * DM, ln1_b + layer * DM, X, Xb);

    // FFN (GELU fused; hidden kept in bf16); LN2 emits bf16
    mgemm_k<1, 1, 0><<<16 * Yt, 256, 0, stream>>>(
        Xb, W1b + (size_t)layer * 1048576, b1 + layer * 2048, nullptr, Hb,
        nullptr, 16, 2048, DM);
    mgemm_k<0, 0, 0><<<4 * Yt, 256, 0, stream>>>(
        Hb, W2b + (size_t)layer * 1048576, b2 + layer * DM, Y2, nullptr,
        nullptr, 4, DM, 2048);
    ln_k<<<M, 128, 0, stream>>>(X, Y2, ln2_g + layer * DM, ln2_b + layer * DM, X, Xb);

    if (layer == 0) {
      im2col_k<<<12288, 256, 0, stream>>>(X, Hb);
      mgemm_k<0, 0, 0><<<4 * 64, 256, 0, stream>>>(
          Hb, Cwb, conv_b, Y2, nullptr, nullptr, 4, DM, 1536);
      bn1_k<<<32, 256, 0, stream>>>(Y2, BNps, BNpq);
      bn2_k<<<1, 512, 0, stream>>>(BNps, BNpq, BNmu, BNvr);
      bnpool_k<<<(NB * 1024 * 512) / 256, 256, 0, stream>>>(
          Y2, BNmu, BNvr, bn_g, bn_b, X, Xb);
    }
  }

  // final LN + projection (N=32, fp32)
  ln_k<<<NB * 1024, 128, 0, stream>>>(X, nullptr, normf_g, normf_b, SCR, nullptr);
  gemm_k<<<dim3(1, 4096 / 64), 256, 0, stream>>>(SCR, proj_w, proj_b, out,
                                                 4096, 32, DM);
}

// Round 14
// 778.271 us; speedup vs baseline: 1.2132x; 1.0092x over previous
//
#include <hip/hip_runtime.h>
#include <cstdint>
#include <cmath>

// ---------------------------------------------------------------------------
// Informer encoder forward (B=4, L=2048, ENC_IN=32, D_MODEL=512, D_FF=2048,
// E_LAYERS=2, H=8, FACTOR=5).
// Round 14: BK=64 K-tiles in mgemm (8 steps for K=512 instead of 16) — halves
// the per-step barrier/vmcnt-drain events that dominate the latency-bound
// GEMMs. Single-buffer 32 KB LDS; dbuf (r13) and XOR swizzle (r12) removed
// (both measured neutral). Token GEMM (K=96) keeps BK=32 via template.
// ---------------------------------------------------------------------------

#define NB 4
#define DM 512
#define NH 8
#define HD 64
#define QS 1536  // QKV row stride

typedef unsigned short ushort_t;
typedef __bf16 bf16x8 __attribute__((ext_vector_type(8)));
typedef float floatx4 __attribute__((ext_vector_type(4)));
typedef unsigned short ushort8_t __attribute__((ext_vector_type(8)));

__device__ inline ushort_t f2b(float f) {
  uint32_t u = __float_as_uint(f);
  uint32_t r = (u + 0x7fffu + ((u >> 16) & 1u)) >> 16;
  return (ushort_t)r;
}
__device__ inline float b2f(ushort_t u) {
  return __uint_as_float((uint32_t)u << 16);
}

// ---------------- fused weight casts ---------------------------------------
__global__ void castqkv_k(const float* __restrict__ Wq,
                          const float* __restrict__ Wk,
                          const float* __restrict__ Wv,
                          ushort_t* __restrict__ out) {
  int gid = blockIdx.x * 256 + threadIdx.x;  // 393216 float4 units
  if (gid >= 393216) return;
  int ly = gid / 196608, r4 = gid - ly * 196608;
  int r = r4 >> 7, c4 = r4 & 127;
  int sel = r >> 9, srow = r & 511;
  const float* src = (sel == 0 ? Wq : sel == 1 ? Wk : Wv) + ly * 262144 +
                     srow * 512 + c4 * 4;
  float4 v = *(const float4*)src;
  ushort4 o;
  o.x = f2b(v.x); o.y = f2b(v.y); o.z = f2b(v.z); o.w = f2b(v.w);
  ((ushort4*)out)[ly * 196608 + r * 128 + c4] = o;
}

__global__ void castw3_k(const float* __restrict__ Wo,
                         const float* __restrict__ W1,
                         const float* __restrict__ W2,
                         const float* __restrict__ tw,
                         ushort_t* __restrict__ oWo, ushort_t* __restrict__ oW1,
                         ushort_t* __restrict__ oW2, ushort_t* __restrict__ otw) {
  int gid = blockIdx.x * 256 + threadIdx.x;  // 1,191,936 float4 units
  if (gid >= 1191936) return;
  const float* src;
  ushort4* dst;
  int i;
  if (gid < 131072) { src = Wo; dst = (ushort4*)oWo; i = gid; }
  else if (gid < 655360) { src = W1; dst = (ushort4*)oW1; i = gid - 131072; }
  else if (gid < 1179648) { src = W2; dst = (ushort4*)oW2; i = gid - 655360; }
  else { src = tw; dst = (ushort4*)otw; i = gid - 1179648; }
  float4 v = ((const float4*)src)[i];
  ushort4 o;
  o.x = f2b(v.x); o.y = f2b(v.y); o.z = f2b(v.z); o.w = f2b(v.w);
  dst[i] = o;
}

__global__ void castw_conv_k(const float* __restrict__ in,
                             ushort_t* __restrict__ out) {
  int gid = blockIdx.x * 256 + threadIdx.x;  // 512*1536
  int d = gid / 1536, r = gid - d * 1536;
  int t = r >> 9, i = r & 511;
  out[gid] = f2b(in[d * 1536 + i * 3 + t]);
}

__global__ void setup_small_k(const float* __restrict__ bq,
                              const float* __restrict__ bk,
                              const float* __restrict__ bv,
                              float* __restrict__ ZB,
                              float* __restrict__ BQKV) {
  int gid = blockIdx.x * 256 + threadIdx.x;  // 3584
  if (gid >= 3584) return;
  if (gid < 512) { ZB[gid] = 0.f; return; }
  int g = gid - 512;
  int layer = g / 1536, r = g - layer * 1536;
  float v;
  if (r < 512) v = bq[layer * 512 + r];
  else if (r < 1024) v = bk[layer * 512 + r - 512];
  else v = bv[layer * 512 + r - 1024];
  BQKV[g] = v;
}

__host__ __device__ inline void threefry2x32(uint32_t k0, uint32_t k1,
                                             uint32_t c0, uint32_t c1,
                                             uint32_t* o0, uint32_t* o1) {
  uint32_t ks0 = k0, ks1 = k1, ks2 = k0 ^ k1 ^ 0x1BD11BDAu;
  uint32_t x0 = c0 + ks0;
  uint32_t x1 = c1 + ks1;
  const uint32_t rotA[4] = {13u, 15u, 26u, 6u};
  const uint32_t rotB[4] = {17u, 29u, 16u, 24u};
  uint32_t ks[3] = {ks0, ks1, ks2};
  #pragma unroll
  for (int i = 0; i < 5; ++i) {
    const uint32_t* r = (i & 1) ? rotB : rotA;
    #pragma unroll
    for (int j = 0; j < 4; ++j) {
      x0 += x1;
      x1 = (x1 << r[j]) | (x1 >> (32u - r[j]));
      x1 ^= x0;
    }
    x0 += ks[(i + 1) % 3];
    x1 += ks[(i + 2) % 3] + (uint32_t)(i + 1);
  }
  *o0 = x0; *o1 = x1;
}

__global__ void gen_idx_k(int* __restrict__ idx, int n, int mask,
                          uint32_t k0, uint32_t k1) {
  int i = blockIdx.x * 256 + threadIdx.x;
  if (i < n) {
    uint32_t o0, o1;
    threefry2x32(k0, k1, 0u, (uint32_t)i, &o0, &o1);
    idx[i] = (int)((o0 ^ o1) & (uint32_t)mask);
  }
}

__device__ inline float wave_sum64(float v) {
  #pragma unroll
  for (int o = 32; o > 0; o >>= 1) v += __shfl_xor(v, o, 64);
  return v;
}
__device__ inline float wave_max64(float v) {
  #pragma unroll
  for (int o = 32; o > 0; o >>= 1) v = fmaxf(v, __shfl_xor(v, o, 64));
  return v;
}

// ---------------- positional-encoding table (2048 x 512) -------------------
__global__ void pe_k(float* __restrict__ pe) {
  int i = blockIdx.x * 256 + threadIdx.x;  // 1,048,576
  int d = i & 511, l = i >> 9;
  int j2 = d & ~1;
  float div = expf((float)j2 * -1.7988946039e-2f);  // -ln(10000)/512
  float ang = (float)l * div;
  pe[i] = (d & 1) ? cosf(ang) : sinf(ang);
}

// ---------------- im2col for token conv: (B*L, 96) bf16 --------------------
__global__ void im2col_tok_k(const float* __restrict__ xe,
                             ushort_t* __restrict__ A) {
  int gid = blockIdx.x * 256 + threadIdx.x;  // 8192*96
  int col = gid % 96;
  int row = gid / 96;
  int c = col / 3, t = col - c * 3;
  int b = row >> 11, l = row & 2047;
  int ls = (l + t - 1) & 2047;
  A[gid] = f2b(xe[((size_t)b * 2048 + ls) * 32 + c]);
}

// ---------------- bf16 MFMA GEMM, XCD swizzle, template BK -----------------
__device__ inline void gload16(const ushort_t* g, ushort_t* l) {
  __builtin_amdgcn_global_load_lds(
      (const __attribute__((address_space(1))) unsigned int*)(const void*)g,
      (__attribute__((address_space(3))) unsigned int*)(void*)l, 16, 0, 0);
}

// 128x128 tile, 4 waves (2x2 of 64x64), K-tile = BK (32 or 64).
template <int BK, int GELU, int OMODE, int ADDPE>  // OMODE: 0 f32,1 bf16,2 both
__global__ __launch_bounds__(256) void mgemm_k(
    const ushort_t* __restrict__ A, const ushort_t* __restrict__ W,
    const float* __restrict__ bias, float* __restrict__ Cf,
    ushort_t* __restrict__ Cb, const float* __restrict__ pe,
    int X, int ldc, int K) {
  __shared__ ushort_t As[128 * BK];
  __shared__ ushort_t Bs[128 * BK];
  int id = blockIdx.x;
  int cc = id & 7, j = id >> 3;
  int bx = j % X;
  int by = (j / X) * 8 + cc;
  int m0 = by * 128, n0 = bx * 128;
  int t = threadIdx.x;
  int lane = t & 63, wv = t >> 6;

  const int RPG = 512 / BK;  // rows covered per gload16 (1 KB)
  const int NG = BK / 16;    // gloads per matrix per wave (covers 32 rows)
  int rl = lane / (BK / 8);
  int cl = (lane % (BK / 8)) * 8;

  const ushort_t* gA[NG];
  const ushort_t* gB[NG];
  ushort_t* lA[NG];
  ushort_t* lB[NG];
  #pragma unroll
  for (int g = 0; g < NG; ++g) {
    int R = wv * 32 + g * RPG;  // local row of this gload's 1 KB chunk
    gA[g] = A + (size_t)(m0 + R + rl) * K + cl;
    gB[g] = W + (size_t)(n0 + R + rl) * K + cl;
    lA[g] = As + R * BK;
    lB[g] = Bs + R * BK;
  }

  int quad = lane >> 4, lr = lane & 15;
  int wm = wv >> 1, wn = wv & 1;

  floatx4 acc[4][4] = {};
  for (int ks = 0; ks < K; ks += BK) {
    if (ks > 0) __syncthreads();  // protect LDS reuse
    #pragma unroll
    for (int g = 0; g < NG; ++g) {
      gload16(gA[g], lA[g]);
      gload16(gB[g], lB[g]);
      gA[g] += BK;
      gB[g] += BK;
    }
    __syncthreads();  // drain staging loads
    #pragma unroll
    for (int kk = 0; kk < BK / 32; ++kk) {
      bf16x8 av[4], bv[4];
      #pragma unroll
      for (int mt = 0; mt < 4; ++mt)
        av[mt] = *(const bf16x8*)
            &As[(wm * 64 + mt * 16 + lr) * BK + kk * 32 + quad * 8];
      #pragma unroll
      for (int nt = 0; nt < 4; ++nt)
        bv[nt] = *(const bf16x8*)
            &Bs[(wn * 64 + nt * 16 + lr) * BK + kk * 32 + quad * 8];
      #pragma unroll
      for (int mt = 0; mt < 4; ++mt)
        #pragma unroll
        for (int nt = 0; nt < 4; ++nt)
          acc[mt][nt] = __builtin_amdgcn_mfma_f32_16x16x32_bf16(
              av[mt], bv[nt], acc[mt][nt], 0, 0, 0);
    }
  }
  #pragma unroll
  for (int nt = 0; nt < 4; ++nt) {
    int col = n0 + wn * 64 + nt * 16 + lr;
    float bsv = bias[col];
    #pragma unroll
    for (int mt = 0; mt < 4; ++mt) {
      int row0 = m0 + wm * 64 + mt * 16 + quad * 4;
      #pragma unroll
      for (int r = 0; r < 4; ++r) {
        int row = row0 + r;
        float v = acc[mt][nt][r] + bsv;
        if (ADDPE) v += pe[(size_t)(row & 2047) * ldc + col];
        if (GELU) v = 0.5f * v * (1.0f + erff(v * 0.70710678118654752f));
        if (OMODE == 0 || OMODE == 2) Cf[(size_t)row * ldc + col] = v;
        if (OMODE == 1 || OMODE == 2) Cb[(size_t)row * ldc + col] = f2b(v);
      }
    }
  }
}

// ---------------- fp32 fallback GEMM (final projection, N=32) --------------
__global__ __launch_bounds__(256) void gemm_k(
    const float* __restrict__ A, const float* __restrict__ W,
    const float* __restrict__ bias, float* __restrict__ C,
    int M, int N, int K) {
  __shared__ float As2[16][64 + 4];
  __shared__ float Ws2[16][64 + 4];
  int m0 = blockIdx.y * 64, n0 = blockIdx.x * 64;
  int t = threadIdx.x;
  int tx = t & 15, ty = t >> 4;
  float acc[4][4] = {};
  for (int k0 = 0; k0 < K; k0 += 16) {
    #pragma unroll
    for (int i = 0; i < 4; ++i) {
      int li = t + i * 256;
      int m = li >> 4, kk = li & 15;
      As2[kk][m] = A[(size_t)(m0 + m) * K + k0 + kk];
    }
    #pragma unroll
    for (int i = 0; i < 4; ++i) {
      int li = t + i * 256;
      int n = li >> 4, kk = li & 15;
      int gn = n0 + n;
      Ws2[kk][n] = (gn < N) ? W[(size_t)gn * K + k0 + kk] : 0.0f;
    }
    __syncthreads();
    #pragma unroll
    for (int kk = 0; kk < 16; ++kk) {
      float4 avv = *(const float4*)&As2[kk][ty * 4];
      float4 bvv = *(const float4*)&Ws2[kk][tx * 4];
      float a[4] = {avv.x, avv.y, avv.z, avv.w};
      float bb[4] = {bvv.x, bvv.y, bvv.z, bvv.w};
      #pragma unroll
      for (int i = 0; i < 4; ++i)
        #pragma unroll
        for (int j = 0; j < 4; ++j) acc[i][j] += a[i] * bb[j];
    }
    __syncthreads();
  }
  #pragma unroll
  for (int i = 0; i < 4; ++i) {
    int m = m0 + ty * 4 + i;
    #pragma unroll
    for (int j = 0; j < 4; ++j) {
      int n = n0 + tx * 4 + j;
      if (n < N) C[(size_t)m * N + n] = acc[i][j] + bias[n];
    }
  }
}

// ---------------- LayerNorm (+optional residual, +optional bf16 copy) ------
__global__ __launch_bounds__(128) void ln_k(
    const float* __restrict__ A, const float* __restrict__ Bres,
    const float* __restrict__ g, const float* __restrict__ be,
    float* __restrict__ O, ushort_t* __restrict__ Ob) {
  int r = blockIdx.x, t = threadIdx.x;
  __shared__ float lds[2];
  float4 v = ((const float4*)(A + (size_t)r * DM))[t];
  if (Bres) {
    float4 u = ((const float4*)(Bres + (size_t)r * DM))[t];
    v.x += u.x; v.y += u.y; v.z += u.z; v.w += u.w;
  }
  float s = wave_sum64(v.x + v.y + v.z + v.w);
  int w = t >> 6;
  if ((t & 63) == 0) lds[w] = s;
  __syncthreads();
  float mu = (lds[0] + lds[1]) * (1.0f / 512.0f);
  __syncthreads();
  float dx = v.x - mu, dy = v.y - mu, dz = v.z - mu, dw = v.w - mu;
  float sq = wave_sum64(dx * dx + dy * dy + dz * dz + dw * dw);
  if ((t & 63) == 0) lds[w] = sq;
  __syncthreads();
  float var = (lds[0] + lds[1]) * (1.0f / 512.0f);
  float inv = 1.0f / sqrtf(var + 1e-5f);
  float4 gv = ((const float4*)g)[t];
  float4 bv = ((const float4*)be)[t];
  float4 o;
  o.x = dx * inv * gv.x + bv.x;
  o.y = dy * inv * gv.y + bv.y;
  o.z = dz * inv * gv.z + bv.z;
  o.w = dw * inv * gv.w + bv.w;
  ((float4*)(O + (size_t)r * DM))[t] = o;
  if (Ob) {
    ushort4 ob;
    ob.x = f2b(o.x); ob.y = f2b(o.y); ob.z = f2b(o.z); ob.w = f2b(o.w);
    ((ushort4*)(Ob + (size_t)r * DM))[t] = ob;
  }
}

// ---------------- M[b,h,l]: one wave per (b,l), all-bf16 QKV ---------------
template <int UU>
__global__ __launch_bounds__(256) void qk_m_k(
    const ushort_t* __restrict__ QKVb, const int* __restrict__ idx,
    float* __restrict__ Mout, int Lx) {
  int l = blockIdx.x;
  int b = threadIdx.x >> 6;  // wave = batch
  int lane = threadIdx.x & 63;
  const ushort_t* qp = QKVb + ((size_t)b * Lx + l) * QS + lane * 8;
  float q[8];
  {
    ushort8_t qv = *(const ushort8_t*)qp;
    #pragma unroll
    for (int c = 0; c < 8; ++c) q[c] = b2f(qv[c]);
  }
  const ushort_t* Kbase = QKVb + (size_t)b * Lx * QS + 512 + lane * 8;
  const int* ip = idx + (size_t)l * UU;
  float maxv = -INFINITY, sumv = 0.f;
  #pragma unroll
  for (int u0 = 0; u0 < UU; u0 += 8) {
    ushort8_t kv[8];
    #pragma unroll
    for (int j = 0; j < 8; ++j) {
      if (u0 + j < UU)
        kv[j] = *(const ushort8_t*)(Kbase + (size_t)ip[u0 + j] * QS);
    }
    #pragma unroll
    for (int j = 0; j < 8; ++j) {
      if (u0 + j < UU) {
        float p = 0.f;
        #pragma unroll
        for (int c = 0; c < 8; ++c) p += q[c] * b2f(kv[j][c]);
        p += __shfl_xor(p, 1, 64);
        p += __shfl_xor(p, 2, 64);
        p += __shfl_xor(p, 4, 64);
        maxv = fmaxf(maxv, p);
        sumv += p;
      }
    }
  }
  if ((lane & 7) == 0) {
    int h = lane >> 3;
    Mout[(size_t)(b * 8 + h) * Lx + l] = maxv - sumv / (float)Lx;
  }
}

// ---------------- rank-based top-U, chunked (exact JAX tie-breaking) -------
__global__ __launch_bounds__(256) void topk_k(
    const float* __restrict__ Mbuf, int* __restrict__ Mtop, int Lx, int U) {
  int nch = Lx >> 8;
  int bh = blockIdx.x / nch, ch = blockIdx.x % nch;
  const float* m = Mbuf + (size_t)bh * Lx;
  __shared__ float sm[2048];
  int t = threadIdx.x;
  for (int i = t; i < Lx; i += 256) sm[i] = m[i];
  __syncthreads();
  int i0 = (ch << 8) + t;
  float v0 = sm[i0];
  int r0 = 0;
  for (int j = 0; j < Lx; j += 4) {
    float4 mj = *(const float4*)&sm[j];
    r0 += (mj.x > v0) || (mj.x == v0 && (j + 0) < i0);
    r0 += (mj.y > v0) || (mj.y == v0 && (j + 1) < i0);
    r0 += (mj.z > v0) || (mj.z == v0 && (j + 2) < i0);
    r0 += (mj.w > v0) || (mj.w == v0 && (j + 3) < i0);
  }
  if (r0 < U) Mtop[bh * U + r0] = i0;
}

// ---------------- meanV from bf16 QKV (V at +1024) -------------------------
__global__ __launch_bounds__(512) void meanv1_k(const ushort_t* __restrict__ QKVb,
                                                float* __restrict__ part,
                                                int Lx) {
  int b = blockIdx.x >> 4, chunk = blockIdx.x & 15;
  int rows = Lx >> 4;
  int t = threadIdx.x;  // 512
  const ushort_t* vp =
      QKVb + ((size_t)b * Lx + (size_t)chunk * rows) * QS + 1024 + t;
  float s = 0.f;
  for (int l = 0; l < rows; ++l) s += b2f(vp[(size_t)l * QS]);
  part[(size_t)blockIdx.x * DM + t] = s;
}
__global__ __launch_bounds__(512) void meanv2_k(const float* __restrict__ part,
                                                float* __restrict__ mv,
                                                int Lx) {
  int b = blockIdx.x, t = threadIdx.x;
  float s = 0.f;
  #pragma unroll
  for (int c = 0; c < 16; ++c) s += part[(size_t)(b * 16 + c) * DM + t];
  mv[b * DM + t] = s / (float)Lx;
}

__global__ void fillctx_k(ushort_t* __restrict__ ctx,
                          const float* __restrict__ mv, int Lx) {
  size_t i4 = (size_t)blockIdx.x * 256 + threadIdx.x;
  int col4 = (int)(i4 & 127);
  size_t row = i4 >> 7;
  int b = (int)(row / (size_t)Lx);
  const float* m = mv + b * DM + col4 * 4;
  ushort4 o;
  o.x = f2b(m[0]); o.y = f2b(m[1]); o.z = f2b(m[2]); o.w = f2b(m[3]);
  ((ushort4*)ctx)[i4] = o;
}

// ---------------- flash split-K attention (bf16 QKV) -----------------------
__global__ __launch_bounds__(512) void attn_flash_k(
    const ushort_t* __restrict__ QKVb, const int* __restrict__ Mtop,
    float* __restrict__ part, int Lx, int U, int nchunk) {
  int blk = blockIdx.x;
  int chunk = blk % nchunk, bh = blk / nchunk;
  int h = bh & 7, b = bh >> 3;
  int rows = Lx / nchunk;
  int ntile = rows >> 6;
  __shared__ float s_q[40 * 64];
  __shared__ float s_k[64 * 65];
  __shared__ float s_v[64 * 65];
  __shared__ float s_p[40 * 64];
  __shared__ float s_m[40], s_l[40], s_a[40];
  int t = threadIdx.x;
  int d = t & 63, wv = t >> 6;

  for (int i = t; i < U * 64; i += 512) {
    int u = i >> 6, dd = i & 63;
    int qi = Mtop[bh * U + u];
    s_q[i] = b2f(QKVb[((size_t)b * Lx + qi) * QS + h * HD + dd]) * 0.125f;
  }
  if (t < U) { s_m[t] = -INFINITY; s_l[t] = 0.f; s_a[t] = 0.f; }
  float o[5] = {0.f, 0.f, 0.f, 0.f, 0.f};
  __syncthreads();

  const ushort_t* Kp = QKVb + (size_t)b * Lx * QS + 512 + h * HD;
  const ushort_t* Vp = QKVb + (size_t)b * Lx * QS + 1024 + h * HD;

  for (int tile = 0; tile < ntile; ++tile) {
    int kr0 = chunk * rows + tile * 64;
    {
      int r = t >> 3, c8 = (t & 7) * 8;  // 8 threads/row x 64 rows
      ushort8_t kv = *(const ushort8_t*)&Kp[(size_t)(kr0 + r) * QS + c8];
      ushort8_t vv = *(const ushort8_t*)&Vp[(size_t)(kr0 + r) * QS + c8];
      float* kd = &s_k[r * 65 + c8];
      float* vd = &s_v[r * 65 + c8];
      #pragma unroll
      for (int jj = 0; jj < 8; ++jj) {
        kd[jj] = b2f(kv[jj]);
        vd[jj] = b2f(vv[jj]);
      }
    }
    __syncthreads();
    {
      float kr[64];
      #pragma unroll
      for (int dd = 0; dd < 64; ++dd) kr[dd] = s_k[d * 65 + dd];
      for (int u = wv; u < U; u += 8) {
        float acc = 0.f;
        #pragma unroll
        for (int c = 0; c < 16; ++c) {
          float4 qv = *(const float4*)&s_q[u * 64 + c * 4];
          acc += qv.x * kr[c * 4] + qv.y * kr[c * 4 + 1] +
                 qv.z * kr[c * 4 + 2] + qv.w * kr[c * 4 + 3];
        }
        s_p[u * 64 + d] = acc;
      }
    }
    __syncthreads();
    for (int u = wv; u < U; u += 8) {
      float sv_ = s_p[u * 64 + d];
      float mx = wave_max64(sv_);
      float mold = s_m[u];
      float mnew = fmaxf(mold, mx);
      float e = expf(sv_ - mnew);
      float se = wave_sum64(e);
      s_p[u * 64 + d] = e;
      if (d == 0) {
        float alpha = expf(mold - mnew);
        s_a[u] = alpha;
        s_l[u] = s_l[u] * alpha + se;
        s_m[u] = mnew;
      }
    }
    __syncthreads();
    {
      float vr[64];
      #pragma unroll
      for (int k = 0; k < 64; ++k) vr[k] = s_v[k * 65 + d];
      int i = 0;
      for (int u = wv; u < U; u += 8, ++i) {
        float acc = 0.f;
        #pragma unroll
        for (int c = 0; c < 16; ++c) {
          float4 pv = *(const float4*)&s_p[u * 64 + c * 4];
          acc += pv.x * vr[c * 4] + pv.y * vr[c * 4 + 1] +
                 pv.z * vr[c * 4 + 2] + pv.w * vr[c * 4 + 3];
        }
        o[i] = o[i] * s_a[u] + acc;
      }
    }
    __syncthreads();
  }
  {
    int i = 0;
    for (int u = wv; u < U; u += 8, ++i) {
      float* pp = part + ((size_t)(bh * nchunk + chunk) * U + u) * 66;
      pp[d] = o[i];
      if (d == 0) { pp[64] = s_m[u]; pp[65] = s_l[u]; }
    }
  }
}

__global__ __launch_bounds__(64) void attn_merge_k(
    const float* __restrict__ part, const int* __restrict__ Mtop,
    ushort_t* __restrict__ ctx, int Lx, int U, int nchunk) {
  int bu = blockIdx.x;
  int u = bu % U, bh = bu / U;
  int h = bh & 7, b = bh >> 3;
  int d = threadIdx.x;  // 64
  float M = -INFINITY;
  for (int c = 0; c < nchunk; ++c)
    M = fmaxf(M, part[((size_t)(bh * nchunk + c) * U + u) * 66 + 64]);
  float L = 0.f, O = 0.f;
  for (int c = 0; c < nchunk; ++c) {
    const float* pp = part + ((size_t)(bh * nchunk + c) * U + u) * 66;
    float w = expf(pp[64] - M);
    L += pp[65] * w;
    O += pp[d] * w;
  }
  int qi = Mtop[bh * U + u];
  ctx[((size_t)b * Lx + qi) * DM + h * HD + d] = f2b(O / L);
}

// ---------------- distil im2col (circular, k=3) -> bf16, [t][c] layout -----
__global__ void im2col_k(const float* __restrict__ X,
                         ushort_t* __restrict__ A2) {
  int gid = blockIdx.x * 256 + threadIdx.x;  // 8192*3*128 ushort4 units
  int i4 = gid & 127;
  int rt = gid >> 7;
  int t = rt % 3, row = rt / 3;
  int b = row >> 11, l = row & 2047;
  int ls = (l + t - 1) & 2047;
  float4 v = ((const float4*)(X + ((size_t)b * 2048 + ls) * DM))[i4];
  ushort4 o;
  o.x = f2b(v.x); o.y = f2b(v.y); o.z = f2b(v.z); o.w = f2b(v.w);
  ((ushort4*)A2)[(size_t)row * 384 + t * 128 + i4] = o;
}

// ---------------- batch-norm stats: coalesced two-stage --------------------
__global__ __launch_bounds__(256) void bn1_k(const float* __restrict__ Y,
                                             float* __restrict__ ps,
                                             float* __restrict__ pq) {
  int blk = blockIdx.x;
  int t = threadIdx.x;
  float s0 = 0, q0 = 0, s1 = 0, q1 = 0;
  const float* base = Y + (size_t)blk * 256 * DM;
  for (int r = 0; r < 256; ++r) {
    float a = base[(size_t)r * DM + t];
    float b = base[(size_t)r * DM + t + 256];
    s0 += a; q0 += a * a; s1 += b; q1 += b * b;
  }
  ps[blk * DM + t] = s0; ps[blk * DM + t + 256] = s1;
  pq[blk * DM + t] = q0; pq[blk * DM + t + 256] = q1;
}
__global__ __launch_bounds__(512) void bn2_k(const float* __restrict__ ps,
                                             const float* __restrict__ pq,
                                             float* __restrict__ mu,
                                             float* __restrict__ var) {
  int t = threadIdx.x;
  float s = 0, q = 0;
  #pragma unroll
  for (int c = 0; c < 32; ++c) { s += ps[c * DM + t]; q += pq[c * DM + t]; }
  float m = s * (1.0f / 8192.f);
  mu[t] = m;
  var[t] = q * (1.0f / 8192.f) - m * m;
}

// fused bn+elu+maxpool(k=3,s=2,pad=1)
__global__ void bnpool_k(const float* __restrict__ Y,
                         const float* __restrict__ mu,
                         const float* __restrict__ var,
                         const float* __restrict__ g,
                         const float* __restrict__ be, float* __restrict__ O,
                         ushort_t* __restrict__ Ob) {
  size_t i = (size_t)blockIdx.x * 256 + threadIdx.x;  // 4*1024*512
  int c = (int)(i & 511);
  size_t row = i >> 9;
  int lo = (int)(row & 1023);
  int b = (int)(row >> 10);
  float sc = g[c] / sqrtf(var[c] + 1e-5f);
  float sh = be[c] - mu[c] * sc;
  int l0 = 2 * lo - 1;
  float m = -INFINITY;
  #pragma unroll
  for (int tt = 0; tt < 3; ++tt) {
    int l = l0 + tt;
    if (l >= 0 && l < 2048) {
      float v = Y[((size_t)b * 2048 + l) * DM + c] * sc + sh;
      v = v > 0.f ? v : expm1f(v);
      m = fmaxf(m, v);
    }
  }
  O[i] = m;
  Ob[i] = f2b(m);
}

// ---------------------------------------------------------------------------
extern "C" void kernel_launch(void* const* d_in, const int* in_sizes, int n_in,
                              void* d_out, int out_size, void* d_ws,
                              size_t ws_size, hipStream_t stream) {
  (void)in_sizes; (void)n_in; (void)out_size; (void)ws_size;
  const float* x_enc  = (const float*)d_in[0];
  const float* tok_w  = (const float*)d_in[1];
  const float* Wq     = (const float*)d_in[2];
  const float* bq     = (const float*)d_in[3];
  const float* Wk     = (const float*)d_in[4];
  const float* bk     = (const float*)d_in[5];
  const float* Wv     = (const float*)d_in[6];
  const float* bv     = (const float*)d_in[7];
  const float* Wo     = (const float*)d_in[8];
  const float* bo     = (const float*)d_in[9];
  const float* W1     = (const float*)d_in[10];
  const float* b1     = (const float*)d_in[11];
  const float* W2     = (const float*)d_in[12];
  const float* b2     = (const float*)d_in[13];
  const float* ln1_g  = (const float*)d_in[14];
  const float* ln1_b  = (const float*)d_in[15];
  const float* ln2_g  = (const float*)d_in[16];
  const float* ln2_b  = (const float*)d_in[17];
  const float* conv_w = (const float*)d_in[18];
  const float* conv_b = (const float*)d_in[19];
  const float* bn_g   = (const float*)d_in[20];
  const float* bn_b   = (const float*)d_in[21];
  const float* normf_g = (const float*)d_in[22];
  const float* normf_b = (const float*)d_in[23];
  const float* proj_w = (const float*)d_in[24];
  const float* proj_b = (const float*)d_in[25];
  float* out = (float*)d_out;
  float* ws = (float*)d_ws;

  // ---- fp32 workspace layout (float offsets) ----
  float* X    = ws;                    // 4,194,304
  float* SCR  = ws + 4194304;          // 12,582,912 (final-LN scratch)
  ushort_t* CTXb = (ushort_t*)(ws + 16777216);  // bf16 ctx
  float* Y2   = ws + 20971520;         // 4,194,304 (attn partials / conv out)
  float* Mb   = ws + 25165824;         // 65,536
  float* MV   = ws + 25231360;         // 2,048
  float* MVP  = ws + 25233408;         // 32,768
  float* BNps = ws + 25266176;         // 16,384
  float* BNpq = ws + 25282560;         // 16,384
  float* BNmu = ws + 25298944;         // 512
  float* BNvr = ws + 25299456;         // 512
  float* ZB   = ws + 25299968;         // 512 (zero bias)
  float* BQKV = ws + 25300480;         // 3,072 (concat qkv bias, 2 layers)
  int*   IDX  = (int*)(ws + 25303552); // 81,920
  int*   MT   = (int*)(ws + 25385472); // 1,280
  // ---- bf16 workspace ----
  ushort_t* U0   = (ushort_t*)(ws + 25386752);
  ushort_t* Xb   = U0;                 // 4,194,304
  ushort_t* Hb   = U0 + 4194304;       // 16,777,216 (FFN hidden / im2col)
  ushort_t* QKVb = Hb;                 // alias: bf16 QKV — live QKV-GEMM ->
                                       // attn, before FFN uses Hb
  ushort_t* Wqkvb= U0 + 20971520;      // 1,572,864
  ushort_t* Wob  = U0 + 22544384;      // 524,288
  ushort_t* W1b  = U0 + 23068672;      // 2,097,152
  ushort_t* W2b  = U0 + 25165824;      // 2,097,152
  ushort_t* Cwb  = U0 + 27262976;      // 786,432
  ushort_t* Twb  = U0 + 28049408;      // 49,152
  ushort_t* Atok = U0 + 28098560;      // 786,432
  float* PEf = ws + 39829248;          // 1,048,576 (PE table)

  // ---- fused preamble ----
  castqkv_k<<<1536, 256, 0, stream>>>(Wq, Wk, Wv, Wqkvb);
  castw3_k<<<4656, 256, 0, stream>>>(Wo, W1, W2, tok_w, Wob, W1b, W2b, Twb);
  castw_conv_k<<<3072, 256, 0, stream>>>(conv_w, Cwb);
  setup_small_k<<<14, 256, 0, stream>>>(bq, bk, bv, ZB, BQKV);
  pe_k<<<4096, 256, 0, stream>>>(PEf);
  im2col_tok_k<<<3072, 256, 0, stream>>>(x_enc, Atok);

  // token embedding GEMM (+PE): K=96 -> BK=32 variant
  mgemm_k<32, 0, 2, 1><<<256, 256, 0, stream>>>(
      Atok, Twb, ZB, X, Xb, PEf, 4, DM, 96);

  for (int layer = 0; layer < 2; ++layer) {
    const int Lx = (layer == 0) ? 2048 : 1024;
    const int U  = (layer == 0) ? 40 : 35;
    const int M  = NB * Lx;
    const int Yt = M / 128;
    const int NCH = 8;

    uint32_t kl0, kl1, s0, s1;
    threefry2x32(0u, 42u, 0u, (uint32_t)layer, &kl0, &kl1);
    threefry2x32(kl0, kl1, 0u, 1u, &s0, &s1);
    int nidx = Lx * U;
    gen_idx_k<<<(nidx + 255) / 256, 256, 0, stream>>>(IDX, nidx, Lx - 1, s0, s1);

    // fused QKV GEMM: bf16-only output, XCD-swizzled, BK=64
    mgemm_k<64, 0, 1, 0><<<12 * Yt, 256, 0, stream>>>(
        Xb, Wqkvb + (size_t)layer * 786432, BQKV + layer * 1536, nullptr, QKVb,
        nullptr, 12, QS, DM);

    // ProbSparse attention (all bf16 QKV)
    if (layer == 0)
      qk_m_k<40><<<Lx, 256, 0, stream>>>(QKVb, IDX, Mb, Lx);
    else
      qk_m_k<35><<<Lx, 256, 0, stream>>>(QKVb, IDX, Mb, Lx);
    topk_k<<<NB * NH * (Lx >> 8), 256, 0, stream>>>(Mb, MT, Lx, U);
    meanv1_k<<<NB * 16, 512, 0, stream>>>(QKVb, MVP, Lx);
    meanv2_k<<<NB, 512, 0, stream>>>(MVP, MV, Lx);
    fillctx_k<<<(M * DM / 4) / 256, 256, 0, stream>>>(CTXb, MV, Lx);
    attn_flash_k<<<NB * NH * NCH, 512, 0, stream>>>(QKVb, MT, Y2, Lx, U, NCH);
    attn_merge_k<<<NB * NH * U, 64, 0, stream>>>(Y2, MT, CTXb, Lx, U, NCH);

    // output projection + residual + LN1 (emits bf16 for FFN1)
    mgemm_k<64, 0, 0, 0><<<4 * Yt, 256, 0, stream>>>(
        CTXb, Wob + (size_t)layer * 262144, bo + layer * DM, Y2, nullptr,
        nullptr, 4, DM, DM);
    ln_k<<<M, 128, 0, stream>>>(X, Y2, ln1_g + layer * DM, ln1_b + layer * DM, X, Xb);

    // FFN (GELU fused; hidden kept in bf16); LN2 emits bf16
    mgemm_k<64, 1, 1, 0><<<16 * Yt, 256, 0, stream>>>(
        Xb, W1b + (size_t)layer * 1048576, b1 + layer * 2048, nullptr, Hb,
        nullptr, 16, 2048, DM);
    mgemm_k<64, 0, 0, 0><<<4 * Yt, 256, 0, stream>>>(
        Hb, W2b + (size_t)layer * 1048576, b2 + layer * DM, Y2, nullptr,
        nullptr, 4, DM, 2048);
    ln_k<<<M, 128, 0, stream>>>(X, Y2, ln2_g + layer * DM, ln2_b + layer * DM, X, Xb);

    if (layer == 0) {
      im2col_k<<<12288, 256, 0, stream>>>(X, Hb);
      mgemm_k<64, 0, 0, 0><<<4 * 64, 256, 0, stream>>>(
          Hb, Cwb, conv_b, Y2, nullptr, nullptr, 4, DM, 1536);
      bn1_k<<<32, 256, 0, stream>>>(Y2, BNps, BNpq);
      bn2_k<<<1, 512, 0, stream>>>(BNps, BNpq, BNmu, BNvr);
      bnpool_k<<<(NB * 1024 * 512) / 256, 256, 0, stream>>>(
          Y2, BNmu, BNvr, bn_g, bn_b, X, Xb);
    }
  }

  // final LN + projection (N=32, fp32)
  ln_k<<<NB * 1024, 128, 0, stream>>>(X, nullptr, normf_g, normf_b, SCR, nullptr);
  gemm_k<<<dim3(1, 4096 / 64), 256, 0, stream>>>(SCR, proj_w, proj_b, out,
                                                 4096, 32, DM);
}

// Round 15
// 742.991 us; speedup vs baseline: 1.2708x; 1.0475x over previous
//
#include <hip/hip_runtime.h>
#include <cstdint>
#include <cmath>

// ---------------------------------------------------------------------------
// Informer encoder forward (B=4, L=2048, ENC_IN=32, D_MODEL=512, D_FF=2048,
// E_LAYERS=2, H=8, FACTOR=5).
// Round 15: mgemm v2 — 8 waves x (32x64) wave tiles (32 AGPR acc, ~95 regs
// -> 4 waves/SIMD, 2.3x occupancy for latency hiding; r12-14 K-loop tweaks
// were all neutral because resident-wave count never changed). Distil im2col
// folded into the conv GEMM staging (implicit GEMM, A=Xb circular rows).
// ---------------------------------------------------------------------------

#define NB 4
#define DM 512
#define NH 8
#define HD 64
#define QS 1536  // QKV row stride

typedef unsigned short ushort_t;
typedef __bf16 bf16x8 __attribute__((ext_vector_type(8)));
typedef float floatx4 __attribute__((ext_vector_type(4)));
typedef unsigned short ushort8_t __attribute__((ext_vector_type(8)));

__device__ inline ushort_t f2b(float f) {
  uint32_t u = __float_as_uint(f);
  uint32_t r = (u + 0x7fffu + ((u >> 16) & 1u)) >> 16;
  return (ushort_t)r;
}
__device__ inline float b2f(ushort_t u) {
  return __uint_as_float((uint32_t)u << 16);
}

// ---------------- fused weight casts ---------------------------------------
__global__ void castqkv_k(const float* __restrict__ Wq,
                          const float* __restrict__ Wk,
                          const float* __restrict__ Wv,
                          ushort_t* __restrict__ out) {
  int gid = blockIdx.x * 256 + threadIdx.x;  // 393216 float4 units
  if (gid >= 393216) return;
  int ly = gid / 196608, r4 = gid - ly * 196608;
  int r = r4 >> 7, c4 = r4 & 127;
  int sel = r >> 9, srow = r & 511;
  const float* src = (sel == 0 ? Wq : sel == 1 ? Wk : Wv) + ly * 262144 +
                     srow * 512 + c4 * 4;
  float4 v = *(const float4*)src;
  ushort4 o;
  o.x = f2b(v.x); o.y = f2b(v.y); o.z = f2b(v.z); o.w = f2b(v.w);
  ((ushort4*)out)[ly * 196608 + r * 128 + c4] = o;
}

__global__ void castw3_k(const float* __restrict__ Wo,
                         const float* __restrict__ W1,
                         const float* __restrict__ W2,
                         const float* __restrict__ tw,
                         ushort_t* __restrict__ oWo, ushort_t* __restrict__ oW1,
                         ushort_t* __restrict__ oW2, ushort_t* __restrict__ otw) {
  int gid = blockIdx.x * 256 + threadIdx.x;  // 1,191,936 float4 units
  if (gid >= 1191936) return;
  const float* src;
  ushort4* dst;
  int i;
  if (gid < 131072) { src = Wo; dst = (ushort4*)oWo; i = gid; }
  else if (gid < 655360) { src = W1; dst = (ushort4*)oW1; i = gid - 131072; }
  else if (gid < 1179648) { src = W2; dst = (ushort4*)oW2; i = gid - 655360; }
  else { src = tw; dst = (ushort4*)otw; i = gid - 1179648; }
  float4 v = ((const float4*)src)[i];
  ushort4 o;
  o.x = f2b(v.x); o.y = f2b(v.y); o.z = f2b(v.z); o.w = f2b(v.w);
  dst[i] = o;
}

// conv weight: (D, I, 3) -> bf16 (D, 3, I) so implicit-GEMM staging is
// contiguous in the input channel dim
__global__ void castw_conv_k(const float* __restrict__ in,
                             ushort_t* __restrict__ out) {
  int gid = blockIdx.x * 256 + threadIdx.x;  // 512*1536
  int d = gid / 1536, r = gid - d * 1536;
  int t = r >> 9, i = r & 511;
  out[gid] = f2b(in[d * 1536 + i * 3 + t]);
}

__global__ void setup_small_k(const float* __restrict__ bq,
                              const float* __restrict__ bk,
                              const float* __restrict__ bv,
                              float* __restrict__ ZB,
                              float* __restrict__ BQKV) {
  int gid = blockIdx.x * 256 + threadIdx.x;  // 3584
  if (gid >= 3584) return;
  if (gid < 512) { ZB[gid] = 0.f; return; }
  int g = gid - 512;
  int layer = g / 1536, r = g - layer * 1536;
  float v;
  if (r < 512) v = bq[layer * 512 + r];
  else if (r < 1024) v = bk[layer * 512 + r - 512];
  else v = bv[layer * 512 + r - 1024];
  BQKV[g] = v;
}

__host__ __device__ inline void threefry2x32(uint32_t k0, uint32_t k1,
                                             uint32_t c0, uint32_t c1,
                                             uint32_t* o0, uint32_t* o1) {
  uint32_t ks0 = k0, ks1 = k1, ks2 = k0 ^ k1 ^ 0x1BD11BDAu;
  uint32_t x0 = c0 + ks0;
  uint32_t x1 = c1 + ks1;
  const uint32_t rotA[4] = {13u, 15u, 26u, 6u};
  const uint32_t rotB[4] = {17u, 29u, 16u, 24u};
  uint32_t ks[3] = {ks0, ks1, ks2};
  #pragma unroll
  for (int i = 0; i < 5; ++i) {
    const uint32_t* r = (i & 1) ? rotB : rotA;
    #pragma unroll
    for (int j = 0; j < 4; ++j) {
      x0 += x1;
      x1 = (x1 << r[j]) | (x1 >> (32u - r[j]));
      x1 ^= x0;
    }
    x0 += ks[(i + 1) % 3];
    x1 += ks[(i + 2) % 3] + (uint32_t)(i + 1);
  }
  *o0 = x0; *o1 = x1;
}

__global__ void gen_idx_k(int* __restrict__ idx, int n, int mask,
                          uint32_t k0, uint32_t k1) {
  int i = blockIdx.x * 256 + threadIdx.x;
  if (i < n) {
    uint32_t o0, o1;
    threefry2x32(k0, k1, 0u, (uint32_t)i, &o0, &o1);
    idx[i] = (int)((o0 ^ o1) & (uint32_t)mask);
  }
}

__device__ inline float wave_sum64(float v) {
  #pragma unroll
  for (int o = 32; o > 0; o >>= 1) v += __shfl_xor(v, o, 64);
  return v;
}
__device__ inline float wave_max64(float v) {
  #pragma unroll
  for (int o = 32; o > 0; o >>= 1) v = fmaxf(v, __shfl_xor(v, o, 64));
  return v;
}

// ---------------- positional-encoding table (2048 x 512) -------------------
__global__ void pe_k(float* __restrict__ pe) {
  int i = blockIdx.x * 256 + threadIdx.x;  // 1,048,576
  int d = i & 511, l = i >> 9;
  int j2 = d & ~1;
  float div = expf((float)j2 * -1.7988946039e-2f);  // -ln(10000)/512
  float ang = (float)l * div;
  pe[i] = (d & 1) ? cosf(ang) : sinf(ang);
}

// ---------------- im2col for token conv: (B*L, 96) bf16 --------------------
__global__ void im2col_tok_k(const float* __restrict__ xe,
                             ushort_t* __restrict__ A) {
  int gid = blockIdx.x * 256 + threadIdx.x;  // 8192*96
  int col = gid % 96;
  int row = gid / 96;
  int c = col / 3, t = col - c * 3;
  int b = row >> 11, l = row & 2047;
  int ls = (l + t - 1) & 2047;
  A[gid] = f2b(xe[((size_t)b * 2048 + ls) * 32 + c]);
}

// ---------------- bf16 MFMA GEMM v2: 8 waves x (32x64), BK=32 --------------
__device__ inline void gload16(const ushort_t* g, ushort_t* l) {
  __builtin_amdgcn_global_load_lds(
      (const __attribute__((address_space(1))) unsigned int*)(const void*)g,
      (__attribute__((address_space(3))) unsigned int*)(void*)l, 16, 0, 0);
}

// CONV: A is Xb (B*L x 512 bf16); logical A[row][k] = Xb[(row_b, (l+t-1)%2048)][c]
// with t = k/512, c = k%512. Otherwise plain row-major A (M x K).
template <int CONV, int GELU, int OMODE, int ADDPE>  // OMODE: 0 f32,1 bf16,2 both
__global__ __launch_bounds__(512) void mgemm_k(
    const ushort_t* __restrict__ A, const ushort_t* __restrict__ W,
    const float* __restrict__ bias, float* __restrict__ Cf,
    ushort_t* __restrict__ Cb, const float* __restrict__ pe,
    int X, int ldc, int K) {
  __shared__ ushort_t As[128 * 32];
  __shared__ ushort_t Bs[128 * 32];
  int id = blockIdx.x;
  int cc = id & 7, j = id >> 3;
  int bx = j % X;
  int by = (j / X) * 8 + cc;
  int m0 = by * 128, n0 = bx * 128;
  int t = threadIdx.x;
  int lane = t & 63, wv = t >> 6;  // 8 waves
  int rl = lane >> 2, cl = (lane & 3) * 8;
  int Ra = wv * 16;  // 16 rows staged per wave (A and B)
  int ga_row = m0 + Ra + rl;
  const ushort_t* gA = A + (size_t)ga_row * K + cl;  // non-CONV path
  const ushort_t* gB = W + (size_t)(n0 + Ra + rl) * K + cl;
  ushort_t* lA = As + Ra * 32;
  ushort_t* lB = Bs + Ra * 32;
  int cb = ga_row >> 11, clr = ga_row & 2047;  // CONV: batch, seq pos

  int quad = lane >> 4, lr = lane & 15;
  int wm = wv >> 1, wn = wv & 1;  // 4 (M) x 2 (N) waves

  floatx4 acc[2][4] = {};
  for (int ks = 0; ks < K; ks += 32) {
    if (ks) __syncthreads();
    if (CONV) {
      int tt = ks >> 9;
      int c = (ks & 511) + cl;
      int ls = (clr + tt - 1) & 2047;
      gload16(A + ((size_t)(cb * 2048 + ls) * 512 + c), lA);
    } else {
      gload16(gA, lA);
      gA += 32;
    }
    gload16(gB, lB);
    gB += 32;
    __syncthreads();
    bf16x8 av[2], bv[4];
    #pragma unroll
    for (int mt = 0; mt < 2; ++mt)
      av[mt] = *(const bf16x8*)&As[(wm * 32 + mt * 16 + lr) * 32 + quad * 8];
    #pragma unroll
    for (int nt = 0; nt < 4; ++nt)
      bv[nt] = *(const bf16x8*)&Bs[(wn * 64 + nt * 16 + lr) * 32 + quad * 8];
    #pragma unroll
    for (int mt = 0; mt < 2; ++mt)
      #pragma unroll
      for (int nt = 0; nt < 4; ++nt)
        acc[mt][nt] = __builtin_amdgcn_mfma_f32_16x16x32_bf16(
            av[mt], bv[nt], acc[mt][nt], 0, 0, 0);
  }
  #pragma unroll
  for (int nt = 0; nt < 4; ++nt) {
    int col = n0 + wn * 64 + nt * 16 + lr;
    float bsv = bias[col];
    #pragma unroll
    for (int mt = 0; mt < 2; ++mt) {
      int row0 = m0 + wm * 32 + mt * 16 + quad * 4;
      #pragma unroll
      for (int r = 0; r < 4; ++r) {
        int row = row0 + r;
        float v = acc[mt][nt][r] + bsv;
        if (ADDPE) v += pe[(size_t)(row & 2047) * ldc + col];
        if (GELU) v = 0.5f * v * (1.0f + erff(v * 0.70710678118654752f));
        if (OMODE == 0 || OMODE == 2) Cf[(size_t)row * ldc + col] = v;
        if (OMODE == 1 || OMODE == 2) Cb[(size_t)row * ldc + col] = f2b(v);
      }
    }
  }
}

// ---------------- fp32 fallback GEMM (final projection, N=32) --------------
__global__ __launch_bounds__(256) void gemm_k(
    const float* __restrict__ A, const float* __restrict__ W,
    const float* __restrict__ bias, float* __restrict__ C,
    int M, int N, int K) {
  __shared__ float As2[16][64 + 4];
  __shared__ float Ws2[16][64 + 4];
  int m0 = blockIdx.y * 64, n0 = blockIdx.x * 64;
  int t = threadIdx.x;
  int tx = t & 15, ty = t >> 4;
  float acc[4][4] = {};
  for (int k0 = 0; k0 < K; k0 += 16) {
    #pragma unroll
    for (int i = 0; i < 4; ++i) {
      int li = t + i * 256;
      int m = li >> 4, kk = li & 15;
      As2[kk][m] = A[(size_t)(m0 + m) * K + k0 + kk];
    }
    #pragma unroll
    for (int i = 0; i < 4; ++i) {
      int li = t + i * 256;
      int n = li >> 4, kk = li & 15;
      int gn = n0 + n;
      Ws2[kk][n] = (gn < N) ? W[(size_t)gn * K + k0 + kk] : 0.0f;
    }
    __syncthreads();
    #pragma unroll
    for (int kk = 0; kk < 16; ++kk) {
      float4 avv = *(const float4*)&As2[kk][ty * 4];
      float4 bvv = *(const float4*)&Ws2[kk][tx * 4];
      float a[4] = {avv.x, avv.y, avv.z, avv.w};
      float bb[4] = {bvv.x, bvv.y, bvv.z, bvv.w};
      #pragma unroll
      for (int i = 0; i < 4; ++i)
        #pragma unroll
        for (int j = 0; j < 4; ++j) acc[i][j] += a[i] * bb[j];
    }
    __syncthreads();
  }
  #pragma unroll
  for (int i = 0; i < 4; ++i) {
    int m = m0 + ty * 4 + i;
    #pragma unroll
    for (int j = 0; j < 4; ++j) {
      int n = n0 + tx * 4 + j;
      if (n < N) C[(size_t)m * N + n] = acc[i][j] + bias[n];
    }
  }
}

// ---------------- LayerNorm (+optional residual, +optional bf16 copy) ------
__global__ __launch_bounds__(128) void ln_k(
    const float* __restrict__ A, const float* __restrict__ Bres,
    const float* __restrict__ g, const float* __restrict__ be,
    float* __restrict__ O, ushort_t* __restrict__ Ob) {
  int r = blockIdx.x, t = threadIdx.x;
  __shared__ float lds[2];
  float4 v = ((const float4*)(A + (size_t)r * DM))[t];
  if (Bres) {
    float4 u = ((const float4*)(Bres + (size_t)r * DM))[t];
    v.x += u.x; v.y += u.y; v.z += u.z; v.w += u.w;
  }
  float s = wave_sum64(v.x + v.y + v.z + v.w);
  int w = t >> 6;
  if ((t & 63) == 0) lds[w] = s;
  __syncthreads();
  float mu = (lds[0] + lds[1]) * (1.0f / 512.0f);
  __syncthreads();
  float dx = v.x - mu, dy = v.y - mu, dz = v.z - mu, dw = v.w - mu;
  float sq = wave_sum64(dx * dx + dy * dy + dz * dz + dw * dw);
  if ((t & 63) == 0) lds[w] = sq;
  __syncthreads();
  float var = (lds[0] + lds[1]) * (1.0f / 512.0f);
  float inv = 1.0f / sqrtf(var + 1e-5f);
  float4 gv = ((const float4*)g)[t];
  float4 bv = ((const float4*)be)[t];
  float4 o;
  o.x = dx * inv * gv.x + bv.x;
  o.y = dy * inv * gv.y + bv.y;
  o.z = dz * inv * gv.z + bv.z;
  o.w = dw * inv * gv.w + bv.w;
  ((float4*)(O + (size_t)r * DM))[t] = o;
  if (Ob) {
    ushort4 ob;
    ob.x = f2b(o.x); ob.y = f2b(o.y); ob.z = f2b(o.z); ob.w = f2b(o.w);
    ((ushort4*)(Ob + (size_t)r * DM))[t] = ob;
  }
}

// ---------------- M[b,h,l]: one wave per (b,l), all-bf16 QKV ---------------
template <int UU>
__global__ __launch_bounds__(256) void qk_m_k(
    const ushort_t* __restrict__ QKVb, const int* __restrict__ idx,
    float* __restrict__ Mout, int Lx) {
  int l = blockIdx.x;
  int b = threadIdx.x >> 6;  // wave = batch
  int lane = threadIdx.x & 63;
  const ushort_t* qp = QKVb + ((size_t)b * Lx + l) * QS + lane * 8;
  float q[8];
  {
    ushort8_t qv = *(const ushort8_t*)qp;
    #pragma unroll
    for (int c = 0; c < 8; ++c) q[c] = b2f(qv[c]);
  }
  const ushort_t* Kbase = QKVb + (size_t)b * Lx * QS + 512 + lane * 8;
  const int* ip = idx + (size_t)l * UU;
  float maxv = -INFINITY, sumv = 0.f;
  #pragma unroll
  for (int u0 = 0; u0 < UU; u0 += 8) {
    ushort8_t kv[8];
    #pragma unroll
    for (int j = 0; j < 8; ++j) {
      if (u0 + j < UU)
        kv[j] = *(const ushort8_t*)(Kbase + (size_t)ip[u0 + j] * QS);
    }
    #pragma unroll
    for (int j = 0; j < 8; ++j) {
      if (u0 + j < UU) {
        float p = 0.f;
        #pragma unroll
        for (int c = 0; c < 8; ++c) p += q[c] * b2f(kv[j][c]);
        p += __shfl_xor(p, 1, 64);
        p += __shfl_xor(p, 2, 64);
        p += __shfl_xor(p, 4, 64);
        maxv = fmaxf(maxv, p);
        sumv += p;
      }
    }
  }
  if ((lane & 7) == 0) {
    int h = lane >> 3;
    Mout[(size_t)(b * 8 + h) * Lx + l] = maxv - sumv / (float)Lx;
  }
}

// ---------------- rank-based top-U, chunked (exact JAX tie-breaking) -------
__global__ __launch_bounds__(256) void topk_k(
    const float* __restrict__ Mbuf, int* __restrict__ Mtop, int Lx, int U) {
  int nch = Lx >> 8;
  int bh = blockIdx.x / nch, ch = blockIdx.x % nch;
  const float* m = Mbuf + (size_t)bh * Lx;
  __shared__ float sm[2048];
  int t = threadIdx.x;
  for (int i = t; i < Lx; i += 256) sm[i] = m[i];
  __syncthreads();
  int i0 = (ch << 8) + t;
  float v0 = sm[i0];
  int r0 = 0;
  for (int j = 0; j < Lx; j += 4) {
    float4 mj = *(const float4*)&sm[j];
    r0 += (mj.x > v0) || (mj.x == v0 && (j + 0) < i0);
    r0 += (mj.y > v0) || (mj.y == v0 && (j + 1) < i0);
    r0 += (mj.z > v0) || (mj.z == v0 && (j + 2) < i0);
    r0 += (mj.w > v0) || (mj.w == v0 && (j + 3) < i0);
  }
  if (r0 < U) Mtop[bh * U + r0] = i0;
}

// ---------------- meanV from bf16 QKV (V at +1024) -------------------------
__global__ __launch_bounds__(512) void meanv1_k(const ushort_t* __restrict__ QKVb,
                                                float* __restrict__ part,
                                                int Lx) {
  int b = blockIdx.x >> 4, chunk = blockIdx.x & 15;
  int rows = Lx >> 4;
  int t = threadIdx.x;  // 512
  const ushort_t* vp =
      QKVb + ((size_t)b * Lx + (size_t)chunk * rows) * QS + 1024 + t;
  float s = 0.f;
  for (int l = 0; l < rows; ++l) s += b2f(vp[(size_t)l * QS]);
  part[(size_t)blockIdx.x * DM + t] = s;
}
__global__ __launch_bounds__(512) void meanv2_k(const float* __restrict__ part,
                                                float* __restrict__ mv,
                                                int Lx) {
  int b = blockIdx.x, t = threadIdx.x;
  float s = 0.f;
  #pragma unroll
  for (int c = 0; c < 16; ++c) s += part[(size_t)(b * 16 + c) * DM + t];
  mv[b * DM + t] = s / (float)Lx;
}

__global__ void fillctx_k(ushort_t* __restrict__ ctx,
                          const float* __restrict__ mv, int Lx) {
  size_t i4 = (size_t)blockIdx.x * 256 + threadIdx.x;
  int col4 = (int)(i4 & 127);
  size_t row = i4 >> 7;
  int b = (int)(row / (size_t)Lx);
  const float* m = mv + b * DM + col4 * 4;
  ushort4 o;
  o.x = f2b(m[0]); o.y = f2b(m[1]); o.z = f2b(m[2]); o.w = f2b(m[3]);
  ((ushort4*)ctx)[i4] = o;
}

// ---------------- flash split-K attention (bf16 QKV) -----------------------
__global__ __launch_bounds__(512) void attn_flash_k(
    const ushort_t* __restrict__ QKVb, const int* __restrict__ Mtop,
    float* __restrict__ part, int Lx, int U, int nchunk) {
  int blk = blockIdx.x;
  int chunk = blk % nchunk, bh = blk / nchunk;
  int h = bh & 7, b = bh >> 3;
  int rows = Lx / nchunk;
  int ntile = rows >> 6;
  __shared__ float s_q[40 * 64];
  __shared__ float s_k[64 * 65];
  __shared__ float s_v[64 * 65];
  __shared__ float s_p[40 * 64];
  __shared__ float s_m[40], s_l[40], s_a[40];
  int t = threadIdx.x;
  int d = t & 63, wv = t >> 6;

  for (int i = t; i < U * 64; i += 512) {
    int u = i >> 6, dd = i & 63;
    int qi = Mtop[bh * U + u];
    s_q[i] = b2f(QKVb[((size_t)b * Lx + qi) * QS + h * HD + dd]) * 0.125f;
  }
  if (t < U) { s_m[t] = -INFINITY; s_l[t] = 0.f; s_a[t] = 0.f; }
  float o[5] = {0.f, 0.f, 0.f, 0.f, 0.f};
  __syncthreads();

  const ushort_t* Kp = QKVb + (size_t)b * Lx * QS + 512 + h * HD;
  const ushort_t* Vp = QKVb + (size_t)b * Lx * QS + 1024 + h * HD;

  for (int tile = 0; tile < ntile; ++tile) {
    int kr0 = chunk * rows + tile * 64;
    {
      int r = t >> 3, c8 = (t & 7) * 8;  // 8 threads/row x 64 rows
      ushort8_t kv = *(const ushort8_t*)&Kp[(size_t)(kr0 + r) * QS + c8];
      ushort8_t vv = *(const ushort8_t*)&Vp[(size_t)(kr0 + r) * QS + c8];
      float* kd = &s_k[r * 65 + c8];
      float* vd = &s_v[r * 65 + c8];
      #pragma unroll
      for (int jj = 0; jj < 8; ++jj) {
        kd[jj] = b2f(kv[jj]);
        vd[jj] = b2f(vv[jj]);
      }
    }
    __syncthreads();
    {
      float kr[64];
      #pragma unroll
      for (int dd = 0; dd < 64; ++dd) kr[dd] = s_k[d * 65 + dd];
      for (int u = wv; u < U; u += 8) {
        float acc = 0.f;
        #pragma unroll
        for (int c = 0; c < 16; ++c) {
          float4 qv = *(const float4*)&s_q[u * 64 + c * 4];
          acc += qv.x * kr[c * 4] + qv.y * kr[c * 4 + 1] +
                 qv.z * kr[c * 4 + 2] + qv.w * kr[c * 4 + 3];
        }
        s_p[u * 64 + d] = acc;
      }
    }
    __syncthreads();
    for (int u = wv; u < U; u += 8) {
      float sv_ = s_p[u * 64 + d];
      float mx = wave_max64(sv_);
      float mold = s_m[u];
      float mnew = fmaxf(mold, mx);
      float e = expf(sv_ - mnew);
      float se = wave_sum64(e);
      s_p[u * 64 + d] = e;
      if (d == 0) {
        float alpha = expf(mold - mnew);
        s_a[u] = alpha;
        s_l[u] = s_l[u] * alpha + se;
        s_m[u] = mnew;
      }
    }
    __syncthreads();
    {
      float vr[64];
      #pragma unroll
      for (int k = 0; k < 64; ++k) vr[k] = s_v[k * 65 + d];
      int i = 0;
      for (int u = wv; u < U; u += 8, ++i) {
        float acc = 0.f;
        #pragma unroll
        for (int c = 0; c < 16; ++c) {
          float4 pv = *(const float4*)&s_p[u * 64 + c * 4];
          acc += pv.x * vr[c * 4] + pv.y * vr[c * 4 + 1] +
                 pv.z * vr[c * 4 + 2] + pv.w * vr[c * 4 + 3];
        }
        o[i] = o[i] * s_a[u] + acc;
      }
    }
    __syncthreads();
  }
  {
    int i = 0;
    for (int u = wv; u < U; u += 8, ++i) {
      float* pp = part + ((size_t)(bh * nchunk + chunk) * U + u) * 66;
      pp[d] = o[i];
      if (d == 0) { pp[64] = s_m[u]; pp[65] = s_l[u]; }
    }
  }
}

__global__ __launch_bounds__(64) void attn_merge_k(
    const float* __restrict__ part, const int* __restrict__ Mtop,
    ushort_t* __restrict__ ctx, int Lx, int U, int nchunk) {
  int bu = blockIdx.x;
  int u = bu % U, bh = bu / U;
  int h = bh & 7, b = bh >> 3;
  int d = threadIdx.x;  // 64
  float M = -INFINITY;
  for (int c = 0; c < nchunk; ++c)
    M = fmaxf(M, part[((size_t)(bh * nchunk + c) * U + u) * 66 + 64]);
  float L = 0.f, O = 0.f;
  for (int c = 0; c < nchunk; ++c) {
    const float* pp = part + ((size_t)(bh * nchunk + c) * U + u) * 66;
    float w = expf(pp[64] - M);
    L += pp[65] * w;
    O += pp[d] * w;
  }
  int qi = Mtop[bh * U + u];
  ctx[((size_t)b * Lx + qi) * DM + h * HD + d] = f2b(O / L);
}

// ---------------- batch-norm stats: coalesced two-stage --------------------
__global__ __launch_bounds__(256) void bn1_k(const float* __restrict__ Y,
                                             float* __restrict__ ps,
                                             float* __restrict__ pq) {
  int blk = blockIdx.x;
  int t = threadIdx.x;
  float s0 = 0, q0 = 0, s1 = 0, q1 = 0;
  const float* base = Y + (size_t)blk * 256 * DM;
  for (int r = 0; r < 256; ++r) {
    float a = base[(size_t)r * DM + t];
    float b = base[(size_t)r * DM + t + 256];
    s0 += a; q0 += a * a; s1 += b; q1 += b * b;
  }
  ps[blk * DM + t] = s0; ps[blk * DM + t + 256] = s1;
  pq[blk * DM + t] = q0; pq[blk * DM + t + 256] = q1;
}
__global__ __launch_bounds__(512) void bn2_k(const float* __restrict__ ps,
                                             const float* __restrict__ pq,
                                             float* __restrict__ mu,
                                             float* __restrict__ var) {
  int t = threadIdx.x;
  float s = 0, q = 0;
  #pragma unroll
  for (int c = 0; c < 32; ++c) { s += ps[c * DM + t]; q += pq[c * DM + t]; }
  float m = s * (1.0f / 8192.f);
  mu[t] = m;
  var[t] = q * (1.0f / 8192.f) - m * m;
}

// fused bn+elu+maxpool(k=3,s=2,pad=1)
__global__ void bnpool_k(const float* __restrict__ Y,
                         const float* __restrict__ mu,
                         const float* __restrict__ var,
                         const float* __restrict__ g,
                         const float* __restrict__ be, float* __restrict__ O,
                         ushort_t* __restrict__ Ob) {
  size_t i = (size_t)blockIdx.x * 256 + threadIdx.x;  // 4*1024*512
  int c = (int)(i & 511);
  size_t row = i >> 9;
  int lo = (int)(row & 1023);
  int b = (int)(row >> 10);
  float sc = g[c] / sqrtf(var[c] + 1e-5f);
  float sh = be[c] - mu[c] * sc;
  int l0 = 2 * lo - 1;
  float m = -INFINITY;
  #pragma unroll
  for (int tt = 0; tt < 3; ++tt) {
    int l = l0 + tt;
    if (l >= 0 && l < 2048) {
      float v = Y[((size_t)b * 2048 + l) * DM + c] * sc + sh;
      v = v > 0.f ? v : expm1f(v);
      m = fmaxf(m, v);
    }
  }
  O[i] = m;
  Ob[i] = f2b(m);
}

// ---------------------------------------------------------------------------
extern "C" void kernel_launch(void* const* d_in, const int* in_sizes, int n_in,
                              void* d_out, int out_size, void* d_ws,
                              size_t ws_size, hipStream_t stream) {
  (void)in_sizes; (void)n_in; (void)out_size; (void)ws_size;
  const float* x_enc  = (const float*)d_in[0];
  const float* tok_w  = (const float*)d_in[1];
  const float* Wq     = (const float*)d_in[2];
  const float* bq     = (const float*)d_in[3];
  const float* Wk     = (const float*)d_in[4];
  const float* bk     = (const float*)d_in[5];
  const float* Wv     = (const float*)d_in[6];
  const float* bv     = (const float*)d_in[7];
  const float* Wo     = (const float*)d_in[8];
  const float* bo     = (const float*)d_in[9];
  const float* W1     = (const float*)d_in[10];
  const float* b1     = (const float*)d_in[11];
  const float* W2     = (const float*)d_in[12];
  const float* b2     = (const float*)d_in[13];
  const float* ln1_g  = (const float*)d_in[14];
  const float* ln1_b  = (const float*)d_in[15];
  const float* ln2_g  = (const float*)d_in[16];
  const float* ln2_b  = (const float*)d_in[17];
  const float* conv_w = (const float*)d_in[18];
  const float* conv_b = (const float*)d_in[19];
  const float* bn_g   = (const float*)d_in[20];
  const float* bn_b   = (const float*)d_in[21];
  const float* normf_g = (const float*)d_in[22];
  const float* normf_b = (const float*)d_in[23];
  const float* proj_w = (const float*)d_in[24];
  const float* proj_b = (const float*)d_in[25];
  float* out = (float*)d_out;
  float* ws = (float*)d_ws;

  // ---- fp32 workspace layout (float offsets) ----
  float* X    = ws;                    // 4,194,304
  float* SCR  = ws + 4194304;          // 12,582,912 (final-LN scratch)
  ushort_t* CTXb = (ushort_t*)(ws + 16777216);  // bf16 ctx
  float* Y2   = ws + 20971520;         // 4,194,304 (attn partials / conv out)
  float* Mb   = ws + 25165824;         // 65,536
  float* MV   = ws + 25231360;         // 2,048
  float* MVP  = ws + 25233408;         // 32,768
  float* BNps = ws + 25266176;         // 16,384
  float* BNpq = ws + 25282560;         // 16,384
  float* BNmu = ws + 25298944;         // 512
  float* BNvr = ws + 25299456;         // 512
  float* ZB   = ws + 25299968;         // 512 (zero bias)
  float* BQKV = ws + 25300480;         // 3,072 (concat qkv bias, 2 layers)
  int*   IDX  = (int*)(ws + 25303552); // 81,920
  int*   MT   = (int*)(ws + 25385472); // 1,280
  // ---- bf16 workspace ----
  ushort_t* U0   = (ushort_t*)(ws + 25386752);
  ushort_t* Xb   = U0;                 // 4,194,304
  ushort_t* Hb   = U0 + 4194304;       // 16,777,216 (FFN hidden)
  ushort_t* QKVb = Hb;                 // alias: bf16 QKV — live QKV-GEMM ->
                                       // attn, before FFN uses Hb
  ushort_t* Wqkvb= U0 + 20971520;      // 1,572,864
  ushort_t* Wob  = U0 + 22544384;      // 524,288
  ushort_t* W1b  = U0 + 23068672;      // 2,097,152
  ushort_t* W2b  = U0 + 25165824;      // 2,097,152
  ushort_t* Cwb  = U0 + 27262976;      // 786,432 ([d][t][i] layout)
  ushort_t* Twb  = U0 + 28049408;      // 49,152
  ushort_t* Atok = U0 + 28098560;      // 786,432
  float* PEf = ws + 39829248;          // 1,048,576 (PE table)

  // ---- fused preamble ----
  castqkv_k<<<1536, 256, 0, stream>>>(Wq, Wk, Wv, Wqkvb);
  castw3_k<<<4656, 256, 0, stream>>>(Wo, W1, W2, tok_w, Wob, W1b, W2b, Twb);
  castw_conv_k<<<3072, 256, 0, stream>>>(conv_w, Cwb);
  setup_small_k<<<14, 256, 0, stream>>>(bq, bk, bv, ZB, BQKV);
  pe_k<<<4096, 256, 0, stream>>>(PEf);
  im2col_tok_k<<<3072, 256, 0, stream>>>(x_enc, Atok);

  // token embedding GEMM (+PE): K=96
  mgemm_k<0, 0, 2, 1><<<256, 512, 0, stream>>>(
      Atok, Twb, ZB, X, Xb, PEf, 4, DM, 96);

  for (int layer = 0; layer < 2; ++layer) {
    const int Lx = (layer == 0) ? 2048 : 1024;
    const int U  = (layer == 0) ? 40 : 35;
    const int M  = NB * Lx;
    const int Yt = M / 128;
    const int NCH = 8;

    uint32_t kl0, kl1, s0, s1;
    threefry2x32(0u, 42u, 0u, (uint32_t)layer, &kl0, &kl1);
    threefry2x32(kl0, kl1, 0u, 1u, &s0, &s1);
    int nidx = Lx * U;
    gen_idx_k<<<(nidx + 255) / 256, 256, 0, stream>>>(IDX, nidx, Lx - 1, s0, s1);

    // fused QKV GEMM: bf16-only output, XCD-swizzled
    mgemm_k<0, 0, 1, 0><<<12 * Yt, 512, 0, stream>>>(
        Xb, Wqkvb + (size_t)layer * 786432, BQKV + layer * 1536, nullptr, QKVb,
        nullptr, 12, QS, DM);

    // ProbSparse attention (all bf16 QKV)
    if (layer == 0)
      qk_m_k<40><<<Lx, 256, 0, stream>>>(QKVb, IDX, Mb, Lx);
    else
      qk_m_k<35><<<Lx, 256, 0, stream>>>(QKVb, IDX, Mb, Lx);
    topk_k<<<NB * NH * (Lx >> 8), 256, 0, stream>>>(Mb, MT, Lx, U);
    meanv1_k<<<NB * 16, 512, 0, stream>>>(QKVb, MVP, Lx);
    meanv2_k<<<NB, 512, 0, stream>>>(MVP, MV, Lx);
    fillctx_k<<<(M * DM / 4) / 256, 256, 0, stream>>>(CTXb, MV, Lx);
    attn_flash_k<<<NB * NH * NCH, 512, 0, stream>>>(QKVb, MT, Y2, Lx, U, NCH);
    attn_merge_k<<<NB * NH * U, 64, 0, stream>>>(Y2, MT, CTXb, Lx, U, NCH);

    // output projection + residual + LN1 (emits bf16 for FFN1)
    mgemm_k<0, 0, 0, 0><<<4 * Yt, 512, 0, stream>>>(
        CTXb, Wob + (size_t)layer * 262144, bo + layer * DM, Y2, nullptr,
        nullptr, 4, DM, DM);
    ln_k<<<M, 128, 0, stream>>>(X, Y2, ln1_g + layer * DM, ln1_b + layer * DM, X, Xb);

    // FFN (GELU fused; hidden kept in bf16); LN2 emits bf16
    mgemm_k<0, 1, 1, 0><<<16 * Yt, 512, 0, stream>>>(
        Xb, W1b + (size_t)layer * 1048576, b1 + layer * 2048, nullptr, Hb,
        nullptr, 16, 2048, DM);
    mgemm_k<0, 0, 0, 0><<<4 * Yt, 512, 0, stream>>>(
        Hb, W2b + (size_t)layer * 1048576, b2 + layer * DM, Y2, nullptr,
        nullptr, 4, DM, 2048);
    ln_k<<<M, 128, 0, stream>>>(X, Y2, ln2_g + layer * DM, ln2_b + layer * DM, X, Xb);

    if (layer == 0) {
      // distil conv as implicit GEMM: A = Xb (circular rows), K=1536
      mgemm_k<1, 0, 0, 0><<<4 * 64, 512, 0, stream>>>(
          Xb, Cwb, conv_b, Y2, nullptr, nullptr, 4, DM, 1536);
      bn1_k<<<32, 256, 0, stream>>>(Y2, BNps, BNpq);
      bn2_k<<<1, 512, 0, stream>>>(BNps, BNpq, BNmu, BNvr);
      bnpool_k<<<(NB * 1024 * 512) / 256, 256, 0, stream>>>(
          Y2, BNmu, BNvr, bn_g, bn_b, X, Xb);
    }
  }

  // final LN + projection (N=32, fp32)
  ln_k<<<NB * 1024, 128, 0, stream>>>(X, nullptr, normf_g, normf_b, SCR, nullptr);
  gemm_k<<<dim3(1, 4096 / 64), 256, 0, stream>>>(SCR, proj_w, proj_b, out,
                                                 4096, 32, DM);
}

// Round 16
// 713.213 us; speedup vs baseline: 1.3239x; 1.0418x over previous
//
#include <hip/hip_runtime.h>
#include <cstdint>
#include <cmath>

// ---------------------------------------------------------------------------
// Informer encoder forward (B=4, L=2048, ENC_IN=32, D_MODEL=512, D_FF=2048,
// E_LAYERS=2, H=8, FACTOR=5).
// Round 16: topk scan split 4-way across a 1024-thread block (16 waves/CU vs
// 4 — the 53 us was latency-bound at 1 block/CU, VALUBusy 23%). Partial ranks
// reduced through LDS; exact JAX tie-breaking preserved.
// ---------------------------------------------------------------------------

#define NB 4
#define DM 512
#define NH 8
#define HD 64
#define QS 1536  // QKV row stride

typedef unsigned short ushort_t;
typedef __bf16 bf16x8 __attribute__((ext_vector_type(8)));
typedef float floatx4 __attribute__((ext_vector_type(4)));
typedef unsigned short ushort8_t __attribute__((ext_vector_type(8)));

__device__ inline ushort_t f2b(float f) {
  uint32_t u = __float_as_uint(f);
  uint32_t r = (u + 0x7fffu + ((u >> 16) & 1u)) >> 16;
  return (ushort_t)r;
}
__device__ inline float b2f(ushort_t u) {
  return __uint_as_float((uint32_t)u << 16);
}

// ---------------- fused weight casts ---------------------------------------
__global__ void castqkv_k(const float* __restrict__ Wq,
                          const float* __restrict__ Wk,
                          const float* __restrict__ Wv,
                          ushort_t* __restrict__ out) {
  int gid = blockIdx.x * 256 + threadIdx.x;  // 393216 float4 units
  if (gid >= 393216) return;
  int ly = gid / 196608, r4 = gid - ly * 196608;
  int r = r4 >> 7, c4 = r4 & 127;
  int sel = r >> 9, srow = r & 511;
  const float* src = (sel == 0 ? Wq : sel == 1 ? Wk : Wv) + ly * 262144 +
                     srow * 512 + c4 * 4;
  float4 v = *(const float4*)src;
  ushort4 o;
  o.x = f2b(v.x); o.y = f2b(v.y); o.z = f2b(v.z); o.w = f2b(v.w);
  ((ushort4*)out)[ly * 196608 + r * 128 + c4] = o;
}

__global__ void castw3_k(const float* __restrict__ Wo,
                         const float* __restrict__ W1,
                         const float* __restrict__ W2,
                         const float* __restrict__ tw,
                         ushort_t* __restrict__ oWo, ushort_t* __restrict__ oW1,
                         ushort_t* __restrict__ oW2, ushort_t* __restrict__ otw) {
  int gid = blockIdx.x * 256 + threadIdx.x;  // 1,191,936 float4 units
  if (gid >= 1191936) return;
  const float* src;
  ushort4* dst;
  int i;
  if (gid < 131072) { src = Wo; dst = (ushort4*)oWo; i = gid; }
  else if (gid < 655360) { src = W1; dst = (ushort4*)oW1; i = gid - 131072; }
  else if (gid < 1179648) { src = W2; dst = (ushort4*)oW2; i = gid - 655360; }
  else { src = tw; dst = (ushort4*)otw; i = gid - 1179648; }
  float4 v = ((const float4*)src)[i];
  ushort4 o;
  o.x = f2b(v.x); o.y = f2b(v.y); o.z = f2b(v.z); o.w = f2b(v.w);
  dst[i] = o;
}

// conv weight: (D, I, 3) -> bf16 (D, 3, I) so implicit-GEMM staging is
// contiguous in the input channel dim
__global__ void castw_conv_k(const float* __restrict__ in,
                             ushort_t* __restrict__ out) {
  int gid = blockIdx.x * 256 + threadIdx.x;  // 512*1536
  int d = gid / 1536, r = gid - d * 1536;
  int t = r >> 9, i = r & 511;
  out[gid] = f2b(in[d * 1536 + i * 3 + t]);
}

__global__ void setup_small_k(const float* __restrict__ bq,
                              const float* __restrict__ bk,
                              const float* __restrict__ bv,
                              float* __restrict__ ZB,
                              float* __restrict__ BQKV) {
  int gid = blockIdx.x * 256 + threadIdx.x;  // 3584
  if (gid >= 3584) return;
  if (gid < 512) { ZB[gid] = 0.f; return; }
  int g = gid - 512;
  int layer = g / 1536, r = g - layer * 1536;
  float v;
  if (r < 512) v = bq[layer * 512 + r];
  else if (r < 1024) v = bk[layer * 512 + r - 512];
  else v = bv[layer * 512 + r - 1024];
  BQKV[g] = v;
}

__host__ __device__ inline void threefry2x32(uint32_t k0, uint32_t k1,
                                             uint32_t c0, uint32_t c1,
                                             uint32_t* o0, uint32_t* o1) {
  uint32_t ks0 = k0, ks1 = k1, ks2 = k0 ^ k1 ^ 0x1BD11BDAu;
  uint32_t x0 = c0 + ks0;
  uint32_t x1 = c1 + ks1;
  const uint32_t rotA[4] = {13u, 15u, 26u, 6u};
  const uint32_t rotB[4] = {17u, 29u, 16u, 24u};
  uint32_t ks[3] = {ks0, ks1, ks2};
  #pragma unroll
  for (int i = 0; i < 5; ++i) {
    const uint32_t* r = (i & 1) ? rotB : rotA;
    #pragma unroll
    for (int j = 0; j < 4; ++j) {
      x0 += x1;
      x1 = (x1 << r[j]) | (x1 >> (32u - r[j]));
      x1 ^= x0;
    }
    x0 += ks[(i + 1) % 3];
    x1 += ks[(i + 2) % 3] + (uint32_t)(i + 1);
  }
  *o0 = x0; *o1 = x1;
}

__global__ void gen_idx_k(int* __restrict__ idx, int n, int mask,
                          uint32_t k0, uint32_t k1) {
  int i = blockIdx.x * 256 + threadIdx.x;
  if (i < n) {
    uint32_t o0, o1;
    threefry2x32(k0, k1, 0u, (uint32_t)i, &o0, &o1);
    idx[i] = (int)((o0 ^ o1) & (uint32_t)mask);
  }
}

__device__ inline float wave_sum64(float v) {
  #pragma unroll
  for (int o = 32; o > 0; o >>= 1) v += __shfl_xor(v, o, 64);
  return v;
}
__device__ inline float wave_max64(float v) {
  #pragma unroll
  for (int o = 32; o > 0; o >>= 1) v = fmaxf(v, __shfl_xor(v, o, 64));
  return v;
}

// ---------------- positional-encoding table (2048 x 512) -------------------
__global__ void pe_k(float* __restrict__ pe) {
  int i = blockIdx.x * 256 + threadIdx.x;  // 1,048,576
  int d = i & 511, l = i >> 9;
  int j2 = d & ~1;
  float div = expf((float)j2 * -1.7988946039e-2f);  // -ln(10000)/512
  float ang = (float)l * div;
  pe[i] = (d & 1) ? cosf(ang) : sinf(ang);
}

// ---------------- im2col for token conv: (B*L, 96) bf16 --------------------
__global__ void im2col_tok_k(const float* __restrict__ xe,
                             ushort_t* __restrict__ A) {
  int gid = blockIdx.x * 256 + threadIdx.x;  // 8192*96
  int col = gid % 96;
  int row = gid / 96;
  int c = col / 3, t = col - c * 3;
  int b = row >> 11, l = row & 2047;
  int ls = (l + t - 1) & 2047;
  A[gid] = f2b(xe[((size_t)b * 2048 + ls) * 32 + c]);
}

// ---------------- bf16 MFMA GEMM v2: 8 waves x (32x64), BK=32 --------------
__device__ inline void gload16(const ushort_t* g, ushort_t* l) {
  __builtin_amdgcn_global_load_lds(
      (const __attribute__((address_space(1))) unsigned int*)(const void*)g,
      (__attribute__((address_space(3))) unsigned int*)(void*)l, 16, 0, 0);
}

// CONV: A is Xb (B*L x 512 bf16); logical A[row][k] = Xb[(row_b, (l+t-1)%2048)][c]
// with t = k/512, c = k%512. Otherwise plain row-major A (M x K).
template <int CONV, int GELU, int OMODE, int ADDPE>  // OMODE: 0 f32,1 bf16,2 both
__global__ __launch_bounds__(512) void mgemm_k(
    const ushort_t* __restrict__ A, const ushort_t* __restrict__ W,
    const float* __restrict__ bias, float* __restrict__ Cf,
    ushort_t* __restrict__ Cb, const float* __restrict__ pe,
    int X, int ldc, int K) {
  __shared__ ushort_t As[128 * 32];
  __shared__ ushort_t Bs[128 * 32];
  int id = blockIdx.x;
  int cc = id & 7, j = id >> 3;
  int bx = j % X;
  int by = (j / X) * 8 + cc;
  int m0 = by * 128, n0 = bx * 128;
  int t = threadIdx.x;
  int lane = t & 63, wv = t >> 6;  // 8 waves
  int rl = lane >> 2, cl = (lane & 3) * 8;
  int Ra = wv * 16;  // 16 rows staged per wave (A and B)
  int ga_row = m0 + Ra + rl;
  const ushort_t* gA = A + (size_t)ga_row * K + cl;  // non-CONV path
  const ushort_t* gB = W + (size_t)(n0 + Ra + rl) * K + cl;
  ushort_t* lA = As + Ra * 32;
  ushort_t* lB = Bs + Ra * 32;
  int cb = ga_row >> 11, clr = ga_row & 2047;  // CONV: batch, seq pos

  int quad = lane >> 4, lr = lane & 15;
  int wm = wv >> 1, wn = wv & 1;  // 4 (M) x 2 (N) waves

  floatx4 acc[2][4] = {};
  for (int ks = 0; ks < K; ks += 32) {
    if (ks) __syncthreads();
    if (CONV) {
      int tt = ks >> 9;
      int c = (ks & 511) + cl;
      int ls = (clr + tt - 1) & 2047;
      gload16(A + ((size_t)(cb * 2048 + ls) * 512 + c), lA);
    } else {
      gload16(gA, lA);
      gA += 32;
    }
    gload16(gB, lB);
    gB += 32;
    __syncthreads();
    bf16x8 av[2], bv[4];
    #pragma unroll
    for (int mt = 0; mt < 2; ++mt)
      av[mt] = *(const bf16x8*)&As[(wm * 32 + mt * 16 + lr) * 32 + quad * 8];
    #pragma unroll
    for (int nt = 0; nt < 4; ++nt)
      bv[nt] = *(const bf16x8*)&Bs[(wn * 64 + nt * 16 + lr) * 32 + quad * 8];
    #pragma unroll
    for (int mt = 0; mt < 2; ++mt)
      #pragma unroll
      for (int nt = 0; nt < 4; ++nt)
        acc[mt][nt] = __builtin_amdgcn_mfma_f32_16x16x32_bf16(
            av[mt], bv[nt], acc[mt][nt], 0, 0, 0);
  }
  #pragma unroll
  for (int nt = 0; nt < 4; ++nt) {
    int col = n0 + wn * 64 + nt * 16 + lr;
    float bsv = bias[col];
    #pragma unroll
    for (int mt = 0; mt < 2; ++mt) {
      int row0 = m0 + wm * 32 + mt * 16 + quad * 4;
      #pragma unroll
      for (int r = 0; r < 4; ++r) {
        int row = row0 + r;
        float v = acc[mt][nt][r] + bsv;
        if (ADDPE) v += pe[(size_t)(row & 2047) * ldc + col];
        if (GELU) v = 0.5f * v * (1.0f + erff(v * 0.70710678118654752f));
        if (OMODE == 0 || OMODE == 2) Cf[(size_t)row * ldc + col] = v;
        if (OMODE == 1 || OMODE == 2) Cb[(size_t)row * ldc + col] = f2b(v);
      }
    }
  }
}

// ---------------- fp32 fallback GEMM (final projection, N=32) --------------
__global__ __launch_bounds__(256) void gemm_k(
    const float* __restrict__ A, const float* __restrict__ W,
    const float* __restrict__ bias, float* __restrict__ C,
    int M, int N, int K) {
  __shared__ float As2[16][64 + 4];
  __shared__ float Ws2[16][64 + 4];
  int m0 = blockIdx.y * 64, n0 = blockIdx.x * 64;
  int t = threadIdx.x;
  int tx = t & 15, ty = t >> 4;
  float acc[4][4] = {};
  for (int k0 = 0; k0 < K; k0 += 16) {
    #pragma unroll
    for (int i = 0; i < 4; ++i) {
      int li = t + i * 256;
      int m = li >> 4, kk = li & 15;
      As2[kk][m] = A[(size_t)(m0 + m) * K + k0 + kk];
    }
    #pragma unroll
    for (int i = 0; i < 4; ++i) {
      int li = t + i * 256;
      int n = li >> 4, kk = li & 15;
      int gn = n0 + n;
      Ws2[kk][n] = (gn < N) ? W[(size_t)gn * K + k0 + kk] : 0.0f;
    }
    __syncthreads();
    #pragma unroll
    for (int kk = 0; kk < 16; ++kk) {
      float4 avv = *(const float4*)&As2[kk][ty * 4];
      float4 bvv = *(const float4*)&Ws2[kk][tx * 4];
      float a[4] = {avv.x, avv.y, avv.z, avv.w};
      float bb[4] = {bvv.x, bvv.y, bvv.z, bvv.w};
      #pragma unroll
      for (int i = 0; i < 4; ++i)
        #pragma unroll
        for (int j = 0; j < 4; ++j) acc[i][j] += a[i] * bb[j];
    }
    __syncthreads();
  }
  #pragma unroll
  for (int i = 0; i < 4; ++i) {
    int m = m0 + ty * 4 + i;
    #pragma unroll
    for (int j = 0; j < 4; ++j) {
      int n = n0 + tx * 4 + j;
      if (n < N) C[(size_t)m * N + n] = acc[i][j] + bias[n];
    }
  }
}

// ---------------- LayerNorm (+optional residual, +optional bf16 copy) ------
__global__ __launch_bounds__(128) void ln_k(
    const float* __restrict__ A, const float* __restrict__ Bres,
    const float* __restrict__ g, const float* __restrict__ be,
    float* __restrict__ O, ushort_t* __restrict__ Ob) {
  int r = blockIdx.x, t = threadIdx.x;
  __shared__ float lds[2];
  float4 v = ((const float4*)(A + (size_t)r * DM))[t];
  if (Bres) {
    float4 u = ((const float4*)(Bres + (size_t)r * DM))[t];
    v.x += u.x; v.y += u.y; v.z += u.z; v.w += u.w;
  }
  float s = wave_sum64(v.x + v.y + v.z + v.w);
  int w = t >> 6;
  if ((t & 63) == 0) lds[w] = s;
  __syncthreads();
  float mu = (lds[0] + lds[1]) * (1.0f / 512.0f);
  __syncthreads();
  float dx = v.x - mu, dy = v.y - mu, dz = v.z - mu, dw = v.w - mu;
  float sq = wave_sum64(dx * dx + dy * dy + dz * dz + dw * dw);
  if ((t & 63) == 0) lds[w] = sq;
  __syncthreads();
  float var = (lds[0] + lds[1]) * (1.0f / 512.0f);
  float inv = 1.0f / sqrtf(var + 1e-5f);
  float4 gv = ((const float4*)g)[t];
  float4 bv = ((const float4*)be)[t];
  float4 o;
  o.x = dx * inv * gv.x + bv.x;
  o.y = dy * inv * gv.y + bv.y;
  o.z = dz * inv * gv.z + bv.z;
  o.w = dw * inv * gv.w + bv.w;
  ((float4*)(O + (size_t)r * DM))[t] = o;
  if (Ob) {
    ushort4 ob;
    ob.x = f2b(o.x); ob.y = f2b(o.y); ob.z = f2b(o.z); ob.w = f2b(o.w);
    ((ushort4*)(Ob + (size_t)r * DM))[t] = ob;
  }
}

// ---------------- M[b,h,l]: one wave per (b,l), all-bf16 QKV ---------------
template <int UU>
__global__ __launch_bounds__(256) void qk_m_k(
    const ushort_t* __restrict__ QKVb, const int* __restrict__ idx,
    float* __restrict__ Mout, int Lx) {
  int l = blockIdx.x;
  int b = threadIdx.x >> 6;  // wave = batch
  int lane = threadIdx.x & 63;
  const ushort_t* qp = QKVb + ((size_t)b * Lx + l) * QS + lane * 8;
  float q[8];
  {
    ushort8_t qv = *(const ushort8_t*)qp;
    #pragma unroll
    for (int c = 0; c < 8; ++c) q[c] = b2f(qv[c]);
  }
  const ushort_t* Kbase = QKVb + (size_t)b * Lx * QS + 512 + lane * 8;
  const int* ip = idx + (size_t)l * UU;
  float maxv = -INFINITY, sumv = 0.f;
  #pragma unroll
  for (int u0 = 0; u0 < UU; u0 += 8) {
    ushort8_t kv[8];
    #pragma unroll
    for (int j = 0; j < 8; ++j) {
      if (u0 + j < UU)
        kv[j] = *(const ushort8_t*)(Kbase + (size_t)ip[u0 + j] * QS);
    }
    #pragma unroll
    for (int j = 0; j < 8; ++j) {
      if (u0 + j < UU) {
        float p = 0.f;
        #pragma unroll
        for (int c = 0; c < 8; ++c) p += q[c] * b2f(kv[j][c]);
        p += __shfl_xor(p, 1, 64);
        p += __shfl_xor(p, 2, 64);
        p += __shfl_xor(p, 4, 64);
        maxv = fmaxf(maxv, p);
        sumv += p;
      }
    }
  }
  if ((lane & 7) == 0) {
    int h = lane >> 3;
    Mout[(size_t)(b * 8 + h) * Lx + l] = maxv - sumv / (float)Lx;
  }
}

// ---------------- rank-based top-U, 4-way scan split (JAX tie-break) -------
// 1024 threads: thread (q,c) ranks candidate ch*256+c over scan quarter q.
// Partial ranks reduced through LDS; rank < U => write at position rank.
__global__ __launch_bounds__(1024) void topk_k(
    const float* __restrict__ Mbuf, int* __restrict__ Mtop, int Lx, int U) {
  int nch = Lx >> 8;
  int bh = blockIdx.x / nch, ch = blockIdx.x % nch;
  const float* m = Mbuf + (size_t)bh * Lx;
  __shared__ float sm[2048];
  __shared__ int part[1024];
  int t = threadIdx.x;
  int c = t & 255, q = t >> 8;
  for (int i = t; i < Lx; i += 1024) sm[i] = m[i];
  __syncthreads();
  int i0 = (ch << 8) + c;
  float v0 = sm[i0];
  int r0 = 0;
  int qlen = Lx >> 2;
  int j0 = q * qlen, j1 = j0 + qlen;
  for (int j = j0; j < j1; j += 4) {
    float4 mj = *(const float4*)&sm[j];
    r0 += (mj.x > v0) || (mj.x == v0 && (j + 0) < i0);
    r0 += (mj.y > v0) || (mj.y == v0 && (j + 1) < i0);
    r0 += (mj.z > v0) || (mj.z == v0 && (j + 2) < i0);
    r0 += (mj.w > v0) || (mj.w == v0 && (j + 3) < i0);
  }
  part[t] = r0;
  __syncthreads();
  if (q == 0) {
    int r = part[c] + part[c + 256] + part[c + 512] + part[c + 768];
    if (r < U) Mtop[bh * U + r] = i0;
  }
}

// ---------------- meanV from bf16 QKV (V at +1024) -------------------------
__global__ __launch_bounds__(512) void meanv1_k(const ushort_t* __restrict__ QKVb,
                                                float* __restrict__ part,
                                                int Lx) {
  int b = blockIdx.x >> 4, chunk = blockIdx.x & 15;
  int rows = Lx >> 4;
  int t = threadIdx.x;  // 512
  const ushort_t* vp =
      QKVb + ((size_t)b * Lx + (size_t)chunk * rows) * QS + 1024 + t;
  float s = 0.f;
  for (int l = 0; l < rows; ++l) s += b2f(vp[(size_t)l * QS]);
  part[(size_t)blockIdx.x * DM + t] = s;
}
__global__ __launch_bounds__(512) void meanv2_k(const float* __restrict__ part,
                                                float* __restrict__ mv,
                                                int Lx) {
  int b = blockIdx.x, t = threadIdx.x;
  float s = 0.f;
  #pragma unroll
  for (int c = 0; c < 16; ++c) s += part[(size_t)(b * 16 + c) * DM + t];
  mv[b * DM + t] = s / (float)Lx;
}

__global__ void fillctx_k(ushort_t* __restrict__ ctx,
                          const float* __restrict__ mv, int Lx) {
  size_t i4 = (size_t)blockIdx.x * 256 + threadIdx.x;
  int col4 = (int)(i4 & 127);
  size_t row = i4 >> 7;
  int b = (int)(row / (size_t)Lx);
  const float* m = mv + b * DM + col4 * 4;
  ushort4 o;
  o.x = f2b(m[0]); o.y = f2b(m[1]); o.z = f2b(m[2]); o.w = f2b(m[3]);
  ((ushort4*)ctx)[i4] = o;
}

// ---------------- flash split-K attention (bf16 QKV) -----------------------
__global__ __launch_bounds__(512) void attn_flash_k(
    const ushort_t* __restrict__ QKVb, const int* __restrict__ Mtop,
    float* __restrict__ part, int Lx, int U, int nchunk) {
  int blk = blockIdx.x;
  int chunk = blk % nchunk, bh = blk / nchunk;
  int h = bh & 7, b = bh >> 3;
  int rows = Lx / nchunk;
  int ntile = rows >> 6;
  __shared__ float s_q[40 * 64];
  __shared__ float s_k[64 * 65];
  __shared__ float s_v[64 * 65];
  __shared__ float s_p[40 * 64];
  __shared__ float s_m[40], s_l[40], s_a[40];
  int t = threadIdx.x;
  int d = t & 63, wv = t >> 6;

  for (int i = t; i < U * 64; i += 512) {
    int u = i >> 6, dd = i & 63;
    int qi = Mtop[bh * U + u];
    s_q[i] = b2f(QKVb[((size_t)b * Lx + qi) * QS + h * HD + dd]) * 0.125f;
  }
  if (t < U) { s_m[t] = -INFINITY; s_l[t] = 0.f; s_a[t] = 0.f; }
  float o[5] = {0.f, 0.f, 0.f, 0.f, 0.f};
  __syncthreads();

  const ushort_t* Kp = QKVb + (size_t)b * Lx * QS + 512 + h * HD;
  const ushort_t* Vp = QKVb + (size_t)b * Lx * QS + 1024 + h * HD;

  for (int tile = 0; tile < ntile; ++tile) {
    int kr0 = chunk * rows + tile * 64;
    {
      int r = t >> 3, c8 = (t & 7) * 8;  // 8 threads/row x 64 rows
      ushort8_t kv = *(const ushort8_t*)&Kp[(size_t)(kr0 + r) * QS + c8];
      ushort8_t vv = *(const ushort8_t*)&Vp[(size_t)(kr0 + r) * QS + c8];
      float* kd = &s_k[r * 65 + c8];
      float* vd = &s_v[r * 65 + c8];
      #pragma unroll
      for (int jj = 0; jj < 8; ++jj) {
        kd[jj] = b2f(kv[jj]);
        vd[jj] = b2f(vv[jj]);
      }
    }
    __syncthreads();
    {
      float kr[64];
      #pragma unroll
      for (int dd = 0; dd < 64; ++dd) kr[dd] = s_k[d * 65 + dd];
      for (int u = wv; u < U; u += 8) {
        float acc = 0.f;
        #pragma unroll
        for (int c = 0; c < 16; ++c) {
          float4 qv = *(const float4*)&s_q[u * 64 + c * 4];
          acc += qv.x * kr[c * 4] + qv.y * kr[c * 4 + 1] +
                 qv.z * kr[c * 4 + 2] + qv.w * kr[c * 4 + 3];
        }
        s_p[u * 64 + d] = acc;
      }
    }
    __syncthreads();
    for (int u = wv; u < U; u += 8) {
      float sv_ = s_p[u * 64 + d];
      float mx = wave_max64(sv_);
      float mold = s_m[u];
      float mnew = fmaxf(mold, mx);
      float e = expf(sv_ - mnew);
      float se = wave_sum64(e);
      s_p[u * 64 + d] = e;
      if (d == 0) {
        float alpha = expf(mold - mnew);
        s_a[u] = alpha;
        s_l[u] = s_l[u] * alpha + se;
        s_m[u] = mnew;
      }
    }
    __syncthreads();
    {
      float vr[64];
      #pragma unroll
      for (int k = 0; k < 64; ++k) vr[k] = s_v[k * 65 + d];
      int i = 0;
      for (int u = wv; u < U; u += 8, ++i) {
        float acc = 0.f;
        #pragma unroll
        for (int c = 0; c < 16; ++c) {
          float4 pv = *(const float4*)&s_p[u * 64 + c * 4];
          acc += pv.x * vr[c * 4] + pv.y * vr[c * 4 + 1] +
                 pv.z * vr[c * 4 + 2] + pv.w * vr[c * 4 + 3];
        }
        o[i] = o[i] * s_a[u] + acc;
      }
    }
    __syncthreads();
  }
  {
    int i = 0;
    for (int u = wv; u < U; u += 8, ++i) {
      float* pp = part + ((size_t)(bh * nchunk + chunk) * U + u) * 66;
      pp[d] = o[i];
      if (d == 0) { pp[64] = s_m[u]; pp[65] = s_l[u]; }
    }
  }
}

__global__ __launch_bounds__(64) void attn_merge_k(
    const float* __restrict__ part, const int* __restrict__ Mtop,
    ushort_t* __restrict__ ctx, int Lx, int U, int nchunk) {
  int bu = blockIdx.x;
  int u = bu % U, bh = bu / U;
  int h = bh & 7, b = bh >> 3;
  int d = threadIdx.x;  // 64
  float M = -INFINITY;
  for (int c = 0; c < nchunk; ++c)
    M = fmaxf(M, part[((size_t)(bh * nchunk + c) * U + u) * 66 + 64]);
  float L = 0.f, O = 0.f;
  for (int c = 0; c < nchunk; ++c) {
    const float* pp = part + ((size_t)(bh * nchunk + c) * U + u) * 66;
    float w = expf(pp[64] - M);
    L += pp[65] * w;
    O += pp[d] * w;
  }
  int qi = Mtop[bh * U + u];
  ctx[((size_t)b * Lx + qi) * DM + h * HD + d] = f2b(O / L);
}

// ---------------- batch-norm stats: coalesced two-stage --------------------
__global__ __launch_bounds__(256) void bn1_k(const float* __restrict__ Y,
                                             float* __restrict__ ps,
                                             float* __restrict__ pq) {
  int blk = blockIdx.x;
  int t = threadIdx.x;
  float s0 = 0, q0 = 0, s1 = 0, q1 = 0;
  const float* base = Y + (size_t)blk * 256 * DM;
  for (int r = 0; r < 256; ++r) {
    float a = base[(size_t)r * DM + t];
    float b = base[(size_t)r * DM + t + 256];
    s0 += a; q0 += a * a; s1 += b; q1 += b * b;
  }
  ps[blk * DM + t] = s0; ps[blk * DM + t + 256] = s1;
  pq[blk * DM + t] = q0; pq[blk * DM + t + 256] = q1;
}
__global__ __launch_bounds__(512) void bn2_k(const float* __restrict__ ps,
                                             const float* __restrict__ pq,
                                             float* __restrict__ mu,
                                             float* __restrict__ var) {
  int t = threadIdx.x;
  float s = 0, q = 0;
  #pragma unroll
  for (int c = 0; c < 32; ++c) { s += ps[c * DM + t]; q += pq[c * DM + t]; }
  float m = s * (1.0f / 8192.f);
  mu[t] = m;
  var[t] = q * (1.0f / 8192.f) - m * m;
}

// fused bn+elu+maxpool(k=3,s=2,pad=1)
__global__ void bnpool_k(const float* __restrict__ Y,
                         const float* __restrict__ mu,
                         const float* __restrict__ var,
                         const float* __restrict__ g,
                         const float* __restrict__ be, float* __restrict__ O,
                         ushort_t* __restrict__ Ob) {
  size_t i = (size_t)blockIdx.x * 256 + threadIdx.x;  // 4*1024*512
  int c = (int)(i & 511);
  size_t row = i >> 9;
  int lo = (int)(row & 1023);
  int b = (int)(row >> 10);
  float sc = g[c] / sqrtf(var[c] + 1e-5f);
  float sh = be[c] - mu[c] * sc;
  int l0 = 2 * lo - 1;
  float m = -INFINITY;
  #pragma unroll
  for (int tt = 0; tt < 3; ++tt) {
    int l = l0 + tt;
    if (l >= 0 && l < 2048) {
      float v = Y[((size_t)b * 2048 + l) * DM + c] * sc + sh;
      v = v > 0.f ? v : expm1f(v);
      m = fmaxf(m, v);
    }
  }
  O[i] = m;
  Ob[i] = f2b(m);
}

// ---------------------------------------------------------------------------
extern "C" void kernel_launch(void* const* d_in, const int* in_sizes, int n_in,
                              void* d_out, int out_size, void* d_ws,
                              size_t ws_size, hipStream_t stream) {
  (void)in_sizes; (void)n_in; (void)out_size; (void)ws_size;
  const float* x_enc  = (const float*)d_in[0];
  const float* tok_w  = (const float*)d_in[1];
  const float* Wq     = (const float*)d_in[2];
  const float* bq     = (const float*)d_in[3];
  const float* Wk     = (const float*)d_in[4];
  const float* bk     = (const float*)d_in[5];
  const float* Wv     = (const float*)d_in[6];
  const float* bv     = (const float*)d_in[7];
  const float* Wo     = (const float*)d_in[8];
  const float* bo     = (const float*)d_in[9];
  const float* W1     = (const float*)d_in[10];
  const float* b1     = (const float*)d_in[11];
  const float* W2     = (const float*)d_in[12];
  const float* b2     = (const float*)d_in[13];
  const float* ln1_g  = (const float*)d_in[14];
  const float* ln1_b  = (const float*)d_in[15];
  const float* ln2_g  = (const float*)d_in[16];
  const float* ln2_b  = (const float*)d_in[17];
  const float* conv_w = (const float*)d_in[18];
  const float* conv_b = (const float*)d_in[19];
  const float* bn_g   = (const float*)d_in[20];
  const float* bn_b   = (const float*)d_in[21];
  const float* normf_g = (const float*)d_in[22];
  const float* normf_b = (const float*)d_in[23];
  const float* proj_w = (const float*)d_in[24];
  const float* proj_b = (const float*)d_in[25];
  float* out = (float*)d_out;
  float* ws = (float*)d_ws;

  // ---- fp32 workspace layout (float offsets) ----
  float* X    = ws;                    // 4,194,304
  float* SCR  = ws + 4194304;          // 12,582,912 (final-LN scratch)
  ushort_t* CTXb = (ushort_t*)(ws + 16777216);  // bf16 ctx
  float* Y2   = ws + 20971520;         // 4,194,304 (attn partials / conv out)
  float* Mb   = ws + 25165824;         // 65,536
  float* MV   = ws + 25231360;         // 2,048
  float* MVP  = ws + 25233408;         // 32,768
  float* BNps = ws + 25266176;         // 16,384
  float* BNpq = ws + 25282560;         // 16,384
  float* BNmu = ws + 25298944;         // 512
  float* BNvr = ws + 25299456;         // 512
  float* ZB   = ws + 25299968;         // 512 (zero bias)
  float* BQKV = ws + 25300480;         // 3,072 (concat qkv bias, 2 layers)
  int*   IDX  = (int*)(ws + 25303552); // 81,920
  int*   MT   = (int*)(ws + 25385472); // 1,280
  // ---- bf16 workspace ----
  ushort_t* U0   = (ushort_t*)(ws + 25386752);
  ushort_t* Xb   = U0;                 // 4,194,304
  ushort_t* Hb   = U0 + 4194304;       // 16,777,216 (FFN hidden)
  ushort_t* QKVb = Hb;                 // alias: bf16 QKV — live QKV-GEMM ->
                                       // attn, before FFN uses Hb
  ushort_t* Wqkvb= U0 + 20971520;      // 1,572,864
  ushort_t* Wob  = U0 + 22544384;      // 524,288
  ushort_t* W1b  = U0 + 23068672;      // 2,097,152
  ushort_t* W2b  = U0 + 25165824;      // 2,097,152
  ushort_t* Cwb  = U0 + 27262976;      // 786,432 ([d][t][i] layout)
  ushort_t* Twb  = U0 + 28049408;      // 49,152
  ushort_t* Atok = U0 + 28098560;      // 786,432
  float* PEf = ws + 39829248;          // 1,048,576 (PE table)

  // ---- fused preamble ----
  castqkv_k<<<1536, 256, 0, stream>>>(Wq, Wk, Wv, Wqkvb);
  castw3_k<<<4656, 256, 0, stream>>>(Wo, W1, W2, tok_w, Wob, W1b, W2b, Twb);
  castw_conv_k<<<3072, 256, 0, stream>>>(conv_w, Cwb);
  setup_small_k<<<14, 256, 0, stream>>>(bq, bk, bv, ZB, BQKV);
  pe_k<<<4096, 256, 0, stream>>>(PEf);
  im2col_tok_k<<<3072, 256, 0, stream>>>(x_enc, Atok);

  // token embedding GEMM (+PE): K=96
  mgemm_k<0, 0, 2, 1><<<256, 512, 0, stream>>>(
      Atok, Twb, ZB, X, Xb, PEf, 4, DM, 96);

  for (int layer = 0; layer < 2; ++layer) {
    const int Lx = (layer == 0) ? 2048 : 1024;
    const int U  = (layer == 0) ? 40 : 35;
    const int M  = NB * Lx;
    const int Yt = M / 128;
    const int NCH = 8;

    uint32_t kl0, kl1, s0, s1;
    threefry2x32(0u, 42u, 0u, (uint32_t)layer, &kl0, &kl1);
    threefry2x32(kl0, kl1, 0u, 1u, &s0, &s1);
    int nidx = Lx * U;
    gen_idx_k<<<(nidx + 255) / 256, 256, 0, stream>>>(IDX, nidx, Lx - 1, s0, s1);

    // fused QKV GEMM: bf16-only output, XCD-swizzled
    mgemm_k<0, 0, 1, 0><<<12 * Yt, 512, 0, stream>>>(
        Xb, Wqkvb + (size_t)layer * 786432, BQKV + layer * 1536, nullptr, QKVb,
        nullptr, 12, QS, DM);

    // ProbSparse attention (all bf16 QKV)
    if (layer == 0)
      qk_m_k<40><<<Lx, 256, 0, stream>>>(QKVb, IDX, Mb, Lx);
    else
      qk_m_k<35><<<Lx, 256, 0, stream>>>(QKVb, IDX, Mb, Lx);
    topk_k<<<NB * NH * (Lx >> 8), 1024, 0, stream>>>(Mb, MT, Lx, U);
    meanv1_k<<<NB * 16, 512, 0, stream>>>(QKVb, MVP, Lx);
    meanv2_k<<<NB, 512, 0, stream>>>(MVP, MV, Lx);
    fillctx_k<<<(M * DM / 4) / 256, 256, 0, stream>>>(CTXb, MV, Lx);
    attn_flash_k<<<NB * NH * NCH, 512, 0, stream>>>(QKVb, MT, Y2, Lx, U, NCH);
    attn_merge_k<<<NB * NH * U, 64, 0, stream>>>(Y2, MT, CTXb, Lx, U, NCH);

    // output projection + residual + LN1 (emits bf16 for FFN1)
    mgemm_k<0, 0, 0, 0><<<4 * Yt, 512, 0, stream>>>(
        CTXb, Wob + (size_t)layer * 262144, bo + layer * DM, Y2, nullptr,
        nullptr, 4, DM, DM);
    ln_k<<<M, 128, 0, stream>>>(X, Y2, ln1_g + layer * DM, ln1_b + layer * DM, X, Xb);

    // FFN (GELU fused; hidden kept in bf16); LN2 emits bf16
    mgemm_k<0, 1, 1, 0><<<16 * Yt, 512, 0, stream>>>(
        Xb, W1b + (size_t)layer * 1048576, b1 + layer * 2048, nullptr, Hb,
        nullptr, 16, 2048, DM);
    mgemm_k<0, 0, 0, 0><<<4 * Yt, 512, 0, stream>>>(
        Hb, W2b + (size_t)layer * 1048576, b2 + layer * DM, Y2, nullptr,
        nullptr, 4, DM, 2048);
    ln_k<<<M, 128, 0, stream>>>(X, Y2, ln2_g + layer * DM, ln2_b + layer * DM, X, Xb);

    if (layer == 0) {
      // distil conv as implicit GEMM: A = Xb (circular rows), K=1536
      mgemm_k<1, 0, 0, 0><<<4 * 64, 512, 0, stream>>>(
          Xb, Cwb, conv_b, Y2, nullptr, nullptr, 4, DM, 1536);
      bn1_k<<<32, 256, 0, stream>>>(Y2, BNps, BNpq);
      bn2_k<<<1, 512, 0, stream>>>(BNps, BNpq, BNmu, BNvr);
      bnpool_k<<<(NB * 1024 * 512) / 256, 256, 0, stream>>>(
          Y2, BNmu, BNvr, bn_g, bn_b, X, Xb);
    }
  }

  // final LN + projection (N=32, fp32)
  ln_k<<<NB * 1024, 128, 0, stream>>>(X, nullptr, normf_g, normf_b, SCR, nullptr);
  gemm_k<<<dim3(1, 4096 / 64), 256, 0, stream>>>(SCR, proj_w, proj_b, out,
                                                 4096, 32, DM);
}